// Round 16
// baseline (342.541 us; speedup 1.0000x reference)
//
#include <hip/hip_runtime.h>

#define NH 8
#define DH 64
#define FF 256
#define CH 128

typedef unsigned short u16;
typedef unsigned int u32;
typedef __attribute__((ext_vector_type(8))) short bf16x8;
typedef __attribute__((ext_vector_type(4))) float f32x4;

__device__ __forceinline__ u16 f2bf(float f) {
    u32 u = __float_as_uint(f);
    return (u16)((u + 0x7fffu + ((u >> 16) & 1u)) >> 16);
}
__device__ __forceinline__ float bf2f(u16 h) { return __uint_as_float(((u32)h) << 16); }
__device__ __forceinline__ u32 pk(u16 a, u16 b) { return (u32)a | ((u32)b << 16); }
__device__ __forceinline__ int swz(int row, int col, int ld) {
    return ((row * ld + col) * 2) ^ ((row & 7) << 4);
}
__device__ __forceinline__ f32x4 MF(bf16x8 a, bf16x8 b, f32x4 c) {
    return __builtin_amdgcn_mfma_f32_16x16x32_bf16(a, b, c, 0, 0, 0);
}
__device__ __forceinline__ float wave_max(float v) {
    #pragma unroll
    for (int o = 32; o; o >>= 1) v = fmaxf(v, __shfl_xor(v, o));
    return v;
}
// async global->LDS, 16B/lane; dest = uniform base + lane*16 (HW)
__device__ __forceinline__ void gload16(const void* g, void* l) {
    __builtin_amdgcn_global_load_lds(
        (const __attribute__((address_space(1))) void*)g,
        (__attribute__((address_space(3))) void*)l, 16, 0, 0);
}

// ---------- split-bf16 convert: A:[hi|hi|lo]  B:[hi|lo|hi] ----------
template<bool ISB>
__global__ __launch_bounds__(256)
void conv_split(const float* __restrict__ src, u16* __restrict__ dst,
                int K, long total4, float scale)
{
    const int K4 = K >> 2;
    for (long i = (long)blockIdx.x * 256 + threadIdx.x; i < total4;
         i += (long)gridDim.x * 256) {
        long row = i / K4;
        int c = (int)(i - row * K4) * 4;
        float4 v = ((const float4*)src)[i];
        float a0 = v.x * scale, a1 = v.y * scale, a2 = v.z * scale, a3 = v.w * scale;
        u16 h0 = f2bf(a0), h1 = f2bf(a1), h2 = f2bf(a2), h3 = f2bf(a3);
        u16 l0 = f2bf(a0 - bf2f(h0)), l1 = f2bf(a1 - bf2f(h1));
        u16 l2 = f2bf(a2 - bf2f(h2)), l3 = f2bf(a3 - bf2f(h3));
        uint2 hh; hh.x = pk(h0, h1); hh.y = pk(h2, h3);
        uint2 ll; ll.x = pk(l0, l1); ll.y = pk(l2, l3);
        u16* d = dst + row * (3L * K) + c;
        *(uint2*)d = hh;
        *(uint2*)(d + (ISB ? 2 * K : K)) = hh;
        *(uint2*)(d + (ISB ? K : 2 * K)) = ll;
    }
}

// ---------- fused Wq/Wk/Wv split convert (B layout [hi|lo|hi], K=512), one launch ----------
__global__ __launch_bounds__(256)
void conv_w3(const float* __restrict__ Wq, const float* __restrict__ Wk,
             const float* __restrict__ Wv, u16* __restrict__ dst)
{
    const int seg = blockIdx.x >> 8;                  // 0=q,1=k,2=v (256 blocks each)
    const float* src = seg == 0 ? Wq : (seg == 1 ? Wk : Wv);
    u16* d0 = dst + (size_t)seg * 786432;
    long i = (long)(blockIdx.x & 255) * 256 + threadIdx.x;   // one float4 each, 65536 total
    long row = i >> 7;
    int c = ((int)i & 127) * 4;
    float4 v = ((const float4*)src)[i];
    float a[4] = {v.x, v.y, v.z, v.w};
    alignas(8) u16 hb[4], lb[4];
    #pragma unroll
    for (int q = 0; q < 4; q++) {
        u16 hh = f2bf(a[q]); hb[q] = hh; lb[q] = f2bf(a[q] - bf2f(hh));
    }
    u16* d = d0 + row * 1536 + c;
    *(uint2*)d = *(uint2*)hb;
    *(uint2*)(d + 512) = *(uint2*)lb;
    *(uint2*)(d + 1024) = *(uint2*)hb;
}

// ---------- proj convert: [256][64] f32 -> [256][128] u16 [hi|hi] ----------
__global__ __launch_bounds__(256)
void conv_projdup(const float* __restrict__ src, u16* __restrict__ dst)
{
    long i = (long)blockIdx.x * 256 + threadIdx.x;   // 4096 float4s
    long row = i >> 4;
    int c = ((int)i & 15) * 4;
    float4 v = ((const float4*)src)[i];
    alignas(8) u16 hb[4];
    hb[0] = f2bf(v.x); hb[1] = f2bf(v.y); hb[2] = f2bf(v.z); hb[3] = f2bf(v.w);
    u16* d = dst + row * 128 + c;
    *(uint2*)d = *(uint2*)hb;
    *(uint2*)(d + 64) = *(uint2*)hb;
}

// ---------- plain bf16 convert ----------
__global__ __launch_bounds__(256)
void conv_plain(const float* __restrict__ src, u16* __restrict__ dst, long total4)
{
    for (long i = (long)blockIdx.x * 256 + threadIdx.x; i < total4;
         i += (long)gridDim.x * 256) {
        float4 v = ((const float4*)src)[i];
        ushort4 o;
        o.x = f2bf(v.x); o.y = f2bf(v.y); o.z = f2bf(v.z); o.w = f2bf(v.w);
        ((ushort4*)dst)[i] = o;
    }
}

// ---------- fused QKV GEMM, 128x128 tile, global_load_lds staging ----------
// q/k epilogue writes [hi|lo] per head (K=128 layout) + diag; v -> vpl hi/lo planes
__global__ __launch_bounds__(256, 3)
void qkv_gemm(const u16* __restrict__ A, const u16* __restrict__ B,
              u16* __restrict__ qs, float* __restrict__ diagb,
              u16* __restrict__ vpl)
{
    __shared__ char smem[34816];
    char* As = smem; char* Bs = smem + 16384;
    const int m0 = blockIdx.x * 128, by = blockIdx.y, n0 = by * 128;
    const int tid = threadIdx.x, lane = tid & 63, wave = tid >> 6;
    const int wm = (wave >> 1) * 64, wn = (wave & 1) * 64;
    const int fr = lane & 15, fk = (lane >> 4) * 8;
    const int lr8 = lane >> 3;
    const int cE = ((lane & 7) ^ lr8) << 3;
    f32x4 acc[4][4] = {};
    for (int k0 = 0; k0 < 1536; k0 += 64) {
        #pragma unroll
        for (int t = 0; t < 4; t++) {
            int i = wave * 4 + t;
            int r = (i << 3) + lr8;
            gload16(A + (size_t)(m0 + r) * 1536 + k0 + cE, As + (i << 10));
            gload16(B + (size_t)(n0 + r) * 1536 + k0 + cE, Bs + (i << 10));
        }
        __syncthreads();
        #pragma unroll
        for (int ks = 0; ks < 2; ks++) {
            bf16x8 af[4], bfv[4];
            #pragma unroll
            for (int mf = 0; mf < 4; mf++)
                af[mf] = *(bf16x8*)(As + swz(wm + mf * 16 + fr, ks * 32 + fk, 64));
            #pragma unroll
            for (int nf = 0; nf < 4; nf++)
                bfv[nf] = *(bf16x8*)(Bs + swz(wn + nf * 16 + fr, ks * 32 + fk, 64));
            #pragma unroll
            for (int mf = 0; mf < 4; mf++)
                #pragma unroll
                for (int nf = 0; nf < 4; nf++)
                    acc[mf][nf] = MF(af[mf], bfv[nf], acc[mf][nf]);
        }
        __syncthreads();
    }
    const float dn = 0.35355339059327373f;
    const int sel = by >> 2;        // 0=q,1=k,2=v
    float* st = (float*)smem;       // [64][130]
    for (int half = 0; half < 2; half++) {
        __syncthreads();
        if ((wave >> 1) == half) {
            #pragma unroll
            for (int mf = 0; mf < 4; mf++) {
                int lr = mf * 16 + (lane >> 4) * 4;
                #pragma unroll
                for (int nf = 0; nf < 4; nf++) {
                    int col = wn + nf * 16 + fr;
                    #pragma unroll
                    for (int r = 0; r < 4; r++)
                        st[(lr + r) * 130 + col] = acc[mf][nf][r];
                }
            }
        }
        __syncthreads();
        int grow = m0 + half * 64 + (tid >> 2);
        if (sel < 2) {
            int hl = (tid >> 1) & 1, e0 = (tid & 1) * 32;
            int h = (by & 3) * 2 + hl;
            alignas(16) u16 hbuf[32], lbuf[32];
            float ss = 0.f;
            #pragma unroll
            for (int q = 0; q < 32; q++) {
                float v = dn * st[(tid >> 2) * 130 + hl * 64 + e0 + q];
                ss += v * v;
                u16 hh = f2bf(v); hbuf[q] = hh; lbuf[q] = f2bf(v - bf2f(hh));
            }
            ss += __shfl_xor(ss, 1);
            if ((tid & 1) == 0)
                diagb[(size_t)sel * 65536 + grow * 8 + h] = 0.5f * ss;
            u16* d = qs + (size_t)sel * 8388608 + (size_t)grow * 1024 + h * 128 + e0;
            #pragma unroll
            for (int q = 0; q < 4; q++) *(uint4*)(d + q * 8) = *(uint4*)&hbuf[q * 8];
            #pragma unroll
            for (int q = 0; q < 4; q++) *(uint4*)(d + 64 + q * 8) = *(uint4*)&lbuf[q * 8];
        } else {
            int e0 = (tid & 3) * 32;
            int colbase = (by & 3) * 128 + e0;
            alignas(16) u16 hbuf[32], lbuf[32];
            #pragma unroll
            for (int q = 0; q < 32; q++) {
                float v = st[(tid >> 2) * 130 + e0 + q];
                u16 hh = f2bf(v); hbuf[q] = hh; lbuf[q] = f2bf(v - bf2f(hh));
            }
            u16* dh = vpl + (size_t)grow * 512 + colbase;
            u16* dl = dh + 4194304;
            #pragma unroll
            for (int q = 0; q < 4; q++) *(uint4*)(dh + q * 8) = *(uint4*)&hbuf[q * 8];
            #pragma unroll
            for (int q = 0; q < 4; q++) *(uint4*)(dl + q * 8) = *(uint4*)&lbuf[q * 8];
        }
    }
}

// ---------- merged dd GEMM, K=128 ([hi|lo] x [hi|hi]), 64x256 per head, grid (128,1,16) ----------
// z<8: q path h=z (fused feat, row max) -> phiQ ; z>=8: k path h=z-8 (split ddk + blockmax)
__global__ __launch_bounds__(256, 3)
void dd_gemm(const u16* __restrict__ Aq, const u16* __restrict__ Ak,
             const u16* __restrict__ Bp,
             const float* __restrict__ diagb, u32* __restrict__ gmax,
             u16* __restrict__ phiQ, u16* __restrict__ ddkhi, u16* __restrict__ ddklo)
{
    __shared__ char sm_[42240];
    char* As = sm_;                       // [64][64] u16 (8K, linear gload dest)
    char* Bs = sm_ + 8192;                // [256][64] u16 (32K, linear gload dest)
    float* red  = (float*)(sm_ + 40960);  // [64][4]
    float* srow = (float*)(sm_ + 41984);  // [64]
    const int isq = (blockIdx.z < 8);
    const int h = isq ? blockIdx.z : (blockIdx.z - 8);
    const int m0 = blockIdx.x * 64;
    const u16* Ag = (isq ? Aq : Ak) + (size_t)m0 * 1024 + h * 128;
    const int tid = threadIdx.x, lane = tid & 63, wave = tid >> 6;
    const int wn = wave * 64;
    const int fr = lane & 15, fk = (lane >> 4) * 8;
    const int lr8 = lane >> 3;
    const int cE = ((lane & 7) ^ lr8) << 3;
    f32x4 acc[4][4] = {};
    for (int k0 = 0; k0 < 128; k0 += 64) {
        #pragma unroll
        for (int t = 0; t < 2; t++) {
            int i = wave * 2 + t;
            int r = (i << 3) + lr8;
            gload16(Ag + (size_t)r * 1024 + k0 + cE, As + (i << 10));
        }
        #pragma unroll
        for (int t = 0; t < 8; t++) {
            int i = wave * 8 + t;
            int r = (i << 3) + lr8;
            gload16(Bp + (size_t)r * 128 + k0 + cE, Bs + (i << 10));
        }
        __syncthreads();
        #pragma unroll
        for (int ks = 0; ks < 2; ks++) {
            bf16x8 af[4], bf4[4];
            #pragma unroll
            for (int mf = 0; mf < 4; mf++)
                af[mf] = *(bf16x8*)(As + swz(mf * 16 + fr, ks * 32 + fk, 64));
            #pragma unroll
            for (int nf = 0; nf < 4; nf++)
                bf4[nf] = *(bf16x8*)(Bs + swz(wn + nf * 16 + fr, ks * 32 + fk, 64));
            #pragma unroll
            for (int mf = 0; mf < 4; mf++)
                #pragma unroll
                for (int nf = 0; nf < 4; nf++)
                    acc[mf][nf] = MF(af[mf], bf4[nf], acc[mf][nf]);
        }
        __syncthreads();
    }

    if (!isq) {
        float mx = -1e30f;
        #pragma unroll
        for (int mf = 0; mf < 4; mf++)
            #pragma unroll
            for (int nf = 0; nf < 4; nf++)
                #pragma unroll
                for (int r = 0; r < 4; r++) mx = fmaxf(mx, acc[mf][nf][r]);
        mx = wave_max(mx);
        __syncthreads();
        if (lane == 0) red[wave] = mx;
        __syncthreads();
        if (tid == 0) {
            float m4 = fmaxf(fmaxf(red[0], red[1]), fmaxf(red[2], red[3]));
            u32 u = __float_as_uint(m4);
            u32 key = (u & 0x80000000u) ? ~u : (u | 0x80000000u);
            atomicMax(gmax, key);
        }
    } else {
        float rm[4][4];
        #pragma unroll
        for (int mf = 0; mf < 4; mf++)
            #pragma unroll
            for (int r = 0; r < 4; r++) {
                float m = acc[mf][0][r];
                m = fmaxf(m, acc[mf][1][r]);
                m = fmaxf(m, acc[mf][2][r]);
                m = fmaxf(m, acc[mf][3][r]);
                #pragma unroll
                for (int o = 1; o < 16; o <<= 1) m = fmaxf(m, __shfl_xor(m, o));
                rm[mf][r] = m;
            }
        __syncthreads();
        if ((lane & 15) == 0) {
            #pragma unroll
            for (int mf = 0; mf < 4; mf++)
                #pragma unroll
                for (int r = 0; r < 4; r++)
                    red[(mf * 16 + (lane >> 4) * 4 + r) * 4 + wave] = rm[mf][r];
        }
        __syncthreads();
        if (tid < 64) {
            float m4 = fmaxf(fmaxf(red[tid * 4], red[tid * 4 + 1]),
                             fmaxf(red[tid * 4 + 2], red[tid * 4 + 3]));
            srow[tid] = m4 + diagb[(size_t)(m0 + tid) * 8 + h];
        }
    }
    // staging + dense writes
    u16* stg = (u16*)sm_;    // [64][264]
    const int NP = isq ? 1 : 2;
    for (int pl = 0; pl < NP; pl++) {
        __syncthreads();
        #pragma unroll
        for (int mf = 0; mf < 4; mf++)
            #pragma unroll
            for (int r = 0; r < 4; r++) {
                int row = mf * 16 + (lane >> 4) * 4 + r;
                #pragma unroll
                for (int nf = 0; nf < 4; nf++) {
                    float v = acc[mf][nf][r];
                    u16 o;
                    if (isq) {
                        o = f2bf(0.0625f * (expf(v - srow[row]) + 1e-4f));
                    } else {
                        u16 hh = f2bf(v);
                        o = pl ? f2bf(v - bf2f(hh)) : hh;
                    }
                    stg[row * 264 + wn + nf * 16 + fr] = o;
                }
            }
        __syncthreads();
        int lr = tid >> 2, c0 = (tid & 3) * 64;
        u16* base = isq ? phiQ : (pl ? ddklo : ddkhi);
        u16* dst = base + (size_t)(m0 + lr) * 2048 + h * 256 + c0;
        #pragma unroll
        for (int q = 0; q < 8; q++)
            *(uint4*)(dst + q * 8) = *(uint4*)(stg + lr * 264 + c0 + q * 8);
    }
}

// ---------- fused transpose_k + feat: phiK(in place over hi) + phiKT ----------
__global__ __launch_bounds__(256)
void transpose_k_feat(const u16* __restrict__ hi, const u16* __restrict__ lo,
                      const float* __restrict__ diagb, const u32* __restrict__ gmaxkey,
                      u16* __restrict__ phiK, u16* __restrict__ phiKT)
{
    __shared__ u16 tr[64 * 136];
    u32 key = *gmaxkey;
    u32 ub = (key & 0x80000000u) ? (key & 0x7fffffffu) : ~key;
    const float mg = __uint_as_float(ub);
    const int gc = blockIdx.x, c = gc & 31, bh = gc >> 5, b = bh >> 3, h = bh & 7;
    const int row0 = b * 4096 + c * 128;
    const u16* srcH = hi + (size_t)row0 * 2048 + h * 256;
    const u16* srcL = lo + (size_t)row0 * 2048 + h * 256;
    u16* dstR = phiK + (size_t)row0 * 2048 + h * 256;
    u16* dstT = phiKT + (size_t)gc * 32768;
    const int tid = threadIdx.x;
    for (int f0 = 0; f0 < 256; f0 += 64) {
        #pragma unroll
        for (int j = 0; j < 4; j++) {
            int ci = tid + j * 256; int r = ci >> 3, ff = (ci & 7) * 8;
            bf16x8 wh = *(const bf16x8*)(srcH + (size_t)r * 2048 + f0 + ff);
            bf16x8 wl = *(const bf16x8*)(srcL + (size_t)r * 2048 + f0 + ff);
            float s = mg + diagb[65536 + (size_t)(row0 + r) * 8 + h];
            alignas(16) u16 ob[8];
            #pragma unroll
            for (int q = 0; q < 8; q++) {
                float dd = bf2f((u16)wh[q]) + bf2f((u16)wl[q]);
                u16 pv = f2bf(0.0625f * (expf(dd - s) + 1e-4f));
                ob[q] = pv;
                tr[(ff + q) * 136 + r] = pv;
            }
            *(uint4*)(dstR + (size_t)r * 2048 + f0 + ff) = *(uint4*)ob;
        }
        __syncthreads();
        {
            int f = tid >> 2, r0 = (tid & 3) * 32;
            uint4 a0 = *(uint4*)&tr[f * 136 + r0];
            uint4 a1 = *(uint4*)&tr[f * 136 + r0 + 8];
            uint4 a2 = *(uint4*)&tr[f * 136 + r0 + 16];
            uint4 a3 = *(uint4*)&tr[f * 136 + r0 + 24];
            u16* dp = dstT + (size_t)(f0 + f) * 128 + r0;
            *(uint4*)dp = a0; *(uint4*)(dp + 8) = a1;
            *(uint4*)(dp + 16) = a2; *(uint4*)(dp + 24) = a3;
        }
        __syncthreads();
    }
}

// ---------- final projection GEMM: plain bf16, K=512, global_load_lds staging ----------
__global__ __launch_bounds__(256, 3)
void proj_gemm(const u16* __restrict__ A, const u16* __restrict__ B,
               float* __restrict__ C, const float* __restrict__ bias)
{
    __shared__ char smem[34816];
    char* As = smem; char* Bs = smem + 16384;
    const int m0 = blockIdx.x * 128, n0 = blockIdx.y * 128;
    const int tid = threadIdx.x, lane = tid & 63, wave = tid >> 6;
    const int wm = (wave >> 1) * 64, wn = (wave & 1) * 64;
    const int fr = lane & 15, fk = (lane >> 4) * 8;
    const int lr8 = lane >> 3;
    const int cE = ((lane & 7) ^ lr8) << 3;
    f32x4 acc[4][4] = {};
    for (int k0 = 0; k0 < 512; k0 += 64) {
        #pragma unroll
        for (int t = 0; t < 4; t++) {
            int i = wave * 4 + t;
            int r = (i << 3) + lr8;
            gload16(A + (size_t)(m0 + r) * 512 + k0 + cE, As + (i << 10));
            gload16(B + (size_t)(n0 + r) * 512 + k0 + cE, Bs + (i << 10));
        }
        __syncthreads();
        #pragma unroll
        for (int ks = 0; ks < 2; ks++) {
            bf16x8 af[4], bfv[4];
            #pragma unroll
            for (int mf = 0; mf < 4; mf++)
                af[mf] = *(bf16x8*)(As + swz(wm + mf * 16 + fr, ks * 32 + fk, 64));
            #pragma unroll
            for (int nf = 0; nf < 4; nf++)
                bfv[nf] = *(bf16x8*)(Bs + swz(wn + nf * 16 + fr, ks * 32 + fk, 64));
            #pragma unroll
            for (int mf = 0; mf < 4; mf++)
                #pragma unroll
                for (int nf = 0; nf < 4; nf++)
                    acc[mf][nf] = MF(af[mf], bfv[nf], acc[mf][nf]);
        }
        __syncthreads();
    }
    float* st = (float*)smem;   // [64][130]
    for (int half = 0; half < 2; half++) {
        __syncthreads();
        if ((wave >> 1) == half) {
            #pragma unroll
            for (int mf = 0; mf < 4; mf++) {
                int lr = mf * 16 + (lane >> 4) * 4;
                #pragma unroll
                for (int nf = 0; nf < 4; nf++) {
                    int col = wn + nf * 16 + fr;
                    #pragma unroll
                    for (int r = 0; r < 4; r++)
                        st[(lr + r) * 130 + col] = acc[mf][nf][r];
                }
            }
        }
        __syncthreads();
        int lr = tid >> 2, c0 = (tid & 3) * 32;
        int grow = m0 + half * 64 + lr;
        float* dst = C + (size_t)grow * 512 + n0 + c0;
        #pragma unroll
        for (int q = 0; q < 8; q++) {
            float4 v;
            v.x = st[lr * 130 + c0 + q * 4 + 0] + bias[n0 + c0 + q * 4 + 0];
            v.y = st[lr * 130 + c0 + q * 4 + 1] + bias[n0 + c0 + q * 4 + 1];
            v.z = st[lr * 130 + c0 + q * 4 + 2] + bias[n0 + c0 + q * 4 + 2];
            v.w = st[lr * 130 + c0 + q * 4 + 3] + bias[n0 + c0 + q * 4 + 3];
            *(float4*)(dst + q * 4) = v;
        }
    }
}

// ---------- transpose v planes per chunk -> Vt[gc][pl][e=64][r=128] ----------
__global__ __launch_bounds__(256)
void transpose_v(const u16* __restrict__ vpl, u16* __restrict__ Vt)
{
    __shared__ u16 tr[64 * 136];
    const int gc = blockIdx.x, c = gc & 31, bh = gc >> 5, b = bh >> 3, h = bh & 7;
    const int row0 = b * 4096 + c * 128;
    u16* dstb = Vt + (size_t)gc * 16384;
    const int tid = threadIdx.x;
    for (int pl = 0; pl < 2; pl++) {
        if (pl) __syncthreads();
        const u16* src = vpl + (size_t)pl * 4194304 + (size_t)row0 * 512 + h * 64;
        #pragma unroll
        for (int j = 0; j < 8; j++) {
            int ci = tid + j * 256; int r = ci >> 4, e = (ci & 15) * 4;
            ushort4 v = *(const ushort4*)(src + (size_t)r * 512 + e);
            tr[(e + 0) * 136 + r] = v.x;
            tr[(e + 1) * 136 + r] = v.y;
            tr[(e + 2) * 136 + r] = v.z;
            tr[(e + 3) * 136 + r] = v.w;
        }
        __syncthreads();
        int e = tid >> 2, r0 = (tid & 3) * 32;
        u16* dst = dstb + pl * 8192;
        #pragma unroll
        for (int q = 0; q < 4; q++) {
            uint4 a = *(uint4*)&tr[e * 136 + r0 + q * 8];
            *(uint4*)(dst + (size_t)e * 128 + r0 + q * 8) = a;
        }
    }
}

// ---------- Pass A: S = K^T (Vhi+Vlo), Z = colsum(K), gload staging ----------
__global__ __launch_bounds__(256)
void chunk_sums_mfma(const u16* __restrict__ phiKT, const u16* __restrict__ Vt,
                     float* __restrict__ sbuf, float* __restrict__ zbuf)
{
    __shared__ char smem[49152];
    char* bufA = smem;            // [256 f][64 r]
    char* bufBh = smem + 32768;   // [64 e][64 r]
    char* bufBl = smem + 40960;
    const int gc = blockIdx.x;
    const u16* Ag = phiKT + (size_t)gc * 32768;
    const u16* Bg = Vt + (size_t)gc * 16384;
    const int tid = threadIdx.x, lane = tid & 63, wave = tid >> 6;
    const int fr = lane & 15, fk = (lane >> 4) * 8;
    const int lr8 = lane >> 3;
    const int cE = ((lane & 7) ^ lr8) << 3;
    {
        float z = 0.f;
        const u16* zp = Ag + (size_t)tid * 128;
        #pragma unroll
        for (int j = 0; j < 16; j++) {
            bf16x8 w = *(const bf16x8*)(zp + j * 8);
            #pragma unroll
            for (int q = 0; q < 8; q++) z += bf2f((u16)w[q]);
        }
        zbuf[(size_t)gc * 256 + tid] = z;
    }
    f32x4 acc[4][4] = {};
    for (int kh = 0; kh < 2; kh++) {
        #pragma unroll
        for (int t = 0; t < 8; t++) {
            int i = wave * 8 + t;
            int f = (i << 3) + lr8;
            gload16(Ag + (size_t)f * 128 + kh * 64 + cE, bufA + (i << 10));
        }
        #pragma unroll
        for (int t = 0; t < 2; t++) {
            int i = wave * 2 + t;
            int e = (i << 3) + lr8;
            gload16(Bg + (size_t)e * 128 + kh * 64 + cE, bufBh + (i << 10));
            gload16(Bg + 8192 + (size_t)e * 128 + kh * 64 + cE, bufBl + (i << 10));
        }
        __syncthreads();
        #pragma unroll
        for (int ks = 0; ks < 2; ks++) {
            bf16x8 af[4], bh4[4], bl4[4];
            #pragma unroll
            for (int mf = 0; mf < 4; mf++)
                af[mf] = *(bf16x8*)(bufA + swz(wave * 64 + mf * 16 + fr, ks * 32 + fk, 64));
            #pragma unroll
            for (int nf = 0; nf < 4; nf++) {
                bh4[nf] = *(bf16x8*)(bufBh + swz(nf * 16 + fr, ks * 32 + fk, 64));
                bl4[nf] = *(bf16x8*)(bufBl + swz(nf * 16 + fr, ks * 32 + fk, 64));
            }
            #pragma unroll
            for (int mf = 0; mf < 4; mf++)
                #pragma unroll
                for (int nf = 0; nf < 4; nf++) {
                    acc[mf][nf] = MF(af[mf], bh4[nf], acc[mf][nf]);
                    acc[mf][nf] = MF(af[mf], bl4[nf], acc[mf][nf]);
                }
        }
        __syncthreads();
    }
    #pragma unroll
    for (int mf = 0; mf < 4; mf++) {
        int fb = wave * 64 + mf * 16 + (lane >> 4) * 4;
        #pragma unroll
        for (int nf = 0; nf < 4; nf++) {
            int e = nf * 16 + fr;
            #pragma unroll
            for (int r = 0; r < 4; r++)
                sbuf[(size_t)gc * 16384 + (size_t)(fb + r) * 64 + e] = acc[mf][nf][r];
        }
    }
}

// ---------- Pass B: exclusive prefix, 256 blocks (16 bh x 16 f-slabs) ----------
__global__ __launch_bounds__(256)
void prefix_scan(const float* __restrict__ sbuf, const float* __restrict__ zbuf,
                 u16* __restrict__ SpT, float* __restrict__ Zp,
                 float* __restrict__ outZ, float* __restrict__ outS)
{
    __shared__ float trans[64 * 17];
    const int bh = blockIdx.x >> 4, f0 = (blockIdx.x & 15) * 16;
    const int tid = threadIdx.x;
    const int e_ = tid >> 2, fl = (tid & 3) * 4;
    float run[4] = {0.f, 0.f, 0.f, 0.f};
    float zrun = 0.f;
    for (int c = 0; c < 32; c++) {
        const int gc = bh * 32 + c;
        const float* base = sbuf + (size_t)gc * 16384 + f0 * 64;
        float v[4];
        #pragma unroll
        for (int i = 0; i < 4; i++) v[i] = base[tid + i * 256];
        #pragma unroll
        for (int i = 0; i < 4; i++) {
            int idx = tid + i * 256;
            trans[(idx & 63) * 17 + (idx >> 6)] = run[i];
        }
        float zv = 0.f;
        if (tid < 16) zv = zbuf[(size_t)gc * 256 + f0 + tid];
        __syncthreads();
        {
            alignas(8) u16 hb[4], lb[4];
            #pragma unroll
            for (int q = 0; q < 4; q++) {
                float vv = trans[e_ * 17 + fl + q];
                u16 hh = f2bf(vv); hb[q] = hh; lb[q] = f2bf(vv - bf2f(hh));
            }
            u16* dh = SpT + (size_t)gc * 32768 + e_ * 256 + f0 + fl;
            *(uint2*)dh = *(uint2*)hb;
            *(uint2*)(dh + 16384) = *(uint2*)lb;
        }
        if (tid < 16) { Zp[(size_t)gc * 256 + f0 + tid] = zrun; zrun += zv; }
        #pragma unroll
        for (int i = 0; i < 4; i++) run[i] += v[i];
        __syncthreads();
    }
    #pragma unroll
    for (int i = 0; i < 4; i++)
        outS[(size_t)bh * 16384 + f0 * 64 + tid + i * 256] = run[i];
    if (tid < 16) outZ[bh * 256 + f0 + tid] = zrun;
}

// ---------- Pass C: aouts(plain bf16) = Dinv*(Q@Sprev + tril(QK^T)@V), gload staging ----------
__global__ __launch_bounds__(256)
void chunk_out_mfma(const u16* __restrict__ phiQ, const u16* __restrict__ phiK,
                    const u16* __restrict__ Vt, const u16* __restrict__ SpT,
                    const float* __restrict__ Zp, u16* __restrict__ aouts)
{
    extern __shared__ char sm[];
    char* bufQ = sm;             // [128][64] Q-slab
    char* bufK = sm + 16384;     // [128][64] K-slab ; later V_hi [64][128] swz
    char* bufA = sm + 32768;     // f0 loop: Sp_hi @+0, Sp_lo @+8192 ; after: A [128][128] swz
    float* Dl = (float*)(sm + 65536);    // [128]
    float* Zl = (float*)(sm + 66048);    // [64]
    const int gc = blockIdx.x, c = gc & 31, bh = gc >> 5, b = bh >> 3, h = bh & 7;
    const int row0 = b * 4096 + c * 128;
    const u16* Qg = phiQ + (size_t)row0 * 2048 + h * 256;
    const u16* Kg = phiK + (size_t)row0 * 2048 + h * 256;
    const u16* Vg = Vt + (size_t)gc * 16384;
    const u16* Sg = SpT + (size_t)gc * 32768;
    const float* Zg = Zp + (size_t)gc * 256;
    const int tid = threadIdx.x, lane = tid & 63, wave = tid >> 6;
    const int fr = lane & 15, fk = (lane >> 4) * 8;
    const int dr = tid >> 1, dc = (tid & 1) * 32;
    const int lr8 = lane >> 3;
    const int cE = ((lane & 7) ^ lr8) << 3;

    f32x4 acc2[2][8] = {};
    f32x4 acc1[2][4] = {};
    float dotZ = 0.f, sumQ = 0.f;

    for (int f0 = 0; f0 < 256; f0 += 64) {
        #pragma unroll
        for (int t = 0; t < 4; t++) {
            int i = wave * 4 + t;
            int r = (i << 3) + lr8;
            gload16(Qg + (size_t)r * 2048 + f0 + cE, bufQ + (i << 10));
            gload16(Kg + (size_t)r * 2048 + f0 + cE, bufK + (i << 10));
        }
        #pragma unroll
        for (int t = 0; t < 2; t++) {
            int i = wave * 2 + t;
            int e = (i << 3) + lr8;
            gload16(Sg + (size_t)e * 256 + f0 + cE, bufA + (i << 10));
            gload16(Sg + 16384 + (size_t)e * 256 + f0 + cE, bufA + 8192 + (i << 10));
        }
        if (tid < 64) Zl[tid] = Zg[f0 + tid];
        __syncthreads();
        #pragma unroll
        for (int ks = 0; ks < 2; ks++) {
            bf16x8 af[2];
            af[0] = *(bf16x8*)(bufQ + swz(wave * 32 + fr, ks * 32 + fk, 64));
            af[1] = *(bf16x8*)(bufQ + swz(wave * 32 + 16 + fr, ks * 32 + fk, 64));
            #pragma unroll
            for (int nf = 0; nf < 8; nf++) {
                bf16x8 bv = *(bf16x8*)(bufK + swz(nf * 16 + fr, ks * 32 + fk, 64));
                acc2[0][nf] = MF(af[0], bv, acc2[0][nf]);
                acc2[1][nf] = MF(af[1], bv, acc2[1][nf]);
            }
            #pragma unroll
            for (int nf = 0; nf < 4; nf++) {
                bf16x8 bvh = *(bf16x8*)(bufA + swz(nf * 16 + fr, ks * 32 + fk, 64));
                bf16x8 bvl = *(bf16x8*)(bufA + 8192 + swz(nf * 16 + fr, ks * 32 + fk, 64));
                acc1[0][nf] = MF(af[0], bvh, acc1[0][nf]);
                acc1[1][nf] = MF(af[1], bvh, acc1[1][nf]);
                acc1[0][nf] = MF(af[0], bvl, acc1[0][nf]);
                acc1[1][nf] = MF(af[1], bvl, acc1[1][nf]);
            }
        }
        #pragma unroll
        for (int jj = 0; jj < 4; jj++) {
            bf16x8 qv = *(bf16x8*)(bufQ + swz(dr, dc + jj * 8, 64));
            f32x4 z0 = *(f32x4*)(Zl + dc + jj * 8);
            f32x4 z1 = *(f32x4*)(Zl + dc + jj * 8 + 4);
            #pragma unroll
            for (int q = 0; q < 8; q++) {
                float qf = bf2f((u16)qv[q]);
                sumQ += qf;
                dotZ += qf * (q < 4 ? z0[q] : z1[q - 4]);
            }
        }
        __syncthreads();
    }
    float4 vvh[4];
    #pragma unroll
    for (int j = 0; j < 4; j++) {
        int ci = tid + j * 256; int e = ci >> 4, cc = (ci & 15) * 8;
        vvh[j] = *(const float4*)(Vg + (size_t)e * 128 + cc);
    }
    #pragma unroll
    for (int mf = 0; mf < 2; mf++) {
        int rb = wave * 32 + mf * 16 + (lane >> 4) * 4;
        #pragma unroll
        for (int nf = 0; nf < 8; nf++) {
            int col = nf * 16 + fr;
            #pragma unroll
            for (int r = 0; r < 4; r++) {
                float v = (col <= rb + r) ? acc2[mf][nf][r] : 0.f;
                *(u16*)(bufA + swz(rb + r, col, 128)) = f2bf(v);
            }
        }
    }
    #pragma unroll
    for (int j = 0; j < 4; j++) {
        int ci = tid + j * 256; int e = ci >> 4, cc = (ci & 15) * 8;
        *(float4*)(bufK + swz(e, cc, 128)) = vvh[j];
    }
    __syncthreads();
    {
        const int dcA = (tid & 1) * 64;
        float rs = 0.f;
        #pragma unroll
        for (int jj = 0; jj < 8; jj++) {
            bf16x8 av = *(bf16x8*)(bufA + swz(dr, dcA + jj * 8, 128));
            #pragma unroll
            for (int q = 0; q < 8; q++) rs += bf2f((u16)av[q]);
        }
        float tot = rs + dotZ + 1e-6f * sumQ;
        tot += __shfl_xor(tot, 1);
        if ((tid & 1) == 0) Dl[dr] = tot;
    }
    #pragma unroll
    for (int ks = 0; ks < 4; ks++) {
        bf16x8 af[2];
        af[0] = *(bf16x8*)(bufA + swz(wave * 32 + fr, ks * 32 + fk, 128));
        af[1] = *(bf16x8*)(bufA + swz(wave * 32 + 16 + fr, ks * 32 + fk, 128));
        #pragma unroll
        for (int nf = 0; nf < 4; nf++) {
            bf16x8 bvh = *(bf16x8*)(bufK + swz(nf * 16 + fr, ks * 32 + fk, 128));
            acc1[0][nf] = MF(af[0], bvh, acc1[0][nf]);
            acc1[1][nf] = MF(af[1], bvh, acc1[1][nf]);
        }
    }
    __syncthreads();
    float* st = (float*)sm;   // [128][65]
    #pragma unroll
    for (int mf = 0; mf < 2; mf++) {
        int rb = wave * 32 + mf * 16 + (lane >> 4) * 4;
        #pragma unroll
        for (int r = 0; r < 4; r++) {
            float dinv = 1.f / Dl[rb + r];
            #pragma unroll
            for (int nf = 0; nf < 4; nf++)
                st[(rb + r) * 65 + nf * 16 + fr] = acc1[mf][nf][r] * dinv;
        }
    }
    __syncthreads();
    {
        int lr = tid >> 1, e0 = (tid & 1) * 32;
        alignas(16) u16 hb[32];
        #pragma unroll
        for (int q = 0; q < 32; q++) hb[q] = f2bf(st[lr * 65 + e0 + q]);
        u16* d = aouts + (size_t)(row0 + lr) * 512 + h * 64 + e0;
        #pragma unroll
        for (int q = 0; q < 4; q++) *(uint4*)(d + q * 8) = *(uint4*)&hb[q * 8];
    }
}

extern "C" void kernel_launch(void* const* d_in, const int* in_sizes, int n_in,
                              void* d_out, int out_size, void* d_ws, size_t ws_size,
                              hipStream_t stream)
{
    const float* x    = (const float*)d_in[0];
    const float* Wq   = (const float*)d_in[1];
    const float* Wk   = (const float*)d_in[2];
    const float* Wv   = (const float*)d_in[3];
    const float* Wo   = (const float*)d_in[4];
    const float* bo   = (const float*)d_in[5];
    const float* proj = (const float*)d_in[6];
    float* out = (float*)d_out;
    float* ws = (float*)d_ws;

    // layout (float offsets)
    u16*   vpl   = (u16*)ws;                    // [2][8192][512] u16
    float* diagb = ws + 4194304;                // [2][8192][8] f32
    u16*   phi   = (u16*)(ws + 12582912);       // [16384][2048] u16
    u16*   ddklo = (u16*)(ws + 29360128);       // [8192][2048] u16 (dead after transpose_k_feat)
    u16*   Vtb   = (u16*)(ws + 37748736);       // [512][2][64][128] u16
    float* sbuf  = ws + 41943040;               // 512*16384 f32
    u16*   qs    = (u16*)(ws + 41943040);       // [2][8192][1024] u16 (dead after dd_gemm)
    u16*   phiKT = (u16*)(ws + 50331648);       // 512*32768 u16 (dead after chunk_sums)
    u16*   SpT   = (u16*)(ws + 50331648);       //   overlay: written by prefix_scan AFTER chunk_sums
    u16*   xs    = (u16*)(ws + 58720256);       // [8192][1536] u16
    u16*   aouts = xs;                          //   overlay: plain [8192][512] u16
    u16*   Wqkvs = (u16*)(ws + 65011712);       // [1536][1536] u16
    float* zbuf  = ws + 65142784;               //   overlay Wqkvs (dead after qkv_gemm)
    float* Zp    = ws + 65273856;
    u32*   gmax  = (u32*)(ws + 65404928);
    u16*   Wos   = (u16*)(ws + 66191360);       // plain [512][512] u16
    u16*   projs = (u16*)(ws + 66584576);       // [256][128] u16 [hi|hi]

    float* outO = out;                 // [2,4096,512]
    float* outZ = out + 4194304;       // [2,8,256]
    float* outS = out + 4198400;       // [2,8,256,64]

    dim3 blk(256);

    // converts
    conv_split<false><<<2048, blk, 0, stream>>>(x, xs, 512, 1048576L, 1.f);
    conv_w3<<<768, blk, 0, stream>>>(Wq, Wk, Wv, Wqkvs);
    conv_plain<<<64, blk, 0, stream>>>(Wo, Wos, 65536L);
    conv_projdup<<<16, blk, 0, stream>>>(proj, projs);
    // fused QKV projection (128x128 tiles, global_load_lds staging)
    qkv_gemm<<<dim3(64, 12), blk, 0, stream>>>(xs, Wqkvs, qs, diagb, vpl);
    hipMemsetAsync(gmax, 0, 4, stream);
    // merged dd GEMM (K=128, q/k split x proj plain): q (z<8) fused feat; k (z>=8) split ddk + blockmax
    const u16* ksplit = qs + 8388608;
    u16* ddkhi = phi + (size_t)8192 * 2048;     // phiK region (in-place exp in transpose)
    dd_gemm<<<dim3(128, 1, 16), blk, 0, stream>>>(qs, ksplit, projs, diagb, gmax,
                                                  phi, ddkhi, ddklo);
    // fused k feature map + transpose: phiK in place + phiKT
    transpose_k_feat<<<512, blk, 0, stream>>>(ddkhi, ddklo, diagb, gmax, ddkhi, phiKT);
    transpose_v<<<512, blk, 0, stream>>>(vpl, Vtb);
    // chunked linear attention
    chunk_sums_mfma<<<512, blk, 0, stream>>>(phiKT, Vtb, sbuf, zbuf);
    prefix_scan<<<256, blk, 0, stream>>>(sbuf, zbuf, SpT, Zp, outZ, outS);
    hipFuncSetAttribute((const void*)chunk_out_mfma,
                        hipFuncAttributeMaxDynamicSharedMemorySize, 66304);
    chunk_out_mfma<<<512, blk, 66304, stream>>>(phi, ddkhi, Vtb, SpT, Zp, aouts);
    // final projection (plain bf16, K=512, global_load_lds staging)
    proj_gemm<<<dim3(64, 4), blk, 0, stream>>>(aouts, Wos, outO, bo);
}

// Round 17
// 325.313 us; speedup vs baseline: 1.0530x; 1.0530x over previous
//
#include <hip/hip_runtime.h>

#define NH 8
#define DH 64
#define FF 256
#define CH 128

typedef unsigned short u16;
typedef unsigned int u32;
typedef __attribute__((ext_vector_type(8))) short bf16x8;
typedef __attribute__((ext_vector_type(4))) float f32x4;

__device__ __forceinline__ u16 f2bf(float f) {
    u32 u = __float_as_uint(f);
    return (u16)((u + 0x7fffu + ((u >> 16) & 1u)) >> 16);
}
__device__ __forceinline__ float bf2f(u16 h) { return __uint_as_float(((u32)h) << 16); }
__device__ __forceinline__ u32 pk(u16 a, u16 b) { return (u32)a | ((u32)b << 16); }
__device__ __forceinline__ int swz(int row, int col, int ld) {
    return ((row * ld + col) * 2) ^ ((row & 7) << 4);
}
__device__ __forceinline__ f32x4 MF(bf16x8 a, bf16x8 b, f32x4 c) {
    return __builtin_amdgcn_mfma_f32_16x16x32_bf16(a, b, c, 0, 0, 0);
}
__device__ __forceinline__ float wave_max(float v) {
    #pragma unroll
    for (int o = 32; o; o >>= 1) v = fmaxf(v, __shfl_xor(v, o));
    return v;
}
// async global->LDS, 16B/lane; dest = uniform base + lane*16 (HW)
__device__ __forceinline__ void gload16(const void* g, void* l) {
    __builtin_amdgcn_global_load_lds(
        (const __attribute__((address_space(1))) void*)g,
        (__attribute__((address_space(3))) void*)l, 16, 0, 0);
}

// ---------- split-bf16 convert: A:[hi|hi|lo]  B:[hi|lo|hi] ----------
template<bool ISB>
__global__ __launch_bounds__(256)
void conv_split(const float* __restrict__ src, u16* __restrict__ dst,
                int K, long total4, float scale)
{
    const int K4 = K >> 2;
    for (long i = (long)blockIdx.x * 256 + threadIdx.x; i < total4;
         i += (long)gridDim.x * 256) {
        long row = i / K4;
        int c = (int)(i - row * K4) * 4;
        float4 v = ((const float4*)src)[i];
        float a0 = v.x * scale, a1 = v.y * scale, a2 = v.z * scale, a3 = v.w * scale;
        u16 h0 = f2bf(a0), h1 = f2bf(a1), h2 = f2bf(a2), h3 = f2bf(a3);
        u16 l0 = f2bf(a0 - bf2f(h0)), l1 = f2bf(a1 - bf2f(h1));
        u16 l2 = f2bf(a2 - bf2f(h2)), l3 = f2bf(a3 - bf2f(h3));
        uint2 hh; hh.x = pk(h0, h1); hh.y = pk(h2, h3);
        uint2 ll; ll.x = pk(l0, l1); ll.y = pk(l2, l3);
        u16* d = dst + row * (3L * K) + c;
        *(uint2*)d = hh;
        *(uint2*)(d + (ISB ? 2 * K : K)) = hh;
        *(uint2*)(d + (ISB ? K : 2 * K)) = ll;
    }
}

// ---------- plain bf16 convert ----------
__global__ __launch_bounds__(256)
void conv_plain(const float* __restrict__ src, u16* __restrict__ dst, long total4)
{
    for (long i = (long)blockIdx.x * 256 + threadIdx.x; i < total4;
         i += (long)gridDim.x * 256) {
        float4 v = ((const float4*)src)[i];
        ushort4 o;
        o.x = f2bf(v.x); o.y = f2bf(v.y); o.z = f2bf(v.z); o.w = f2bf(v.w);
        ((ushort4*)dst)[i] = o;
    }
}

// ---------- fused QKV GEMM, 128x128 tile, global_load_lds staging ----------
__global__ __launch_bounds__(256, 3)
void qkv_gemm(const u16* __restrict__ A, const u16* __restrict__ B,
              u16* __restrict__ qs, float* __restrict__ diagb,
              u16* __restrict__ vpl)
{
    __shared__ char smem[34816];
    char* As = smem; char* Bs = smem + 16384;
    const int m0 = blockIdx.x * 128, by = blockIdx.y, n0 = by * 128;
    const int tid = threadIdx.x, lane = tid & 63, wave = tid >> 6;
    const int wm = (wave >> 1) * 64, wn = (wave & 1) * 64;
    const int fr = lane & 15, fk = (lane >> 4) * 8;
    const int lr8 = lane >> 3;
    const int cE = ((lane & 7) ^ lr8) << 3;
    f32x4 acc[4][4] = {};
    for (int k0 = 0; k0 < 1536; k0 += 64) {
        #pragma unroll
        for (int t = 0; t < 4; t++) {
            int i = wave * 4 + t;
            int r = (i << 3) + lr8;
            gload16(A + (size_t)(m0 + r) * 1536 + k0 + cE, As + (i << 10));
            gload16(B + (size_t)(n0 + r) * 1536 + k0 + cE, Bs + (i << 10));
        }
        __syncthreads();
        #pragma unroll
        for (int ks = 0; ks < 2; ks++) {
            bf16x8 af[4], bfv[4];
            #pragma unroll
            for (int mf = 0; mf < 4; mf++)
                af[mf] = *(bf16x8*)(As + swz(wm + mf * 16 + fr, ks * 32 + fk, 64));
            #pragma unroll
            for (int nf = 0; nf < 4; nf++)
                bfv[nf] = *(bf16x8*)(Bs + swz(wn + nf * 16 + fr, ks * 32 + fk, 64));
            #pragma unroll
            for (int mf = 0; mf < 4; mf++)
                #pragma unroll
                for (int nf = 0; nf < 4; nf++)
                    acc[mf][nf] = MF(af[mf], bfv[nf], acc[mf][nf]);
        }
        __syncthreads();
    }
    const float dn = 0.35355339059327373f;
    const int sel = by >> 2;        // 0=q,1=k,2=v
    float* st = (float*)smem;       // [64][130]
    for (int half = 0; half < 2; half++) {
        __syncthreads();
        if ((wave >> 1) == half) {
            #pragma unroll
            for (int mf = 0; mf < 4; mf++) {
                int lr = mf * 16 + (lane >> 4) * 4;
                #pragma unroll
                for (int nf = 0; nf < 4; nf++) {
                    int col = wn + nf * 16 + fr;
                    #pragma unroll
                    for (int r = 0; r < 4; r++)
                        st[(lr + r) * 130 + col] = acc[mf][nf][r];
                }
            }
        }
        __syncthreads();
        int grow = m0 + half * 64 + (tid >> 2);
        if (sel < 2) {
            int hl = (tid >> 1) & 1, e0 = (tid & 1) * 32;
            int h = (by & 3) * 2 + hl;
            alignas(16) u16 hbuf[32], lbuf[32];
            float ss = 0.f;
            #pragma unroll
            for (int q = 0; q < 32; q++) {
                float v = dn * st[(tid >> 2) * 130 + hl * 64 + e0 + q];
                ss += v * v;
                u16 hh = f2bf(v); hbuf[q] = hh; lbuf[q] = f2bf(v - bf2f(hh));
            }
            ss += __shfl_xor(ss, 1);
            if ((tid & 1) == 0)
                diagb[(size_t)sel * 65536 + grow * 8 + h] = 0.5f * ss;
            u16* d = qs + (size_t)sel * 12582912 + (size_t)grow * 1536 + h * 192 + e0;
            #pragma unroll
            for (int q = 0; q < 4; q++) *(uint4*)(d + q * 8) = *(uint4*)&hbuf[q * 8];
            #pragma unroll
            for (int q = 0; q < 4; q++) *(uint4*)(d + 64 + q * 8) = *(uint4*)&hbuf[q * 8];
            #pragma unroll
            for (int q = 0; q < 4; q++) *(uint4*)(d + 128 + q * 8) = *(uint4*)&lbuf[q * 8];
        } else {
            int e0 = (tid & 3) * 32;
            int colbase = (by & 3) * 128 + e0;
            alignas(16) u16 hbuf[32], lbuf[32];
            #pragma unroll
            for (int q = 0; q < 32; q++) {
                float v = st[(tid >> 2) * 130 + e0 + q];
                u16 hh = f2bf(v); hbuf[q] = hh; lbuf[q] = f2bf(v - bf2f(hh));
            }
            u16* dh = vpl + (size_t)grow * 512 + colbase;
            u16* dl = dh + 4194304;
            #pragma unroll
            for (int q = 0; q < 4; q++) *(uint4*)(dh + q * 8) = *(uint4*)&hbuf[q * 8];
            #pragma unroll
            for (int q = 0; q < 4; q++) *(uint4*)(dl + q * 8) = *(uint4*)&lbuf[q * 8];
        }
    }
}

// ---------- merged dd GEMM, 64x256 per head, grid (128,1,16), LDS 40960 -> 4 blk/CU ----------
// z<8: q path h=z (fused feat, row max) -> phiQ ; z>=8: k path h=z-8 (split ddk + blockmax)
__global__ __launch_bounds__(256, 4)
void dd_gemm(const u16* __restrict__ Aq, const u16* __restrict__ Ak,
             const u16* __restrict__ Bp,
             const float* __restrict__ diagb, u32* __restrict__ gmax,
             u16* __restrict__ phiQ, u16* __restrict__ ddkhi, u16* __restrict__ ddklo)
{
    __shared__ char sm_[40960];
    char* As = sm_;                       // [64][64] u16 (8K, linear gload dest; dead after K-loop)
    char* Bs = sm_ + 8192;                // [256][64] u16 (32K; dead after K-loop)
    float* red  = (float*)(sm_ + 34816);  // [64][4]  (epilogue only; above stg 33792B)
    float* srow = (float*)(sm_ + 35840);  // [64]
    const int isq = (blockIdx.z < 8);
    const int h = isq ? blockIdx.z : (blockIdx.z - 8);
    const int m0 = blockIdx.x * 64;
    const u16* Ag = (isq ? Aq : Ak) + (size_t)m0 * 1536 + h * 192;
    const int tid = threadIdx.x, lane = tid & 63, wave = tid >> 6;
    const int wn = wave * 64;
    const int fr = lane & 15, fk = (lane >> 4) * 8;
    const int lr8 = lane >> 3;
    const int cE = ((lane & 7) ^ lr8) << 3;
    f32x4 acc[4][4] = {};
    for (int k0 = 0; k0 < 192; k0 += 64) {
        #pragma unroll
        for (int t = 0; t < 2; t++) {
            int i = wave * 2 + t;
            int r = (i << 3) + lr8;
            gload16(Ag + (size_t)r * 1536 + k0 + cE, As + (i << 10));
        }
        #pragma unroll
        for (int t = 0; t < 8; t++) {
            int i = wave * 8 + t;
            int r = (i << 3) + lr8;
            gload16(Bp + (size_t)r * 192 + k0 + cE, Bs + (i << 10));
        }
        __syncthreads();
        #pragma unroll
        for (int ks = 0; ks < 2; ks++) {
            bf16x8 af[4], bf4[4];
            #pragma unroll
            for (int mf = 0; mf < 4; mf++)
                af[mf] = *(bf16x8*)(As + swz(mf * 16 + fr, ks * 32 + fk, 64));
            #pragma unroll
            for (int nf = 0; nf < 4; nf++)
                bf4[nf] = *(bf16x8*)(Bs + swz(wn + nf * 16 + fr, ks * 32 + fk, 64));
            #pragma unroll
            for (int mf = 0; mf < 4; mf++)
                #pragma unroll
                for (int nf = 0; nf < 4; nf++)
                    acc[mf][nf] = MF(af[mf], bf4[nf], acc[mf][nf]);
        }
        __syncthreads();
    }

    if (!isq) {
        float mx = -1e30f;
        #pragma unroll
        for (int mf = 0; mf < 4; mf++)
            #pragma unroll
            for (int nf = 0; nf < 4; nf++)
                #pragma unroll
                for (int r = 0; r < 4; r++) mx = fmaxf(mx, acc[mf][nf][r]);
        mx = wave_max(mx);
        __syncthreads();
        if (lane == 0) red[wave] = mx;
        __syncthreads();
        if (tid == 0) {
            float m4 = fmaxf(fmaxf(red[0], red[1]), fmaxf(red[2], red[3]));
            u32 u = __float_as_uint(m4);
            u32 key = (u & 0x80000000u) ? ~u : (u | 0x80000000u);
            atomicMax(gmax, key);
        }
    } else {
        float rm[4][4];
        #pragma unroll
        for (int mf = 0; mf < 4; mf++)
            #pragma unroll
            for (int r = 0; r < 4; r++) {
                float m = acc[mf][0][r];
                m = fmaxf(m, acc[mf][1][r]);
                m = fmaxf(m, acc[mf][2][r]);
                m = fmaxf(m, acc[mf][3][r]);
                #pragma unroll
                for (int o = 1; o < 16; o <<= 1) m = fmaxf(m, __shfl_xor(m, o));
                rm[mf][r] = m;
            }
        __syncthreads();
        if ((lane & 15) == 0) {
            #pragma unroll
            for (int mf = 0; mf < 4; mf++)
                #pragma unroll
                for (int r = 0; r < 4; r++)
                    red[(mf * 16 + (lane >> 4) * 4 + r) * 4 + wave] = rm[mf][r];
        }
        __syncthreads();
        if (tid < 64) {
            float m4 = fmaxf(fmaxf(red[tid * 4], red[tid * 4 + 1]),
                             fmaxf(red[tid * 4 + 2], red[tid * 4 + 3]));
            srow[tid] = m4 + diagb[(size_t)(m0 + tid) * 8 + h];
        }
    }
    // staging + dense writes (stg occupies [0, 33792); red/srow live above at 34816+)
    u16* stg = (u16*)sm_;    // [64][264]
    const int NP = isq ? 1 : 2;
    for (int pl = 0; pl < NP; pl++) {
        __syncthreads();
        #pragma unroll
        for (int mf = 0; mf < 4; mf++)
            #pragma unroll
            for (int r = 0; r < 4; r++) {
                int row = mf * 16 + (lane >> 4) * 4 + r;
                #pragma unroll
                for (int nf = 0; nf < 4; nf++) {
                    float v = acc[mf][nf][r];
                    u16 o;
                    if (isq) {
                        o = f2bf(0.0625f * (expf(v - srow[row]) + 1e-4f));
                    } else {
                        u16 hh = f2bf(v);
                        o = pl ? f2bf(v - bf2f(hh)) : hh;
                    }
                    stg[row * 264 + wn + nf * 16 + fr] = o;
                }
            }
        __syncthreads();
        int lr = tid >> 2, c0 = (tid & 3) * 64;
        u16* base = isq ? phiQ : (pl ? ddklo : ddkhi);
        u16* dst = base + (size_t)(m0 + lr) * 2048 + h * 256 + c0;
        #pragma unroll
        for (int q = 0; q < 8; q++)
            *(uint4*)(dst + q * 8) = *(uint4*)(stg + lr * 264 + c0 + q * 8);
    }
}

// ---------- fused transpose_k + feat: phiK(in place over hi) + phiKT ----------
__global__ __launch_bounds__(256)
void transpose_k_feat(const u16* __restrict__ hi, const u16* __restrict__ lo,
                      const float* __restrict__ diagb, const u32* __restrict__ gmaxkey,
                      u16* __restrict__ phiK, u16* __restrict__ phiKT)
{
    __shared__ u16 tr[64 * 136];
    u32 key = *gmaxkey;
    u32 ub = (key & 0x80000000u) ? (key & 0x7fffffffu) : ~key;
    const float mg = __uint_as_float(ub);
    const int gc = blockIdx.x, c = gc & 31, bh = gc >> 5, b = bh >> 3, h = bh & 7;
    const int row0 = b * 4096 + c * 128;
    const u16* srcH = hi + (size_t)row0 * 2048 + h * 256;
    const u16* srcL = lo + (size_t)row0 * 2048 + h * 256;
    u16* dstR = phiK + (size_t)row0 * 2048 + h * 256;
    u16* dstT = phiKT + (size_t)gc * 32768;
    const int tid = threadIdx.x;
    for (int f0 = 0; f0 < 256; f0 += 64) {
        #pragma unroll
        for (int j = 0; j < 4; j++) {
            int ci = tid + j * 256; int r = ci >> 3, ff = (ci & 7) * 8;
            bf16x8 wh = *(const bf16x8*)(srcH + (size_t)r * 2048 + f0 + ff);
            bf16x8 wl = *(const bf16x8*)(srcL + (size_t)r * 2048 + f0 + ff);
            float s = mg + diagb[65536 + (size_t)(row0 + r) * 8 + h];
            alignas(16) u16 ob[8];
            #pragma unroll
            for (int q = 0; q < 8; q++) {
                float dd = bf2f((u16)wh[q]) + bf2f((u16)wl[q]);
                u16 pv = f2bf(0.0625f * (expf(dd - s) + 1e-4f));
                ob[q] = pv;
                tr[(ff + q) * 136 + r] = pv;
            }
            *(uint4*)(dstR + (size_t)r * 2048 + f0 + ff) = *(uint4*)ob;
        }
        __syncthreads();
        {
            int f = tid >> 2, r0 = (tid & 3) * 32;
            uint4 a0 = *(uint4*)&tr[f * 136 + r0];
            uint4 a1 = *(uint4*)&tr[f * 136 + r0 + 8];
            uint4 a2 = *(uint4*)&tr[f * 136 + r0 + 16];
            uint4 a3 = *(uint4*)&tr[f * 136 + r0 + 24];
            u16* dp = dstT + (size_t)(f0 + f) * 128 + r0;
            *(uint4*)dp = a0; *(uint4*)(dp + 8) = a1;
            *(uint4*)(dp + 16) = a2; *(uint4*)(dp + 24) = a3;
        }
        __syncthreads();
    }
}

// ---------- final projection GEMM: plain bf16, K=512, global_load_lds staging ----------
__global__ __launch_bounds__(256, 3)
void proj_gemm(const u16* __restrict__ A, const u16* __restrict__ B,
               float* __restrict__ C, const float* __restrict__ bias)
{
    __shared__ char smem[34816];
    char* As = smem; char* Bs = smem + 16384;
    const int m0 = blockIdx.x * 128, n0 = blockIdx.y * 128;
    const int tid = threadIdx.x, lane = tid & 63, wave = tid >> 6;
    const int wm = (wave >> 1) * 64, wn = (wave & 1) * 64;
    const int fr = lane & 15, fk = (lane >> 4) * 8;
    const int lr8 = lane >> 3;
    const int cE = ((lane & 7) ^ lr8) << 3;
    f32x4 acc[4][4] = {};
    for (int k0 = 0; k0 < 512; k0 += 64) {
        #pragma unroll
        for (int t = 0; t < 4; t++) {
            int i = wave * 4 + t;
            int r = (i << 3) + lr8;
            gload16(A + (size_t)(m0 + r) * 512 + k0 + cE, As + (i << 10));
            gload16(B + (size_t)(n0 + r) * 512 + k0 + cE, Bs + (i << 10));
        }
        __syncthreads();
        #pragma unroll
        for (int ks = 0; ks < 2; ks++) {
            bf16x8 af[4], bfv[4];
            #pragma unroll
            for (int mf = 0; mf < 4; mf++)
                af[mf] = *(bf16x8*)(As + swz(wm + mf * 16 + fr, ks * 32 + fk, 64));
            #pragma unroll
            for (int nf = 0; nf < 4; nf++)
                bfv[nf] = *(bf16x8*)(Bs + swz(wn + nf * 16 + fr, ks * 32 + fk, 64));
            #pragma unroll
            for (int mf = 0; mf < 4; mf++)
                #pragma unroll
                for (int nf = 0; nf < 4; nf++)
                    acc[mf][nf] = MF(af[mf], bfv[nf], acc[mf][nf]);
        }
        __syncthreads();
    }
    float* st = (float*)smem;   // [64][130]
    for (int half = 0; half < 2; half++) {
        __syncthreads();
        if ((wave >> 1) == half) {
            #pragma unroll
            for (int mf = 0; mf < 4; mf++) {
                int lr = mf * 16 + (lane >> 4) * 4;
                #pragma unroll
                for (int nf = 0; nf < 4; nf++) {
                    int col = wn + nf * 16 + fr;
                    #pragma unroll
                    for (int r = 0; r < 4; r++)
                        st[(lr + r) * 130 + col] = acc[mf][nf][r];
                }
            }
        }
        __syncthreads();
        int lr = tid >> 2, c0 = (tid & 3) * 32;
        int grow = m0 + half * 64 + lr;
        float* dst = C + (size_t)grow * 512 + n0 + c0;
        #pragma unroll
        for (int q = 0; q < 8; q++) {
            float4 v;
            v.x = st[lr * 130 + c0 + q * 4 + 0] + bias[n0 + c0 + q * 4 + 0];
            v.y = st[lr * 130 + c0 + q * 4 + 1] + bias[n0 + c0 + q * 4 + 1];
            v.z = st[lr * 130 + c0 + q * 4 + 2] + bias[n0 + c0 + q * 4 + 2];
            v.w = st[lr * 130 + c0 + q * 4 + 3] + bias[n0 + c0 + q * 4 + 3];
            *(float4*)(dst + q * 4) = v;
        }
    }
}

// ---------- transpose v planes per chunk -> Vt[gc][pl][e=64][r=128] ----------
__global__ __launch_bounds__(256)
void transpose_v(const u16* __restrict__ vpl, u16* __restrict__ Vt)
{
    __shared__ u16 tr[64 * 136];
    const int gc = blockIdx.x, c = gc & 31, bh = gc >> 5, b = bh >> 3, h = bh & 7;
    const int row0 = b * 4096 + c * 128;
    u16* dstb = Vt + (size_t)gc * 16384;
    const int tid = threadIdx.x;
    for (int pl = 0; pl < 2; pl++) {
        if (pl) __syncthreads();
        const u16* src = vpl + (size_t)pl * 4194304 + (size_t)row0 * 512 + h * 64;
        #pragma unroll
        for (int j = 0; j < 8; j++) {
            int ci = tid + j * 256; int r = ci >> 4, e = (ci & 15) * 4;
            ushort4 v = *(const ushort4*)(src + (size_t)r * 512 + e);
            tr[(e + 0) * 136 + r] = v.x;
            tr[(e + 1) * 136 + r] = v.y;
            tr[(e + 2) * 136 + r] = v.z;
            tr[(e + 3) * 136 + r] = v.w;
        }
        __syncthreads();
        int e = tid >> 2, r0 = (tid & 3) * 32;
        u16* dst = dstb + pl * 8192;
        #pragma unroll
        for (int q = 0; q < 4; q++) {
            uint4 a = *(uint4*)&tr[e * 136 + r0 + q * 8];
            *(uint4*)(dst + (size_t)e * 128 + r0 + q * 8) = a;
        }
    }
}

// ---------- Pass A: S = K^T (Vhi+Vlo), Z = colsum(K), gload staging ----------
__global__ __launch_bounds__(256)
void chunk_sums_mfma(const u16* __restrict__ phiKT, const u16* __restrict__ Vt,
                     float* __restrict__ sbuf, float* __restrict__ zbuf)
{
    __shared__ char smem[49152];
    char* bufA = smem;            // [256 f][64 r]
    char* bufBh = smem + 32768;   // [64 e][64 r]
    char* bufBl = smem + 40960;
    const int gc = blockIdx.x;
    const u16* Ag = phiKT + (size_t)gc * 32768;
    const u16* Bg = Vt + (size_t)gc * 16384;
    const int tid = threadIdx.x, lane = tid & 63, wave = tid >> 6;
    const int fr = lane & 15, fk = (lane >> 4) * 8;
    const int lr8 = lane >> 3;
    const int cE = ((lane & 7) ^ lr8) << 3;
    {
        float z = 0.f;
        const u16* zp = Ag + (size_t)tid * 128;
        #pragma unroll
        for (int j = 0; j < 16; j++) {
            bf16x8 w = *(const bf16x8*)(zp + j * 8);
            #pragma unroll
            for (int q = 0; q < 8; q++) z += bf2f((u16)w[q]);
        }
        zbuf[(size_t)gc * 256 + tid] = z;
    }
    f32x4 acc[4][4] = {};
    for (int kh = 0; kh < 2; kh++) {
        #pragma unroll
        for (int t = 0; t < 8; t++) {
            int i = wave * 8 + t;
            int f = (i << 3) + lr8;
            gload16(Ag + (size_t)f * 128 + kh * 64 + cE, bufA + (i << 10));
        }
        #pragma unroll
        for (int t = 0; t < 2; t++) {
            int i = wave * 2 + t;
            int e = (i << 3) + lr8;
            gload16(Bg + (size_t)e * 128 + kh * 64 + cE, bufBh + (i << 10));
            gload16(Bg + 8192 + (size_t)e * 128 + kh * 64 + cE, bufBl + (i << 10));
        }
        __syncthreads();
        #pragma unroll
        for (int ks = 0; ks < 2; ks++) {
            bf16x8 af[4], bh4[4], bl4[4];
            #pragma unroll
            for (int mf = 0; mf < 4; mf++)
                af[mf] = *(bf16x8*)(bufA + swz(wave * 64 + mf * 16 + fr, ks * 32 + fk, 64));
            #pragma unroll
            for (int nf = 0; nf < 4; nf++) {
                bh4[nf] = *(bf16x8*)(bufBh + swz(nf * 16 + fr, ks * 32 + fk, 64));
                bl4[nf] = *(bf16x8*)(bufBl + swz(nf * 16 + fr, ks * 32 + fk, 64));
            }
            #pragma unroll
            for (int mf = 0; mf < 4; mf++)
                #pragma unroll
                for (int nf = 0; nf < 4; nf++) {
                    acc[mf][nf] = MF(af[mf], bh4[nf], acc[mf][nf]);
                    acc[mf][nf] = MF(af[mf], bl4[nf], acc[mf][nf]);
                }
        }
        __syncthreads();
    }
    #pragma unroll
    for (int mf = 0; mf < 4; mf++) {
        int fb = wave * 64 + mf * 16 + (lane >> 4) * 4;
        #pragma unroll
        for (int nf = 0; nf < 4; nf++) {
            int e = nf * 16 + fr;
            #pragma unroll
            for (int r = 0; r < 4; r++)
                sbuf[(size_t)gc * 16384 + (size_t)(fb + r) * 64 + e] = acc[mf][nf][r];
        }
    }
}

// ---------- Pass B: exclusive prefix, 256 blocks (16 bh x 16 f-slabs) ----------
__global__ __launch_bounds__(256)
void prefix_scan(const float* __restrict__ sbuf, const float* __restrict__ zbuf,
                 u16* __restrict__ SpT, float* __restrict__ Zp,
                 float* __restrict__ outZ, float* __restrict__ outS)
{
    __shared__ float trans[64 * 17];
    const int bh = blockIdx.x >> 4, f0 = (blockIdx.x & 15) * 16;
    const int tid = threadIdx.x;
    const int e_ = tid >> 2, fl = (tid & 3) * 4;
    float run[4] = {0.f, 0.f, 0.f, 0.f};
    float zrun = 0.f;
    for (int c = 0; c < 32; c++) {
        const int gc = bh * 32 + c;
        const float* base = sbuf + (size_t)gc * 16384 + f0 * 64;
        float v[4];
        #pragma unroll
        for (int i = 0; i < 4; i++) v[i] = base[tid + i * 256];
        #pragma unroll
        for (int i = 0; i < 4; i++) {
            int idx = tid + i * 256;
            trans[(idx & 63) * 17 + (idx >> 6)] = run[i];
        }
        float zv = 0.f;
        if (tid < 16) zv = zbuf[(size_t)gc * 256 + f0 + tid];
        __syncthreads();
        {
            alignas(8) u16 hb[4], lb[4];
            #pragma unroll
            for (int q = 0; q < 4; q++) {
                float vv = trans[e_ * 17 + fl + q];
                u16 hh = f2bf(vv); hb[q] = hh; lb[q] = f2bf(vv - bf2f(hh));
            }
            u16* dh = SpT + (size_t)gc * 32768 + e_ * 256 + f0 + fl;
            *(uint2*)dh = *(uint2*)hb;
            *(uint2*)(dh + 16384) = *(uint2*)lb;
        }
        if (tid < 16) { Zp[(size_t)gc * 256 + f0 + tid] = zrun; zrun += zv; }
        #pragma unroll
        for (int i = 0; i < 4; i++) run[i] += v[i];
        __syncthreads();
    }
    #pragma unroll
    for (int i = 0; i < 4; i++)
        outS[(size_t)bh * 16384 + f0 * 64 + tid + i * 256] = run[i];
    if (tid < 16) outZ[bh * 256 + f0 + tid] = zrun;
}

// ---------- Pass C: aouts(plain bf16) = Dinv*(Q@Sprev + tril(QK^T)@V), gload staging ----------
__global__ __launch_bounds__(256)
void chunk_out_mfma(const u16* __restrict__ phiQ, const u16* __restrict__ phiK,
                    const u16* __restrict__ Vt, const u16* __restrict__ SpT,
                    const float* __restrict__ Zp, u16* __restrict__ aouts)
{
    extern __shared__ char sm[];
    char* bufQ = sm;             // [128][64] Q-slab
    char* bufK = sm + 16384;     // [128][64] K-slab ; later V_hi [64][128] swz
    char* bufA = sm + 32768;     // f0 loop: Sp_hi @+0, Sp_lo @+8192 ; after: A [128][128] swz
    float* Dl = (float*)(sm + 65536);    // [128]
    float* Zl = (float*)(sm + 66048);    // [64]
    const int gc = blockIdx.x, c = gc & 31, bh = gc >> 5, b = bh >> 3, h = bh & 7;
    const int row0 = b * 4096 + c * 128;
    const u16* Qg = phiQ + (size_t)row0 * 2048 + h * 256;
    const u16* Kg = phiK + (size_t)row0 * 2048 + h * 256;
    const u16* Vg = Vt + (size_t)gc * 16384;
    const u16* Sg = SpT + (size_t)gc * 32768;
    const float* Zg = Zp + (size_t)gc * 256;
    const int tid = threadIdx.x, lane = tid & 63, wave = tid >> 6;
    const int fr = lane & 15, fk = (lane >> 4) * 8;
    const int dr = tid >> 1, dc = (tid & 1) * 32;
    const int lr8 = lane >> 3;
    const int cE = ((lane & 7) ^ lr8) << 3;

    f32x4 acc2[2][8] = {};
    f32x4 acc1[2][4] = {};
    float dotZ = 0.f, sumQ = 0.f;

    for (int f0 = 0; f0 < 256; f0 += 64) {
        #pragma unroll
        for (int t = 0; t < 4; t++) {
            int i = wave * 4 + t;
            int r = (i << 3) + lr8;
            gload16(Qg + (size_t)r * 2048 + f0 + cE, bufQ + (i << 10));
            gload16(Kg + (size_t)r * 2048 + f0 + cE, bufK + (i << 10));
        }
        #pragma unroll
        for (int t = 0; t < 2; t++) {
            int i = wave * 2 + t;
            int e = (i << 3) + lr8;
            gload16(Sg + (size_t)e * 256 + f0 + cE, bufA + (i << 10));
            gload16(Sg + 16384 + (size_t)e * 256 + f0 + cE, bufA + 8192 + (i << 10));
        }
        if (tid < 64) Zl[tid] = Zg[f0 + tid];
        __syncthreads();
        #pragma unroll
        for (int ks = 0; ks < 2; ks++) {
            bf16x8 af[2];
            af[0] = *(bf16x8*)(bufQ + swz(wave * 32 + fr, ks * 32 + fk, 64));
            af[1] = *(bf16x8*)(bufQ + swz(wave * 32 + 16 + fr, ks * 32 + fk, 64));
            #pragma unroll
            for (int nf = 0; nf < 8; nf++) {
                bf16x8 bv = *(bf16x8*)(bufK + swz(nf * 16 + fr, ks * 32 + fk, 64));
                acc2[0][nf] = MF(af[0], bv, acc2[0][nf]);
                acc2[1][nf] = MF(af[1], bv, acc2[1][nf]);
            }
            #pragma unroll
            for (int nf = 0; nf < 4; nf++) {
                bf16x8 bvh = *(bf16x8*)(bufA + swz(nf * 16 + fr, ks * 32 + fk, 64));
                bf16x8 bvl = *(bf16x8*)(bufA + 8192 + swz(nf * 16 + fr, ks * 32 + fk, 64));
                acc1[0][nf] = MF(af[0], bvh, acc1[0][nf]);
                acc1[1][nf] = MF(af[1], bvh, acc1[1][nf]);
                acc1[0][nf] = MF(af[0], bvl, acc1[0][nf]);
                acc1[1][nf] = MF(af[1], bvl, acc1[1][nf]);
            }
        }
        #pragma unroll
        for (int jj = 0; jj < 4; jj++) {
            bf16x8 qv = *(bf16x8*)(bufQ + swz(dr, dc + jj * 8, 64));
            f32x4 z0 = *(f32x4*)(Zl + dc + jj * 8);
            f32x4 z1 = *(f32x4*)(Zl + dc + jj * 8 + 4);
            #pragma unroll
            for (int q = 0; q < 8; q++) {
                float qf = bf2f((u16)qv[q]);
                sumQ += qf;
                dotZ += qf * (q < 4 ? z0[q] : z1[q - 4]);
            }
        }
        __syncthreads();
    }
    float4 vvh[4];
    #pragma unroll
    for (int j = 0; j < 4; j++) {
        int ci = tid + j * 256; int e = ci >> 4, cc = (ci & 15) * 8;
        vvh[j] = *(const float4*)(Vg + (size_t)e * 128 + cc);
    }
    #pragma unroll
    for (int mf = 0; mf < 2; mf++) {
        int rb = wave * 32 + mf * 16 + (lane >> 4) * 4;
        #pragma unroll
        for (int nf = 0; nf < 8; nf++) {
            int col = nf * 16 + fr;
            #pragma unroll
            for (int r = 0; r < 4; r++) {
                float v = (col <= rb + r) ? acc2[mf][nf][r] : 0.f;
                *(u16*)(bufA + swz(rb + r, col, 128)) = f2bf(v);
            }
        }
    }
    #pragma unroll
    for (int j = 0; j < 4; j++) {
        int ci = tid + j * 256; int e = ci >> 4, cc = (ci & 15) * 8;
        *(float4*)(bufK + swz(e, cc, 128)) = vvh[j];
    }
    __syncthreads();
    {
        const int dcA = (tid & 1) * 64;
        float rs = 0.f;
        #pragma unroll
        for (int jj = 0; jj < 8; jj++) {
            bf16x8 av = *(bf16x8*)(bufA + swz(dr, dcA + jj * 8, 128));
            #pragma unroll
            for (int q = 0; q < 8; q++) rs += bf2f((u16)av[q]);
        }
        float tot = rs + dotZ + 1e-6f * sumQ;
        tot += __shfl_xor(tot, 1);
        if ((tid & 1) == 0) Dl[dr] = tot;
    }
    #pragma unroll
    for (int ks = 0; ks < 4; ks++) {
        bf16x8 af[2];
        af[0] = *(bf16x8*)(bufA + swz(wave * 32 + fr, ks * 32 + fk, 128));
        af[1] = *(bf16x8*)(bufA + swz(wave * 32 + 16 + fr, ks * 32 + fk, 128));
        #pragma unroll
        for (int nf = 0; nf < 4; nf++) {
            bf16x8 bvh = *(bf16x8*)(bufK + swz(nf * 16 + fr, ks * 32 + fk, 128));
            acc1[0][nf] = MF(af[0], bvh, acc1[0][nf]);
            acc1[1][nf] = MF(af[1], bvh, acc1[1][nf]);
        }
    }
    __syncthreads();
    float* st = (float*)sm;   // [128][65]
    #pragma unroll
    for (int mf = 0; mf < 2; mf++) {
        int rb = wave * 32 + mf * 16 + (lane >> 4) * 4;
        #pragma unroll
        for (int r = 0; r < 4; r++) {
            float dinv = 1.f / Dl[rb + r];
            #pragma unroll
            for (int nf = 0; nf < 4; nf++)
                st[(rb + r) * 65 + nf * 16 + fr] = acc1[mf][nf][r] * dinv;
        }
    }
    __syncthreads();
    {
        int lr = tid >> 1, e0 = (tid & 1) * 32;
        alignas(16) u16 hb[32];
        #pragma unroll
        for (int q = 0; q < 32; q++) hb[q] = f2bf(st[lr * 65 + e0 + q]);
        u16* d = aouts + (size_t)(row0 + lr) * 512 + h * 64 + e0;
        #pragma unroll
        for (int q = 0; q < 4; q++) *(uint4*)(d + q * 8) = *(uint4*)&hb[q * 8];
    }
}

extern "C" void kernel_launch(void* const* d_in, const int* in_sizes, int n_in,
                              void* d_out, int out_size, void* d_ws, size_t ws_size,
                              hipStream_t stream)
{
    const float* x    = (const float*)d_in[0];
    const float* Wq   = (const float*)d_in[1];
    const float* Wk   = (const float*)d_in[2];
    const float* Wv   = (const float*)d_in[3];
    const float* Wo   = (const float*)d_in[4];
    const float* bo   = (const float*)d_in[5];
    const float* proj = (const float*)d_in[6];
    float* out = (float*)d_out;
    float* ws = (float*)d_ws;

    // layout (float offsets)
    u16*   vpl   = (u16*)ws;                    // [2][8192][512] u16
    float* diagb = ws + 4194304;                // [2][8192][8] f32
    u16*   phi   = (u16*)(ws + 12582912);       // [16384][2048] u16
    u16*   ddklo = (u16*)(ws + 29360128);       // [8192][2048] u16 (dead after transpose_k_feat)
    u16*   Vtb   = (u16*)(ws + 37748736);       // [512][2][64][128] u16
    float* sbuf  = ws + 41943040;               // 512*16384 f32
    u16*   qs    = (u16*)(ws + 41943040);       // q|k split u16 (dead after dd_gemm)
    u16*   phiKT = (u16*)(ws + 50331648);       // 512*32768 u16 (dead after chunk_sums)
    u16*   SpT   = (u16*)(ws + 50331648);       //   overlay: written by prefix_scan AFTER chunk_sums
    u16*   xs    = (u16*)(ws + 58720256);       // [8192][1536] u16
    u16*   aouts = xs;                          //   overlay: plain [8192][512] u16
    u16*   Wqkvs = (u16*)(ws + 65011712);       // [1536][1536] u16
    float* zbuf  = ws + 65142784;               //   overlay Wqkvs (dead after qkv_gemm)
    float* Zp    = ws + 65273856;
    u32*   gmax  = (u32*)(ws + 65404928);
    u16*   Wos   = (u16*)(ws + 66191360);       // plain [512][512] u16
    u16*   projs = (u16*)(ws + 66584576);       // [256][192] u16

    float* outO = out;                 // [2,4096,512]
    float* outZ = out + 4194304;       // [2,8,256]
    float* outS = out + 4198400;       // [2,8,256,64]

    dim3 blk(256);

    // converts
    conv_split<false><<<2048, blk, 0, stream>>>(x, xs, 512, 1048576L, 1.f);
    conv_split<true ><<<256, blk, 0, stream>>>(Wq, Wqkvs, 512, 65536L, 1.f);
    conv_split<true ><<<256, blk, 0, stream>>>(Wk, Wqkvs + 786432, 512, 65536L, 1.f);
    conv_split<true ><<<256, blk, 0, stream>>>(Wv, Wqkvs + 1572864, 512, 65536L, 1.f);
    conv_plain<<<64, blk, 0, stream>>>(Wo, Wos, 65536L);
    conv_split<true ><<<16, blk, 0, stream>>>(proj, projs, 64, 4096L, 1.f);
    // fused QKV projection (128x128 tiles, global_load_lds staging)
    qkv_gemm<<<dim3(64, 12), blk, 0, stream>>>(xs, Wqkvs, qs, diagb, vpl);
    hipMemsetAsync(gmax, 0, 4, stream);
    // merged dd GEMM (K=192, 4 blk/CU): q (z<8) fused feat; k (z>=8) split ddk + blockmax
    const u16* ksplit = qs + 12582912;
    u16* ddkhi = phi + (size_t)8192 * 2048;     // phiK region (in-place exp in transpose)
    dd_gemm<<<dim3(128, 1, 16), blk, 0, stream>>>(qs, ksplit, projs, diagb, gmax,
                                                  phi, ddkhi, ddklo);
    // fused k feature map + transpose: phiK in place + phiKT
    transpose_k_feat<<<512, blk, 0, stream>>>(ddkhi, ddklo, diagb, gmax, ddkhi, phiKT);
    transpose_v<<<512, blk, 0, stream>>>(vpl, Vtb);
    // chunked linear attention
    chunk_sums_mfma<<<512, blk, 0, stream>>>(phiKT, Vtb, sbuf, zbuf);
    prefix_scan<<<256, blk, 0, stream>>>(sbuf, zbuf, SpT, Zp, outZ, outS);
    hipFuncSetAttribute((const void*)chunk_out_mfma,
                        hipFuncAttributeMaxDynamicSharedMemorySize, 66304);
    chunk_out_mfma<<<512, blk, 66304, stream>>>(phi, ddkhi, Vtb, SpT, Zp, aouts);
    // final projection (plain bf16, K=512, global_load_lds staging)
    proj_gemm<<<dim3(64, 4), blk, 0, stream>>>(aouts, Wos, outO, bo);
}

// Round 18
// 255.839 us; speedup vs baseline: 1.3389x; 1.2716x over previous
//
#include <hip/hip_runtime.h>

typedef unsigned short u16;
typedef unsigned int u32;
typedef __attribute__((ext_vector_type(8))) short bf16x8;
typedef __attribute__((ext_vector_type(4))) float f32x4;

__device__ __forceinline__ u16 f2bf(float f) {
    u32 u = __float_as_uint(f);
    return (u16)((u + 0x7fffu + ((u >> 16) & 1u)) >> 16);
}
__device__ __forceinline__ float bf2f(u16 h) { return __uint_as_float(((u32)h) << 16); }
__device__ __forceinline__ u32 pk(u16 a, u16 b) { return (u32)a | ((u32)b << 16); }
__device__ __forceinline__ int swz(int row, int col, int ld) {
    return ((row * ld + col) * 2) ^ ((row & 7) << 4);
}
__device__ __forceinline__ f32x4 MF(bf16x8 a, bf16x8 b, f32x4 c) {
    return __builtin_amdgcn_mfma_f32_16x16x32_bf16(a, b, c, 0, 0, 0);
}
__device__ __forceinline__ float wave_max(float v) {
    #pragma unroll
    for (int o = 32; o; o >>= 1) v = fmaxf(v, __shfl_xor(v, o));
    return v;
}
__device__ __forceinline__ void gload16(const void* g, void* l) {
    __builtin_amdgcn_global_load_lds(
        (const __attribute__((address_space(1))) void*)g,
        (__attribute__((address_space(3))) void*)l, 16, 0, 0);
}
__device__ __forceinline__ float gmax_decode(const u32* gmaxkey) {
    u32 key = *gmaxkey;
    u32 ub = (key & 0x80000000u) ? (key & 0x7fffffffu) : ~key;
    return __uint_as_float(ub);
}

// ---------- split-bf16 convert: A:[hi|hi|lo]  B:[hi|lo|hi] ----------
template<bool ISB>
__global__ __launch_bounds__(256)
void conv_split(const float* __restrict__ src, u16* __restrict__ dst,
                int K, long total4, float scale)
{
    const int K4 = K >> 2;
    for (long i = (long)blockIdx.x * 256 + threadIdx.x; i < total4;
         i += (long)gridDim.x * 256) {
        long row = i / K4;
        int c = (int)(i - row * K4) * 4;
        float4 v = ((const float4*)src)[i];
        float a0 = v.x * scale, a1 = v.y * scale, a2 = v.z * scale, a3 = v.w * scale;
        u16 h0 = f2bf(a0), h1 = f2bf(a1), h2 = f2bf(a2), h3 = f2bf(a3);
        u16 l0 = f2bf(a0 - bf2f(h0)), l1 = f2bf(a1 - bf2f(h1));
        u16 l2 = f2bf(a2 - bf2f(h2)), l3 = f2bf(a3 - bf2f(h3));
        uint2 hh; hh.x = pk(h0, h1); hh.y = pk(h2, h3);
        uint2 ll; ll.x = pk(l0, l1); ll.y = pk(l2, l3);
        u16* d = dst + row * (3L * K) + c;
        *(uint2*)d = hh;
        *(uint2*)(d + (ISB ? 2 * K : K)) = hh;
        *(uint2*)(d + (ISB ? K : 2 * K)) = ll;
    }
}

// ---------- plain bf16 convert ----------
__global__ __launch_bounds__(256)
void conv_plain(const float* __restrict__ src, u16* __restrict__ dst, long total4)
{
    for (long i = (long)blockIdx.x * 256 + threadIdx.x; i < total4;
         i += (long)gridDim.x * 256) {
        float4 v = ((const float4*)src)[i];
        ushort4 o;
        o.x = f2bf(v.x); o.y = f2bf(v.y); o.z = f2bf(v.z); o.w = f2bf(v.w);
        ((ushort4*)dst)[i] = o;
    }
}

// ---------- fused QKV GEMM, 128x128 tile, global_load_lds staging ----------
__global__ __launch_bounds__(256, 3)
void qkv_gemm(const u16* __restrict__ A, const u16* __restrict__ B,
              u16* __restrict__ qs, float* __restrict__ diagb,
              u16* __restrict__ vpl)
{
    __shared__ char smem[34816];
    char* As = smem; char* Bs = smem + 16384;
    const int m0 = blockIdx.x * 128, by = blockIdx.y, n0 = by * 128;
    const int tid = threadIdx.x, lane = tid & 63, wave = tid >> 6;
    const int wm = (wave >> 1) * 64, wn = (wave & 1) * 64;
    const int fr = lane & 15, fk = (lane >> 4) * 8;
    const int lr8 = lane >> 3;
    const int cE = ((lane & 7) ^ lr8) << 3;
    f32x4 acc[4][4] = {};
    for (int k0 = 0; k0 < 1536; k0 += 64) {
        #pragma unroll
        for (int t = 0; t < 4; t++) {
            int i = wave * 4 + t;
            int r = (i << 3) + lr8;
            gload16(A + (size_t)(m0 + r) * 1536 + k0 + cE, As + (i << 10));
            gload16(B + (size_t)(n0 + r) * 1536 + k0 + cE, Bs + (i << 10));
        }
        __syncthreads();
        #pragma unroll
        for (int ks = 0; ks < 2; ks++) {
            bf16x8 af[4], bfv[4];
            #pragma unroll
            for (int mf = 0; mf < 4; mf++)
                af[mf] = *(bf16x8*)(As + swz(wm + mf * 16 + fr, ks * 32 + fk, 64));
            #pragma unroll
            for (int nf = 0; nf < 4; nf++)
                bfv[nf] = *(bf16x8*)(Bs + swz(wn + nf * 16 + fr, ks * 32 + fk, 64));
            #pragma unroll
            for (int mf = 0; mf < 4; mf++)
                #pragma unroll
                for (int nf = 0; nf < 4; nf++)
                    acc[mf][nf] = MF(af[mf], bfv[nf], acc[mf][nf]);
        }
        __syncthreads();
    }
    const float dn = 0.35355339059327373f;
    const int sel = by >> 2;        // 0=q,1=k,2=v
    float* st = (float*)smem;       // [64][130]
    for (int half = 0; half < 2; half++) {
        __syncthreads();
        if ((wave >> 1) == half) {
            #pragma unroll
            for (int mf = 0; mf < 4; mf++) {
                int lr = mf * 16 + (lane >> 4) * 4;
                #pragma unroll
                for (int nf = 0; nf < 4; nf++) {
                    int col = wn + nf * 16 + fr;
                    #pragma unroll
                    for (int r = 0; r < 4; r++)
                        st[(lr + r) * 130 + col] = acc[mf][nf][r];
                }
            }
        }
        __syncthreads();
        int grow = m0 + half * 64 + (tid >> 2);
        if (sel < 2) {
            int hl = (tid >> 1) & 1, e0 = (tid & 1) * 32;
            int h = (by & 3) * 2 + hl;
            alignas(16) u16 hbuf[32], lbuf[32];
            float ss = 0.f;
            #pragma unroll
            for (int q = 0; q < 32; q++) {
                float v = dn * st[(tid >> 2) * 130 + hl * 64 + e0 + q];
                ss += v * v;
                u16 hh = f2bf(v); hbuf[q] = hh; lbuf[q] = f2bf(v - bf2f(hh));
            }
            ss += __shfl_xor(ss, 1);
            if ((tid & 1) == 0)
                diagb[(size_t)sel * 65536 + grow * 8 + h] = 0.5f * ss;
            u16* d = qs + (size_t)sel * 12582912 + (size_t)grow * 1536 + h * 192 + e0;
            #pragma unroll
            for (int q = 0; q < 4; q++) *(uint4*)(d + q * 8) = *(uint4*)&hbuf[q * 8];
            #pragma unroll
            for (int q = 0; q < 4; q++) *(uint4*)(d + 64 + q * 8) = *(uint4*)&hbuf[q * 8];
            #pragma unroll
            for (int q = 0; q < 4; q++) *(uint4*)(d + 128 + q * 8) = *(uint4*)&lbuf[q * 8];
        } else {
            int e0 = (tid & 3) * 32;
            int colbase = (by & 3) * 128 + e0;
            alignas(16) u16 hbuf[32], lbuf[32];
            #pragma unroll
            for (int q = 0; q < 32; q++) {
                float v = st[(tid >> 2) * 130 + e0 + q];
                u16 hh = f2bf(v); hbuf[q] = hh; lbuf[q] = f2bf(v - bf2f(hh));
            }
            u16* dh = vpl + (size_t)grow * 512 + colbase;
            u16* dl = dh + 4194304;
            #pragma unroll
            for (int q = 0; q < 4; q++) *(uint4*)(dh + q * 8) = *(uint4*)&hbuf[q * 8];
            #pragma unroll
            for (int q = 0; q < 4; q++) *(uint4*)(dl + q * 8) = *(uint4*)&lbuf[q * 8];
        }
    }
}

// ---------- merged dd GEMM, 64x256 per head, grid (128,1,16), round-15 LDS ----------
// z<8: q path h=z: phiQ = ratio*(exp(dd - diag - rowmax) + 1e-4)
// z>=8: k path h=z-8: psi = exp(dd - diag), single pass; blockmax -> gmax (publishes m)
__global__ __launch_bounds__(256, 3)
void dd_gemm(const u16* __restrict__ Aq, const u16* __restrict__ Ak,
             const u16* __restrict__ Bp,
             const float* __restrict__ diagb, u32* __restrict__ gmax,
             u16* __restrict__ phiQ, u16* __restrict__ psiK)
{
    __shared__ char sm_[42240];
    char* As = sm_;                       // [64][64] u16 (8K, linear gload dest)
    char* Bs = sm_ + 8192;                // [256][64] u16 (32K)
    float* red  = (float*)(sm_ + 40960);  // [64][4]
    float* srow = (float*)(sm_ + 41984);  // [64]
    const int isq = (blockIdx.z < 8);
    const int h = isq ? blockIdx.z : (blockIdx.z - 8);
    const int m0 = blockIdx.x * 64;
    const u16* Ag = (isq ? Aq : Ak) + (size_t)m0 * 1536 + h * 192;
    const int tid = threadIdx.x, lane = tid & 63, wave = tid >> 6;
    const int wn = wave * 64;
    const int fr = lane & 15, fk = (lane >> 4) * 8;
    const int lr8 = lane >> 3;
    const int cE = ((lane & 7) ^ lr8) << 3;
    f32x4 acc[4][4] = {};
    for (int k0 = 0; k0 < 192; k0 += 64) {
        #pragma unroll
        for (int t = 0; t < 2; t++) {
            int i = wave * 2 + t;
            int r = (i << 3) + lr8;
            gload16(Ag + (size_t)r * 1536 + k0 + cE, As + (i << 10));
        }
        #pragma unroll
        for (int t = 0; t < 8; t++) {
            int i = wave * 8 + t;
            int r = (i << 3) + lr8;
            gload16(Bp + (size_t)r * 192 + k0 + cE, Bs + (i << 10));
        }
        __syncthreads();
        #pragma unroll
        for (int ks = 0; ks < 2; ks++) {
            bf16x8 af[4], bf4[4];
            #pragma unroll
            for (int mf = 0; mf < 4; mf++)
                af[mf] = *(bf16x8*)(As + swz(mf * 16 + fr, ks * 32 + fk, 64));
            #pragma unroll
            for (int nf = 0; nf < 4; nf++)
                bf4[nf] = *(bf16x8*)(Bs + swz(wn + nf * 16 + fr, ks * 32 + fk, 64));
            #pragma unroll
            for (int mf = 0; mf < 4; mf++)
                #pragma unroll
                for (int nf = 0; nf < 4; nf++)
                    acc[mf][nf] = MF(af[mf], bf4[nf], acc[mf][nf]);
        }
        __syncthreads();
    }

    if (!isq) {
        // publish block max (for m); srow = diag only
        float mx = -1e30f;
        #pragma unroll
        for (int mf = 0; mf < 4; mf++)
            #pragma unroll
            for (int nf = 0; nf < 4; nf++)
                #pragma unroll
                for (int r = 0; r < 4; r++) mx = fmaxf(mx, acc[mf][nf][r]);
        mx = wave_max(mx);
        __syncthreads();
        if (lane == 0) red[wave] = mx;
        __syncthreads();
        if (tid == 0) {
            float m4 = fmaxf(fmaxf(red[0], red[1]), fmaxf(red[2], red[3]));
            u32 u = __float_as_uint(m4);
            u32 key = (u & 0x80000000u) ? ~u : (u | 0x80000000u);
            atomicMax(gmax, key);
        }
        if (tid < 64)
            srow[tid] = diagb[65536 + (size_t)(m0 + tid) * 8 + h];
    } else {
        float rm[4][4];
        #pragma unroll
        for (int mf = 0; mf < 4; mf++)
            #pragma unroll
            for (int r = 0; r < 4; r++) {
                float m = acc[mf][0][r];
                m = fmaxf(m, acc[mf][1][r]);
                m = fmaxf(m, acc[mf][2][r]);
                m = fmaxf(m, acc[mf][3][r]);
                #pragma unroll
                for (int o = 1; o < 16; o <<= 1) m = fmaxf(m, __shfl_xor(m, o));
                rm[mf][r] = m;
            }
        __syncthreads();
        if ((lane & 15) == 0) {
            #pragma unroll
            for (int mf = 0; mf < 4; mf++)
                #pragma unroll
                for (int r = 0; r < 4; r++)
                    red[(mf * 16 + (lane >> 4) * 4 + r) * 4 + wave] = rm[mf][r];
        }
        __syncthreads();
        if (tid < 64) {
            float m4 = fmaxf(fmaxf(red[tid * 4], red[tid * 4 + 1]),
                             fmaxf(red[tid * 4 + 2], red[tid * 4 + 3]));
            srow[tid] = m4 + diagb[(size_t)(m0 + tid) * 8 + h];
        }
    }
    // single-pass staging + dense writes
    u16* stg = (u16*)sm_;    // [64][264]
    __syncthreads();
    #pragma unroll
    for (int mf = 0; mf < 4; mf++)
        #pragma unroll
        for (int r = 0; r < 4; r++) {
            int row = mf * 16 + (lane >> 4) * 4 + r;
            float s = srow[row];
            #pragma unroll
            for (int nf = 0; nf < 4; nf++) {
                float v = acc[mf][nf][r];
                u16 o = isq ? f2bf(0.0625f * (expf(v - s) + 1e-4f))
                            : f2bf(expf(v - s));
                stg[row * 264 + wn + nf * 16 + fr] = o;
            }
        }
    __syncthreads();
    {
        int lr = tid >> 2, c0 = (tid & 3) * 64;
        u16* base = isq ? phiQ : psiK;
        u16* dst = base + (size_t)(m0 + lr) * 2048 + h * 256 + c0;
        #pragma unroll
        for (int q = 0; q < 8; q++)
            *(uint4*)(dst + q * 8) = *(uint4*)(stg + lr * 264 + c0 + q * 8);
    }
}

// ---------- plain transpose psiK per chunk -> psiKT[gc][f=256][r=128] ----------
__global__ __launch_bounds__(256)
void transpose_k(const u16* __restrict__ phiK, u16* __restrict__ phiKT)
{
    __shared__ u16 tr[64 * 136];
    const int gc = blockIdx.x, c = gc & 31, bh = gc >> 5, b = bh >> 3, h = bh & 7;
    const int row0 = b * 4096 + c * 128;
    const u16* src = phiK + (size_t)row0 * 2048 + h * 256;
    u16* dst = phiKT + (size_t)gc * 32768;
    const int tid = threadIdx.x;
    for (int f0 = 0; f0 < 256; f0 += 64) {
        #pragma unroll
        for (int j = 0; j < 4; j++) {
            int ci = tid + j * 256; int r = ci >> 3, ff = (ci & 7) * 8;
            bf16x8 w = *(const bf16x8*)(src + (size_t)r * 2048 + f0 + ff);
            #pragma unroll
            for (int q = 0; q < 8; q++) tr[(ff + q) * 136 + r] = (u16)w[q];
        }
        __syncthreads();
        {
            int f = tid >> 2, r0 = (tid & 3) * 32;
            uint4 a0 = *(uint4*)&tr[f * 136 + r0];
            uint4 a1 = *(uint4*)&tr[f * 136 + r0 + 8];
            uint4 a2 = *(uint4*)&tr[f * 136 + r0 + 16];
            uint4 a3 = *(uint4*)&tr[f * 136 + r0 + 24];
            u16* dp = dst + (size_t)(f0 + f) * 128 + r0;
            *(uint4*)dp = a0; *(uint4*)(dp + 8) = a1;
            *(uint4*)(dp + 16) = a2; *(uint4*)(dp + 24) = a3;
        }
        __syncthreads();
    }
}

// ---------- final projection GEMM: plain bf16, K=512, global_load_lds staging ----------
__global__ __launch_bounds__(256, 3)
void proj_gemm(const u16* __restrict__ A, const u16* __restrict__ B,
               float* __restrict__ C, const float* __restrict__ bias)
{
    __shared__ char smem[34816];
    char* As = smem; char* Bs = smem + 16384;
    const int m0 = blockIdx.x * 128, n0 = blockIdx.y * 128;
    const int tid = threadIdx.x, lane = tid & 63, wave = tid >> 6;
    const int wm = (wave >> 1) * 64, wn = (wave & 1) * 64;
    const int fr = lane & 15, fk = (lane >> 4) * 8;
    const int lr8 = lane >> 3;
    const int cE = ((lane & 7) ^ lr8) << 3;
    f32x4 acc[4][4] = {};
    for (int k0 = 0; k0 < 512; k0 += 64) {
        #pragma unroll
        for (int t = 0; t < 4; t++) {
            int i = wave * 4 + t;
            int r = (i << 3) + lr8;
            gload16(A + (size_t)(m0 + r) * 512 + k0 + cE, As + (i << 10));
            gload16(B + (size_t)(n0 + r) * 512 + k0 + cE, Bs + (i << 10));
        }
        __syncthreads();
        #pragma unroll
        for (int ks = 0; ks < 2; ks++) {
            bf16x8 af[4], bfv[4];
            #pragma unroll
            for (int mf = 0; mf < 4; mf++)
                af[mf] = *(bf16x8*)(As + swz(wm + mf * 16 + fr, ks * 32 + fk, 64));
            #pragma unroll
            for (int nf = 0; nf < 4; nf++)
                bfv[nf] = *(bf16x8*)(Bs + swz(wn + nf * 16 + fr, ks * 32 + fk, 64));
            #pragma unroll
            for (int mf = 0; mf < 4; mf++)
                #pragma unroll
                for (int nf = 0; nf < 4; nf++)
                    acc[mf][nf] = MF(af[mf], bfv[nf], acc[mf][nf]);
        }
        __syncthreads();
    }
    float* st = (float*)smem;   // [64][130]
    for (int half = 0; half < 2; half++) {
        __syncthreads();
        if ((wave >> 1) == half) {
            #pragma unroll
            for (int mf = 0; mf < 4; mf++) {
                int lr = mf * 16 + (lane >> 4) * 4;
                #pragma unroll
                for (int nf = 0; nf < 4; nf++) {
                    int col = wn + nf * 16 + fr;
                    #pragma unroll
                    for (int r = 0; r < 4; r++)
                        st[(lr + r) * 130 + col] = acc[mf][nf][r];
                }
            }
        }
        __syncthreads();
        int lr = tid >> 2, c0 = (tid & 3) * 32;
        int grow = m0 + half * 64 + lr;
        float* dst = C + (size_t)grow * 512 + n0 + c0;
        #pragma unroll
        for (int q = 0; q < 8; q++) {
            float4 v;
            v.x = st[lr * 130 + c0 + q * 4 + 0] + bias[n0 + c0 + q * 4 + 0];
            v.y = st[lr * 130 + c0 + q * 4 + 1] + bias[n0 + c0 + q * 4 + 1];
            v.z = st[lr * 130 + c0 + q * 4 + 2] + bias[n0 + c0 + q * 4 + 2];
            v.w = st[lr * 130 + c0 + q * 4 + 3] + bias[n0 + c0 + q * 4 + 3];
            *(float4*)(dst + q * 4) = v;
        }
    }
}

// ---------- transpose v planes per chunk -> Vt[gc][pl][e=64][r=128] ----------
__global__ __launch_bounds__(256)
void transpose_v(const u16* __restrict__ vpl, u16* __restrict__ Vt)
{
    __shared__ u16 tr[64 * 136];
    const int gc = blockIdx.x, c = gc & 31, bh = gc >> 5, b = bh >> 3, h = bh & 7;
    const int row0 = b * 4096 + c * 128;
    u16* dstb = Vt + (size_t)gc * 16384;
    const int tid = threadIdx.x;
    for (int pl = 0; pl < 2; pl++) {
        if (pl) __syncthreads();
        const u16* src = vpl + (size_t)pl * 4194304 + (size_t)row0 * 512 + h * 64;
        #pragma unroll
        for (int j = 0; j < 8; j++) {
            int ci = tid + j * 256; int r = ci >> 4, e = (ci & 15) * 4;
            ushort4 v = *(const ushort4*)(src + (size_t)r * 512 + e);
            tr[(e + 0) * 136 + r] = v.x;
            tr[(e + 1) * 136 + r] = v.y;
            tr[(e + 2) * 136 + r] = v.z;
            tr[(e + 3) * 136 + r] = v.w;
        }
        __syncthreads();
        int e = tid >> 2, r0 = (tid & 3) * 32;
        u16* dst = dstb + pl * 8192;
        #pragma unroll
        for (int q = 0; q < 4; q++) {
            uint4 a = *(uint4*)&tr[e * 136 + r0 + q * 8];
            *(uint4*)(dst + (size_t)e * 128 + r0 + q * 8) = a;
        }
    }
}

// ---------- Pass A: S = a*(psi^T(Vhi+Vlo)) + b*Vcsum, Z = a*colsum(psi) + 128b ----------
__global__ __launch_bounds__(256)
void chunk_sums_mfma(const u16* __restrict__ phiKT, const u16* __restrict__ Vt,
                     const u32* __restrict__ gmaxkey,
                     float* __restrict__ sbuf, float* __restrict__ zbuf)
{
    __shared__ char smem[49152];
    __shared__ float vcs[64];
    char* bufA = smem;            // [256 f][64 r]
    char* bufBh = smem + 32768;   // [64 e][64 r]
    char* bufBl = smem + 40960;
    const float mg = gmax_decode(gmaxkey);
    const float aF = 0.0625f * expf(-mg);
    const float bF = 0.0625f * 1e-4f;
    const int gc = blockIdx.x;
    const u16* Ag = phiKT + (size_t)gc * 32768;
    const u16* Bg = Vt + (size_t)gc * 16384;
    const int tid = threadIdx.x, lane = tid & 63, wave = tid >> 6;
    const int fr = lane & 15, fk = (lane >> 4) * 8;
    const int lr8 = lane >> 3;
    const int cE = ((lane & 7) ^ lr8) << 3;
    {
        float z = 0.f;
        const u16* zp = Ag + (size_t)tid * 128;
        #pragma unroll
        for (int j = 0; j < 16; j++) {
            bf16x8 w = *(const bf16x8*)(zp + j * 8);
            #pragma unroll
            for (int q = 0; q < 8; q++) z += bf2f((u16)w[q]);
        }
        zbuf[(size_t)gc * 256 + tid] = aF * z + bF * 128.0f;
    }
    if (tid < 64) {
        const u16* vh = Bg + (size_t)tid * 128;
        const u16* vl = vh + 8192;
        float s = 0.f;
        #pragma unroll
        for (int j = 0; j < 16; j++) {
            bf16x8 wh = *(const bf16x8*)(vh + j * 8);
            bf16x8 wl = *(const bf16x8*)(vl + j * 8);
            #pragma unroll
            for (int q = 0; q < 8; q++)
                s += bf2f((u16)wh[q]) + bf2f((u16)wl[q]);
        }
        vcs[tid] = s;
    }
    f32x4 acc[4][4] = {};
    for (int kh = 0; kh < 2; kh++) {
        #pragma unroll
        for (int t = 0; t < 8; t++) {
            int i = wave * 8 + t;
            int f = (i << 3) + lr8;
            gload16(Ag + (size_t)f * 128 + kh * 64 + cE, bufA + (i << 10));
        }
        #pragma unroll
        for (int t = 0; t < 2; t++) {
            int i = wave * 2 + t;
            int e = (i << 3) + lr8;
            gload16(Bg + (size_t)e * 128 + kh * 64 + cE, bufBh + (i << 10));
            gload16(Bg + 8192 + (size_t)e * 128 + kh * 64 + cE, bufBl + (i << 10));
        }
        __syncthreads();
        #pragma unroll
        for (int ks = 0; ks < 2; ks++) {
            bf16x8 af[4], bh4[4], bl4[4];
            #pragma unroll
            for (int mf = 0; mf < 4; mf++)
                af[mf] = *(bf16x8*)(bufA + swz(wave * 64 + mf * 16 + fr, ks * 32 + fk, 64));
            #pragma unroll
            for (int nf = 0; nf < 4; nf++) {
                bh4[nf] = *(bf16x8*)(bufBh + swz(nf * 16 + fr, ks * 32 + fk, 64));
                bl4[nf] = *(bf16x8*)(bufBl + swz(nf * 16 + fr, ks * 32 + fk, 64));
            }
            #pragma unroll
            for (int mf = 0; mf < 4; mf++)
                #pragma unroll
                for (int nf = 0; nf < 4; nf++) {
                    acc[mf][nf] = MF(af[mf], bh4[nf], acc[mf][nf]);
                    acc[mf][nf] = MF(af[mf], bl4[nf], acc[mf][nf]);
                }
        }
        __syncthreads();
    }
    #pragma unroll
    for (int mf = 0; mf < 4; mf++) {
        int fb = wave * 64 + mf * 16 + (lane >> 4) * 4;
        #pragma unroll
        for (int nf = 0; nf < 4; nf++) {
            int e = nf * 16 + fr;
            float vb = bF * vcs[e];
            #pragma unroll
            for (int r = 0; r < 4; r++)
                sbuf[(size_t)gc * 16384 + (size_t)(fb + r) * 64 + e] =
                    aF * acc[mf][nf][r] + vb;
        }
    }
}

// ---------- Pass B: exclusive prefix, 256 blocks (16 bh x 16 f-slabs) ----------
__global__ __launch_bounds__(256)
void prefix_scan(const float* __restrict__ sbuf, const float* __restrict__ zbuf,
                 u16* __restrict__ SpT, float* __restrict__ Zp,
                 float* __restrict__ outZ, float* __restrict__ outS)
{
    __shared__ float trans[64 * 17];
    const int bh = blockIdx.x >> 4, f0 = (blockIdx.x & 15) * 16;
    const int tid = threadIdx.x;
    const int e_ = tid >> 2, fl = (tid & 3) * 4;
    float run[4] = {0.f, 0.f, 0.f, 0.f};
    float zrun = 0.f;
    for (int c = 0; c < 32; c++) {
        const int gc = bh * 32 + c;
        const float* base = sbuf + (size_t)gc * 16384 + f0 * 64;
        float v[4];
        #pragma unroll
        for (int i = 0; i < 4; i++) v[i] = base[tid + i * 256];
        #pragma unroll
        for (int i = 0; i < 4; i++) {
            int idx = tid + i * 256;
            trans[(idx & 63) * 17 + (idx >> 6)] = run[i];
        }
        float zv = 0.f;
        if (tid < 16) zv = zbuf[(size_t)gc * 256 + f0 + tid];
        __syncthreads();
        {
            alignas(8) u16 hb[4], lb[4];
            #pragma unroll
            for (int q = 0; q < 4; q++) {
                float vv = trans[e_ * 17 + fl + q];
                u16 hh = f2bf(vv); hb[q] = hh; lb[q] = f2bf(vv - bf2f(hh));
            }
            u16* dh = SpT + (size_t)gc * 32768 + e_ * 256 + f0 + fl;
            *(uint2*)dh = *(uint2*)hb;
            *(uint2*)(dh + 16384) = *(uint2*)lb;
        }
        if (tid < 16) { Zp[(size_t)gc * 256 + f0 + tid] = zrun; zrun += zv; }
        #pragma unroll
        for (int i = 0; i < 4; i++) run[i] += v[i];
        __syncthreads();
    }
    #pragma unroll
    for (int i = 0; i < 4; i++)
        outS[(size_t)bh * 16384 + f0 * 64 + tid + i * 256] = run[i];
    if (tid < 16) outZ[bh * 256 + f0 + tid] = zrun;
}

// ---------- Pass C: aouts = Dinv*(Q@Sprev + tril(a*Q psi^T + b*rowQ)@V) ----------
__global__ __launch_bounds__(256)
void chunk_out_mfma(const u16* __restrict__ phiQ, const u16* __restrict__ psiK,
                    const u16* __restrict__ Vt, const u16* __restrict__ SpT,
                    const float* __restrict__ Zp, const u32* __restrict__ gmaxkey,
                    u16* __restrict__ aouts)
{
    extern __shared__ char sm[];
    char* bufQ = sm;             // [128][64] Q-slab
    char* bufK = sm + 16384;     // [128][64] psi-slab ; later V_hi [64][128] swz
    char* bufA = sm + 32768;     // f0 loop: Sp_hi @+0, Sp_lo @+8192 ; after: A [128][128] swz
    float* Dl = (float*)(sm + 65536);    // [128]
    float* Zl = (float*)(sm + 66048);    // [64]
    float* RowQ = (float*)(sm + 66304);  // [128]
    const float mg = gmax_decode(gmaxkey);
    const float aF = 0.0625f * expf(-mg);
    const float bF = 0.0625f * 1e-4f;
    const int gc = blockIdx.x, c = gc & 31, bh = gc >> 5, b = bh >> 3, h = bh & 7;
    const int row0 = b * 4096 + c * 128;
    const u16* Qg = phiQ + (size_t)row0 * 2048 + h * 256;
    const u16* Kg = psiK + (size_t)row0 * 2048 + h * 256;
    const u16* Vg = Vt + (size_t)gc * 16384;
    const u16* Sg = SpT + (size_t)gc * 32768;
    const float* Zg = Zp + (size_t)gc * 256;
    const int tid = threadIdx.x, lane = tid & 63, wave = tid >> 6;
    const int fr = lane & 15, fk = (lane >> 4) * 8;
    const int dr = tid >> 1, dc = (tid & 1) * 32;
    const int lr8 = lane >> 3;
    const int cE = ((lane & 7) ^ lr8) << 3;

    f32x4 acc2[2][8] = {};
    f32x4 acc1[2][4] = {};
    float dotZ = 0.f, sumQ = 0.f;

    for (int f0 = 0; f0 < 256; f0 += 64) {
        #pragma unroll
        for (int t = 0; t < 4; t++) {
            int i = wave * 4 + t;
            int r = (i << 3) + lr8;
            gload16(Qg + (size_t)r * 2048 + f0 + cE, bufQ + (i << 10));
            gload16(Kg + (size_t)r * 2048 + f0 + cE, bufK + (i << 10));
        }
        #pragma unroll
        for (int t = 0; t < 2; t++) {
            int i = wave * 2 + t;
            int e = (i << 3) + lr8;
            gload16(Sg + (size_t)e * 256 + f0 + cE, bufA + (i << 10));
            gload16(Sg + 16384 + (size_t)e * 256 + f0 + cE, bufA + 8192 + (i << 10));
        }
        if (tid < 64) Zl[tid] = Zg[f0 + tid];
        __syncthreads();
        #pragma unroll
        for (int ks = 0; ks < 2; ks++) {
            bf16x8 af[2];
            af[0] = *(bf16x8*)(bufQ + swz(wave * 32 + fr, ks * 32 + fk, 64));
            af[1] = *(bf16x8*)(bufQ + swz(wave * 32 + 16 + fr, ks * 32 + fk, 64));
            #pragma unroll
            for (int nf = 0; nf < 8; nf++) {
                bf16x8 bv = *(bf16x8*)(bufK + swz(nf * 16 + fr, ks * 32 + fk, 64));
                acc2[0][nf] = MF(af[0], bv, acc2[0][nf]);
                acc2[1][nf] = MF(af[1], bv, acc2[1][nf]);
            }
            #pragma unroll
            for (int nf = 0; nf < 4; nf++) {
                bf16x8 bvh = *(bf16x8*)(bufA + swz(nf * 16 + fr, ks * 32 + fk, 64));
                bf16x8 bvl = *(bf16x8*)(bufA + 8192 + swz(nf * 16 + fr, ks * 32 + fk, 64));
                acc1[0][nf] = MF(af[0], bvh, acc1[0][nf]);
                acc1[1][nf] = MF(af[1], bvh, acc1[1][nf]);
                acc1[0][nf] = MF(af[0], bvl, acc1[0][nf]);
                acc1[1][nf] = MF(af[1], bvl, acc1[1][nf]);
            }
        }
        #pragma unroll
        for (int jj = 0; jj < 4; jj++) {
            bf16x8 qv = *(bf16x8*)(bufQ + swz(dr, dc + jj * 8, 64));
            f32x4 z0 = *(f32x4*)(Zl + dc + jj * 8);
            f32x4 z1 = *(f32x4*)(Zl + dc + jj * 8 + 4);
            #pragma unroll
            for (int q = 0; q < 8; q++) {
                float qf = bf2f((u16)qv[q]);
                sumQ += qf;
                dotZ += qf * (q < 4 ? z0[q] : z1[q - 4]);
            }
        }
        __syncthreads();
    }
    // publish full row sums of phiQ (for A affine correction)
    {
        float rq = sumQ + __shfl_xor(sumQ, 1);
        if ((tid & 1) == 0) RowQ[dr] = rq;
    }
    __syncthreads();
    float4 vvh[4];
    #pragma unroll
    for (int j = 0; j < 4; j++) {
        int ci = tid + j * 256; int e = ci >> 4, cc = (ci & 15) * 8;
        vvh[j] = *(const float4*)(Vg + (size_t)e * 128 + cc);
    }
    #pragma unroll
    for (int mf = 0; mf < 2; mf++) {
        int rb = wave * 32 + mf * 16 + (lane >> 4) * 4;
        #pragma unroll
        for (int nf = 0; nf < 8; nf++) {
            int col = nf * 16 + fr;
            #pragma unroll
            for (int r = 0; r < 4; r++) {
                float v = (col <= rb + r) ? (aF * acc2[mf][nf][r] + bF * RowQ[rb + r]) : 0.f;
                *(u16*)(bufA + swz(rb + r, col, 128)) = f2bf(v);
            }
        }
    }
    #pragma unroll
    for (int j = 0; j < 4; j++) {
        int ci = tid + j * 256; int e = ci >> 4, cc = (ci & 15) * 8;
        *(float4*)(bufK + swz(e, cc, 128)) = vvh[j];
    }
    __syncthreads();
    {
        const int dcA = (tid & 1) * 64;
        float rs = 0.f;
        #pragma unroll
        for (int jj = 0; jj < 8; jj++) {
            bf16x8 av = *(bf16x8*)(bufA + swz(dr, dcA + jj * 8, 128));
            #pragma unroll
            for (int q = 0; q < 8; q++) rs += bf2f((u16)av[q]);
        }
        float tot = rs + dotZ + 1e-6f * sumQ;
        tot += __shfl_xor(tot, 1);
        if ((tid & 1) == 0) Dl[dr] = tot;
    }
    #pragma unroll
    for (int ks = 0; ks < 4; ks++) {
        bf16x8 af[2];
        af[0] = *(bf16x8*)(bufA + swz(wave * 32 + fr, ks * 32 + fk, 128));
        af[1] = *(bf16x8*)(bufA + swz(wave * 32 + 16 + fr, ks * 32 + fk, 128));
        #pragma unroll
        for (int nf = 0; nf < 4; nf++) {
            bf16x8 bvh = *(bf16x8*)(bufK + swz(nf * 16 + fr, ks * 32 + fk, 128));
            acc1[0][nf] = MF(af[0], bvh, acc1[0][nf]);
            acc1[1][nf] = MF(af[1], bvh, acc1[1][nf]);
        }
    }
    __syncthreads();
    float* st = (float*)sm;   // [128][65]
    #pragma unroll
    for (int mf = 0; mf < 2; mf++) {
        int rb = wave * 32 + mf * 16 + (lane >> 4) * 4;
        #pragma unroll
        for (int r = 0; r < 4; r++) {
            float dinv = 1.f / Dl[rb + r];
            #pragma unroll
            for (int nf = 0; nf < 4; nf++)
                st[(rb + r) * 65 + nf * 16 + fr] = acc1[mf][nf][r] * dinv;
        }
    }
    __syncthreads();
    {
        int lr = tid >> 1, e0 = (tid & 1) * 32;
        alignas(16) u16 hb[32];
        #pragma unroll
        for (int q = 0; q < 32; q++) hb[q] = f2bf(st[lr * 65 + e0 + q]);
        u16* d = aouts + (size_t)(row0 + lr) * 512 + h * 64 + e0;
        #pragma unroll
        for (int q = 0; q < 4; q++) *(uint4*)(d + q * 8) = *(uint4*)&hb[q * 8];
    }
}

extern "C" void kernel_launch(void* const* d_in, const int* in_sizes, int n_in,
                              void* d_out, int out_size, void* d_ws, size_t ws_size,
                              hipStream_t stream)
{
    const float* x    = (const float*)d_in[0];
    const float* Wq   = (const float*)d_in[1];
    const float* Wk   = (const float*)d_in[2];
    const float* Wv   = (const float*)d_in[3];
    const float* Wo   = (const float*)d_in[4];
    const float* bo   = (const float*)d_in[5];
    const float* proj = (const float*)d_in[6];
    float* out = (float*)d_out;
    float* ws = (float*)d_ws;

    // layout (float offsets)
    u16*   vpl   = (u16*)ws;                    // [2][8192][512] u16
    float* diagb = ws + 4194304;                // [2][8192][8] f32
    u16*   phi   = (u16*)(ws + 12582912);       // phiQ [8192][2048] | psiK [8192][2048]
    u16*   Vtb   = (u16*)(ws + 37748736);       // [512][2][64][128] u16
    float* sbuf  = ws + 41943040;               // 512*16384 f32
    u16*   qs    = (u16*)(ws + 41943040);       // q|k split u16 (dead after dd_gemm)
    u16*   phiKT = (u16*)(ws + 50331648);       // 512*32768 u16 (dead after chunk_sums)
    u16*   SpT   = (u16*)(ws + 50331648);       //   overlay: written by prefix_scan AFTER chunk_sums
    u16*   xs    = (u16*)(ws + 58720256);       // [8192][1536] u16
    u16*   aouts = xs;                          //   overlay: plain [8192][512] u16
    u16*   Wqkvs = (u16*)(ws + 65011712);       // [1536][1536] u16
    float* zbuf  = ws + 65142784;               //   overlay Wqkvs (dead after qkv_gemm)
    float* Zp    = ws + 65273856;
    u32*   gmax  = (u32*)(ws + 65404928);
    u16*   Wos   = (u16*)(ws + 66191360);       // plain [512][512] u16
    u16*   projs = (u16*)(ws + 66584576);       // [256][192] u16

    float* outO = out;                 // [2,4096,512]
    float* outZ = out + 4194304;       // [2,8,256]
    float* outS = out + 4198400;       // [2,8,256,64]

    dim3 blk(256);

    conv_split<false><<<2048, blk, 0, stream>>>(x, xs, 512, 1048576L, 1.f);
    conv_split<true ><<<256, blk, 0, stream>>>(Wq, Wqkvs, 512, 65536L, 1.f);
    conv_split<true ><<<256, blk, 0, stream>>>(Wk, Wqkvs + 786432, 512, 65536L, 1.f);
    conv_split<true ><<<256, blk, 0, stream>>>(Wv, Wqkvs + 1572864, 512, 65536L, 1.f);
    conv_plain<<<64, blk, 0, stream>>>(Wo, Wos, 65536L);
    conv_split<true ><<<16, blk, 0, stream>>>(proj, projs, 64, 4096L, 1.f);
    // fused QKV projection
    qkv_gemm<<<dim3(64, 12), blk, 0, stream>>>(xs, Wqkvs, qs, diagb, vpl);
    hipMemsetAsync(gmax, 0, 4, stream);
    // merged dd GEMM: q -> phiQ (full feature map); k -> psi = exp(dd - diag) + blockmax
    const u16* ksplit = qs + 12582912;
    u16* psiK = phi + (size_t)8192 * 2048;
    dd_gemm<<<dim3(128, 1, 16), blk, 0, stream>>>(qs, ksplit, projs, diagb, gmax,
                                                  phi, psiK);
    // plain transpose psi -> psiT
    transpose_k<<<512, blk, 0, stream>>>(psiK, phiKT);
    transpose_v<<<512, blk, 0, stream>>>(vpl, Vtb);
    // chunked linear attention (affine-corrected with a = ratio*e^-m, b = ratio*1e-4)
    chunk_sums_mfma<<<512, blk, 0, stream>>>(phiKT, Vtb, gmax, sbuf, zbuf);
    prefix_scan<<<256, blk, 0, stream>>>(sbuf, zbuf, SpT, Zp, outZ, outS);
    hipFuncSetAttribute((const void*)chunk_out_mfma,
                        hipFuncAttributeMaxDynamicSharedMemorySize, 66816);
    chunk_out_mfma<<<512, blk, 66816, stream>>>(phi, psiK, Vtb, SpT, Zp, gmax, aouts);
    // final projection
    proj_gemm<<<dim3(64, 4), blk, 0, stream>>>(aouts, Wos, outO, bo);
}

// Round 19
// 231.415 us; speedup vs baseline: 1.4802x; 1.1055x over previous
//
#include <hip/hip_runtime.h>

typedef unsigned short u16;
typedef unsigned int u32;
typedef __attribute__((ext_vector_type(8))) short bf16x8;
typedef __attribute__((ext_vector_type(4))) float f32x4;

__device__ __forceinline__ u16 f2bf(float f) {
    u32 u = __float_as_uint(f);
    return (u16)((u + 0x7fffu + ((u >> 16) & 1u)) >> 16);
}
__device__ __forceinline__ float bf2f(u16 h) { return __uint_as_float(((u32)h) << 16); }
__device__ __forceinline__ u32 pk(u16 a, u16 b) { return (u32)a | ((u32)b << 16); }
__device__ __forceinline__ int swz(int row, int col, int ld) {
    return ((row * ld + col) * 2) ^ ((row & 7) << 4);
}
__device__ __forceinline__ f32x4 MF(bf16x8 a, bf16x8 b, f32x4 c) {
    return __builtin_amdgcn_mfma_f32_16x16x32_bf16(a, b, c, 0, 0, 0);
}
__device__ __forceinline__ float wave_max(float v) {
    #pragma unroll
    for (int o = 32; o; o >>= 1) v = fmaxf(v, __shfl_xor(v, o));
    return v;
}
__device__ __forceinline__ void gload16(const void* g, void* l) {
    __builtin_amdgcn_global_load_lds(
        (const __attribute__((address_space(1))) void*)g,
        (__attribute__((address_space(3))) void*)l, 16, 0, 0);
}
__device__ __forceinline__ float gmax_decode(const u32* gmaxkey) {
    u32 key = *gmaxkey;
    u32 ub = (key & 0x80000000u) ? (key & 0x7fffffffu) : ~key;
    return __uint_as_float(ub);
}

// ---------- split-bf16 convert: A:[hi|hi|lo]  B:[hi|lo|hi] ----------
template<bool ISB>
__global__ __launch_bounds__(256)
void conv_split(const float* __restrict__ src, u16* __restrict__ dst,
                int K, long total4, float scale)
{
    const int K4 = K >> 2;
    for (long i = (long)blockIdx.x * 256 + threadIdx.x; i < total4;
         i += (long)gridDim.x * 256) {
        long row = i / K4;
        int c = (int)(i - row * K4) * 4;
        float4 v = ((const float4*)src)[i];
        float a0 = v.x * scale, a1 = v.y * scale, a2 = v.z * scale, a3 = v.w * scale;
        u16 h0 = f2bf(a0), h1 = f2bf(a1), h2 = f2bf(a2), h3 = f2bf(a3);
        u16 l0 = f2bf(a0 - bf2f(h0)), l1 = f2bf(a1 - bf2f(h1));
        u16 l2 = f2bf(a2 - bf2f(h2)), l3 = f2bf(a3 - bf2f(h3));
        uint2 hh; hh.x = pk(h0, h1); hh.y = pk(h2, h3);
        uint2 ll; ll.x = pk(l0, l1); ll.y = pk(l2, l3);
        u16* d = dst + row * (3L * K) + c;
        *(uint2*)d = hh;
        *(uint2*)(d + (ISB ? 2 * K : K)) = hh;
        *(uint2*)(d + (ISB ? K : 2 * K)) = ll;
    }
}

// ---------- plain bf16 convert ----------
__global__ __launch_bounds__(256)
void conv_plain(const float* __restrict__ src, u16* __restrict__ dst, long total4)
{
    for (long i = (long)blockIdx.x * 256 + threadIdx.x; i < total4;
         i += (long)gridDim.x * 256) {
        float4 v = ((const float4*)src)[i];
        ushort4 o;
        o.x = f2bf(v.x); o.y = f2bf(v.y); o.z = f2bf(v.z); o.w = f2bf(v.w);
        ((ushort4*)dst)[i] = o;
    }
}

// ---------- fused QKV GEMM, plain bf16 K=512, 128x128 tile, gload staging ----------
// q/k epilogue: split [hi|hi|lo] per head + diag; v -> vpl hi/lo planes
__global__ __launch_bounds__(256, 3)
void qkv_gemm(const u16* __restrict__ A, const u16* __restrict__ B,
              u16* __restrict__ qs, float* __restrict__ diagb,
              u16* __restrict__ vpl)
{
    __shared__ char smem[34816];
    char* As = smem; char* Bs = smem + 16384;
    const int m0 = blockIdx.x * 128, by = blockIdx.y, n0 = by * 128;
    const int tid = threadIdx.x, lane = tid & 63, wave = tid >> 6;
    const int wm = (wave >> 1) * 64, wn = (wave & 1) * 64;
    const int fr = lane & 15, fk = (lane >> 4) * 8;
    const int lr8 = lane >> 3;
    const int cE = ((lane & 7) ^ lr8) << 3;
    f32x4 acc[4][4] = {};
    for (int k0 = 0; k0 < 512; k0 += 64) {
        #pragma unroll
        for (int t = 0; t < 4; t++) {
            int i = wave * 4 + t;
            int r = (i << 3) + lr8;
            gload16(A + (size_t)(m0 + r) * 512 + k0 + cE, As + (i << 10));
            gload16(B + (size_t)(n0 + r) * 512 + k0 + cE, Bs + (i << 10));
        }
        __syncthreads();
        #pragma unroll
        for (int ks = 0; ks < 2; ks++) {
            bf16x8 af[4], bfv[4];
            #pragma unroll
            for (int mf = 0; mf < 4; mf++)
                af[mf] = *(bf16x8*)(As + swz(wm + mf * 16 + fr, ks * 32 + fk, 64));
            #pragma unroll
            for (int nf = 0; nf < 4; nf++)
                bfv[nf] = *(bf16x8*)(Bs + swz(wn + nf * 16 + fr, ks * 32 + fk, 64));
            #pragma unroll
            for (int mf = 0; mf < 4; mf++)
                #pragma unroll
                for (int nf = 0; nf < 4; nf++)
                    acc[mf][nf] = MF(af[mf], bfv[nf], acc[mf][nf]);
        }
        __syncthreads();
    }
    const float dn = 0.35355339059327373f;
    const int sel = by >> 2;        // 0=q,1=k,2=v
    float* st = (float*)smem;       // [64][130]
    for (int half = 0; half < 2; half++) {
        __syncthreads();
        if ((wave >> 1) == half) {
            #pragma unroll
            for (int mf = 0; mf < 4; mf++) {
                int lr = mf * 16 + (lane >> 4) * 4;
                #pragma unroll
                for (int nf = 0; nf < 4; nf++) {
                    int col = wn + nf * 16 + fr;
                    #pragma unroll
                    for (int r = 0; r < 4; r++)
                        st[(lr + r) * 130 + col] = acc[mf][nf][r];
                }
            }
        }
        __syncthreads();
        int grow = m0 + half * 64 + (tid >> 2);
        if (sel < 2) {
            int hl = (tid >> 1) & 1, e0 = (tid & 1) * 32;
            int h = (by & 3) * 2 + hl;
            alignas(16) u16 hbuf[32], lbuf[32];
            float ss = 0.f;
            #pragma unroll
            for (int q = 0; q < 32; q++) {
                float v = dn * st[(tid >> 2) * 130 + hl * 64 + e0 + q];
                ss += v * v;
                u16 hh = f2bf(v); hbuf[q] = hh; lbuf[q] = f2bf(v - bf2f(hh));
            }
            ss += __shfl_xor(ss, 1);
            if ((tid & 1) == 0)
                diagb[(size_t)sel * 65536 + grow * 8 + h] = 0.5f * ss;
            u16* d = qs + (size_t)sel * 12582912 + (size_t)grow * 1536 + h * 192 + e0;
            #pragma unroll
            for (int q = 0; q < 4; q++) *(uint4*)(d + q * 8) = *(uint4*)&hbuf[q * 8];
            #pragma unroll
            for (int q = 0; q < 4; q++) *(uint4*)(d + 64 + q * 8) = *(uint4*)&hbuf[q * 8];
            #pragma unroll
            for (int q = 0; q < 4; q++) *(uint4*)(d + 128 + q * 8) = *(uint4*)&lbuf[q * 8];
        } else {
            int e0 = (tid & 3) * 32;
            int colbase = (by & 3) * 128 + e0;
            alignas(16) u16 hbuf[32], lbuf[32];
            #pragma unroll
            for (int q = 0; q < 32; q++) {
                float v = st[(tid >> 2) * 130 + e0 + q];
                u16 hh = f2bf(v); hbuf[q] = hh; lbuf[q] = f2bf(v - bf2f(hh));
            }
            u16* dh = vpl + (size_t)grow * 512 + colbase;
            u16* dl = dh + 4194304;
            #pragma unroll
            for (int q = 0; q < 4; q++) *(uint4*)(dh + q * 8) = *(uint4*)&hbuf[q * 8];
            #pragma unroll
            for (int q = 0; q < 4; q++) *(uint4*)(dl + q * 8) = *(uint4*)&lbuf[q * 8];
        }
    }
}

// ---------- merged dd GEMM, 64x256 per head, grid (128,1,16) ----------
// z<8: q path h=z: phiQ = ratio*(exp(dd - diag - rowmax) + 1e-4)
// z>=8: k path h=z-8: psi = exp(dd - diag), single pass; blockmax -> gmax (publishes m)
__global__ __launch_bounds__(256, 3)
void dd_gemm(const u16* __restrict__ Aq, const u16* __restrict__ Ak,
             const u16* __restrict__ Bp,
             const float* __restrict__ diagb, u32* __restrict__ gmax,
             u16* __restrict__ phiQ, u16* __restrict__ psiK)
{
    __shared__ char sm_[42240];
    char* As = sm_;                       // [64][64] u16 (8K, linear gload dest)
    char* Bs = sm_ + 8192;                // [256][64] u16 (32K)
    float* red  = (float*)(sm_ + 40960);  // [64][4]
    float* srow = (float*)(sm_ + 41984);  // [64]
    const int isq = (blockIdx.z < 8);
    const int h = isq ? blockIdx.z : (blockIdx.z - 8);
    const int m0 = blockIdx.x * 64;
    const u16* Ag = (isq ? Aq : Ak) + (size_t)m0 * 1536 + h * 192;
    const int tid = threadIdx.x, lane = tid & 63, wave = tid >> 6;
    const int wn = wave * 64;
    const int fr = lane & 15, fk = (lane >> 4) * 8;
    const int lr8 = lane >> 3;
    const int cE = ((lane & 7) ^ lr8) << 3;
    f32x4 acc[4][4] = {};
    for (int k0 = 0; k0 < 192; k0 += 64) {
        #pragma unroll
        for (int t = 0; t < 2; t++) {
            int i = wave * 2 + t;
            int r = (i << 3) + lr8;
            gload16(Ag + (size_t)r * 1536 + k0 + cE, As + (i << 10));
        }
        #pragma unroll
        for (int t = 0; t < 8; t++) {
            int i = wave * 8 + t;
            int r = (i << 3) + lr8;
            gload16(Bp + (size_t)r * 192 + k0 + cE, Bs + (i << 10));
        }
        __syncthreads();
        #pragma unroll
        for (int ks = 0; ks < 2; ks++) {
            bf16x8 af[4], bf4[4];
            #pragma unroll
            for (int mf = 0; mf < 4; mf++)
                af[mf] = *(bf16x8*)(As + swz(mf * 16 + fr, ks * 32 + fk, 64));
            #pragma unroll
            for (int nf = 0; nf < 4; nf++)
                bf4[nf] = *(bf16x8*)(Bs + swz(wn + nf * 16 + fr, ks * 32 + fk, 64));
            #pragma unroll
            for (int mf = 0; mf < 4; mf++)
                #pragma unroll
                for (int nf = 0; nf < 4; nf++)
                    acc[mf][nf] = MF(af[mf], bf4[nf], acc[mf][nf]);
        }
        __syncthreads();
    }

    if (!isq) {
        float mx = -1e30f;
        #pragma unroll
        for (int mf = 0; mf < 4; mf++)
            #pragma unroll
            for (int nf = 0; nf < 4; nf++)
                #pragma unroll
                for (int r = 0; r < 4; r++) mx = fmaxf(mx, acc[mf][nf][r]);
        mx = wave_max(mx);
        __syncthreads();
        if (lane == 0) red[wave] = mx;
        __syncthreads();
        if (tid == 0) {
            float m4 = fmaxf(fmaxf(red[0], red[1]), fmaxf(red[2], red[3]));
            u32 u = __float_as_uint(m4);
            u32 key = (u & 0x80000000u) ? ~u : (u | 0x80000000u);
            atomicMax(gmax, key);
        }
        if (tid < 64)
            srow[tid] = diagb[65536 + (size_t)(m0 + tid) * 8 + h];
    } else {
        float rm[4][4];
        #pragma unroll
        for (int mf = 0; mf < 4; mf++)
            #pragma unroll
            for (int r = 0; r < 4; r++) {
                float m = acc[mf][0][r];
                m = fmaxf(m, acc[mf][1][r]);
                m = fmaxf(m, acc[mf][2][r]);
                m = fmaxf(m, acc[mf][3][r]);
                #pragma unroll
                for (int o = 1; o < 16; o <<= 1) m = fmaxf(m, __shfl_xor(m, o));
                rm[mf][r] = m;
            }
        __syncthreads();
        if ((lane & 15) == 0) {
            #pragma unroll
            for (int mf = 0; mf < 4; mf++)
                #pragma unroll
                for (int r = 0; r < 4; r++)
                    red[(mf * 16 + (lane >> 4) * 4 + r) * 4 + wave] = rm[mf][r];
        }
        __syncthreads();
        if (tid < 64) {
            float m4 = fmaxf(fmaxf(red[tid * 4], red[tid * 4 + 1]),
                             fmaxf(red[tid * 4 + 2], red[tid * 4 + 3]));
            srow[tid] = m4 + diagb[(size_t)(m0 + tid) * 8 + h];
        }
    }
    // single-pass staging + dense writes
    u16* stg = (u16*)sm_;    // [64][264]
    __syncthreads();
    #pragma unroll
    for (int mf = 0; mf < 4; mf++)
        #pragma unroll
        for (int r = 0; r < 4; r++) {
            int row = mf * 16 + (lane >> 4) * 4 + r;
            float s = srow[row];
            #pragma unroll
            for (int nf = 0; nf < 4; nf++) {
                float v = acc[mf][nf][r];
                u16 o = isq ? f2bf(0.0625f * (expf(v - s) + 1e-4f))
                            : f2bf(expf(v - s));
                stg[row * 264 + wn + nf * 16 + fr] = o;
            }
        }
    __syncthreads();
    {
        int lr = tid >> 2, c0 = (tid & 3) * 64;
        u16* base = isq ? phiQ : psiK;
        u16* dst = base + (size_t)(m0 + lr) * 2048 + h * 256 + c0;
        #pragma unroll
        for (int q = 0; q < 8; q++)
            *(uint4*)(dst + q * 8) = *(uint4*)(stg + lr * 264 + c0 + q * 8);
    }
}

// ---------- merged transpose: bid<512 psiK -> psiKT ; bid>=512 vpl -> Vt ----------
__global__ __launch_bounds__(256)
void transpose_kv(const u16* __restrict__ phiK, u16* __restrict__ phiKT,
                  const u16* __restrict__ vpl, u16* __restrict__ Vt)
{
    __shared__ u16 tr[64 * 136];
    const int isk = (blockIdx.x < 512);
    const int gc = isk ? blockIdx.x : (blockIdx.x - 512);
    const int c = gc & 31, bh = gc >> 5, b = bh >> 3, h = bh & 7;
    const int row0 = b * 4096 + c * 128;
    const int tid = threadIdx.x;
    if (isk) {
        const u16* src = phiK + (size_t)row0 * 2048 + h * 256;
        u16* dst = phiKT + (size_t)gc * 32768;
        for (int f0 = 0; f0 < 256; f0 += 64) {
            #pragma unroll
            for (int j = 0; j < 4; j++) {
                int ci = tid + j * 256; int r = ci >> 3, ff = (ci & 7) * 8;
                bf16x8 w = *(const bf16x8*)(src + (size_t)r * 2048 + f0 + ff);
                #pragma unroll
                for (int q = 0; q < 8; q++) tr[(ff + q) * 136 + r] = (u16)w[q];
            }
            __syncthreads();
            {
                int f = tid >> 2, r0 = (tid & 3) * 32;
                uint4 a0 = *(uint4*)&tr[f * 136 + r0];
                uint4 a1 = *(uint4*)&tr[f * 136 + r0 + 8];
                uint4 a2 = *(uint4*)&tr[f * 136 + r0 + 16];
                uint4 a3 = *(uint4*)&tr[f * 136 + r0 + 24];
                u16* dp = dst + (size_t)(f0 + f) * 128 + r0;
                *(uint4*)dp = a0; *(uint4*)(dp + 8) = a1;
                *(uint4*)(dp + 16) = a2; *(uint4*)(dp + 24) = a3;
            }
            __syncthreads();
        }
    } else {
        u16* dstb = Vt + (size_t)gc * 16384;
        for (int pl = 0; pl < 2; pl++) {
            if (pl) __syncthreads();
            const u16* src = vpl + (size_t)pl * 4194304 + (size_t)row0 * 512 + h * 64;
            #pragma unroll
            for (int j = 0; j < 8; j++) {
                int ci = tid + j * 256; int r = ci >> 4, e = (ci & 15) * 4;
                ushort4 v = *(const ushort4*)(src + (size_t)r * 512 + e);
                tr[(e + 0) * 136 + r] = v.x;
                tr[(e + 1) * 136 + r] = v.y;
                tr[(e + 2) * 136 + r] = v.z;
                tr[(e + 3) * 136 + r] = v.w;
            }
            __syncthreads();
            int e = tid >> 2, r0 = (tid & 3) * 32;
            u16* dst = dstb + pl * 8192;
            #pragma unroll
            for (int q = 0; q < 4; q++) {
                uint4 a = *(uint4*)&tr[e * 136 + r0 + q * 8];
                *(uint4*)(dst + (size_t)e * 128 + r0 + q * 8) = a;
            }
        }
    }
}

// ---------- final projection GEMM: plain bf16, K=512, gload staging ----------
__global__ __launch_bounds__(256, 3)
void proj_gemm(const u16* __restrict__ A, const u16* __restrict__ B,
               float* __restrict__ C, const float* __restrict__ bias)
{
    __shared__ char smem[34816];
    char* As = smem; char* Bs = smem + 16384;
    const int m0 = blockIdx.x * 128, n0 = blockIdx.y * 128;
    const int tid = threadIdx.x, lane = tid & 63, wave = tid >> 6;
    const int wm = (wave >> 1) * 64, wn = (wave & 1) * 64;
    const int fr = lane & 15, fk = (lane >> 4) * 8;
    const int lr8 = lane >> 3;
    const int cE = ((lane & 7) ^ lr8) << 3;
    f32x4 acc[4][4] = {};
    for (int k0 = 0; k0 < 512; k0 += 64) {
        #pragma unroll
        for (int t = 0; t < 4; t++) {
            int i = wave * 4 + t;
            int r = (i << 3) + lr8;
            gload16(A + (size_t)(m0 + r) * 512 + k0 + cE, As + (i << 10));
            gload16(B + (size_t)(n0 + r) * 512 + k0 + cE, Bs + (i << 10));
        }
        __syncthreads();
        #pragma unroll
        for (int ks = 0; ks < 2; ks++) {
            bf16x8 af[4], bfv[4];
            #pragma unroll
            for (int mf = 0; mf < 4; mf++)
                af[mf] = *(bf16x8*)(As + swz(wm + mf * 16 + fr, ks * 32 + fk, 64));
            #pragma unroll
            for (int nf = 0; nf < 4; nf++)
                bfv[nf] = *(bf16x8*)(Bs + swz(wn + nf * 16 + fr, ks * 32 + fk, 64));
            #pragma unroll
            for (int mf = 0; mf < 4; mf++)
                #pragma unroll
                for (int nf = 0; nf < 4; nf++)
                    acc[mf][nf] = MF(af[mf], bfv[nf], acc[mf][nf]);
        }
        __syncthreads();
    }
    float* st = (float*)smem;   // [64][130]
    for (int half = 0; half < 2; half++) {
        __syncthreads();
        if ((wave >> 1) == half) {
            #pragma unroll
            for (int mf = 0; mf < 4; mf++) {
                int lr = mf * 16 + (lane >> 4) * 4;
                #pragma unroll
                for (int nf = 0; nf < 4; nf++) {
                    int col = wn + nf * 16 + fr;
                    #pragma unroll
                    for (int r = 0; r < 4; r++)
                        st[(lr + r) * 130 + col] = acc[mf][nf][r];
                }
            }
        }
        __syncthreads();
        int lr = tid >> 2, c0 = (tid & 3) * 32;
        int grow = m0 + half * 64 + lr;
        float* dst = C + (size_t)grow * 512 + n0 + c0;
        #pragma unroll
        for (int q = 0; q < 8; q++) {
            float4 v;
            v.x = st[lr * 130 + c0 + q * 4 + 0] + bias[n0 + c0 + q * 4 + 0];
            v.y = st[lr * 130 + c0 + q * 4 + 1] + bias[n0 + c0 + q * 4 + 1];
            v.z = st[lr * 130 + c0 + q * 4 + 2] + bias[n0 + c0 + q * 4 + 2];
            v.w = st[lr * 130 + c0 + q * 4 + 3] + bias[n0 + c0 + q * 4 + 3];
            *(float4*)(dst + q * 4) = v;
        }
    }
}

// ---------- Pass A: S = a*(psi^T(Vhi+Vlo)) + b*Vcsum, Z = a*colsum(psi) + 128b ----------
__global__ __launch_bounds__(256)
void chunk_sums_mfma(const u16* __restrict__ phiKT, const u16* __restrict__ Vt,
                     const u32* __restrict__ gmaxkey,
                     float* __restrict__ sbuf, float* __restrict__ zbuf)
{
    __shared__ char smem[49152];
    __shared__ float vcs[64];
    char* bufA = smem;            // [256 f][64 r]
    char* bufBh = smem + 32768;   // [64 e][64 r]
    char* bufBl = smem + 40960;
    const float mg = gmax_decode(gmaxkey);
    const float aF = 0.0625f * expf(-mg);
    const float bF = 0.0625f * 1e-4f;
    const int gc = blockIdx.x;
    const u16* Ag = phiKT + (size_t)gc * 32768;
    const u16* Bg = Vt + (size_t)gc * 16384;
    const int tid = threadIdx.x, lane = tid & 63, wave = tid >> 6;
    const int fr = lane & 15, fk = (lane >> 4) * 8;
    const int lr8 = lane >> 3;
    const int cE = ((lane & 7) ^ lr8) << 3;
    {
        float z = 0.f;
        const u16* zp = Ag + (size_t)tid * 128;
        #pragma unroll
        for (int j = 0; j < 16; j++) {
            bf16x8 w = *(const bf16x8*)(zp + j * 8);
            #pragma unroll
            for (int q = 0; q < 8; q++) z += bf2f((u16)w[q]);
        }
        zbuf[(size_t)gc * 256 + tid] = aF * z + bF * 128.0f;
    }
    if (tid < 64) {
        const u16* vh = Bg + (size_t)tid * 128;
        const u16* vl = vh + 8192;
        float s = 0.f;
        #pragma unroll
        for (int j = 0; j < 16; j++) {
            bf16x8 wh = *(const bf16x8*)(vh + j * 8);
            bf16x8 wl = *(const bf16x8*)(vl + j * 8);
            #pragma unroll
            for (int q = 0; q < 8; q++)
                s += bf2f((u16)wh[q]) + bf2f((u16)wl[q]);
        }
        vcs[tid] = s;
    }
    f32x4 acc[4][4] = {};
    for (int kh = 0; kh < 2; kh++) {
        #pragma unroll
        for (int t = 0; t < 8; t++) {
            int i = wave * 8 + t;
            int f = (i << 3) + lr8;
            gload16(Ag + (size_t)f * 128 + kh * 64 + cE, bufA + (i << 10));
        }
        #pragma unroll
        for (int t = 0; t < 2; t++) {
            int i = wave * 2 + t;
            int e = (i << 3) + lr8;
            gload16(Bg + (size_t)e * 128 + kh * 64 + cE, bufBh + (i << 10));
            gload16(Bg + 8192 + (size_t)e * 128 + kh * 64 + cE, bufBl + (i << 10));
        }
        __syncthreads();
        #pragma unroll
        for (int ks = 0; ks < 2; ks++) {
            bf16x8 af[4], bh4[4], bl4[4];
            #pragma unroll
            for (int mf = 0; mf < 4; mf++)
                af[mf] = *(bf16x8*)(bufA + swz(wave * 64 + mf * 16 + fr, ks * 32 + fk, 64));
            #pragma unroll
            for (int nf = 0; nf < 4; nf++) {
                bh4[nf] = *(bf16x8*)(bufBh + swz(nf * 16 + fr, ks * 32 + fk, 64));
                bl4[nf] = *(bf16x8*)(bufBl + swz(nf * 16 + fr, ks * 32 + fk, 64));
            }
            #pragma unroll
            for (int mf = 0; mf < 4; mf++)
                #pragma unroll
                for (int nf = 0; nf < 4; nf++) {
                    acc[mf][nf] = MF(af[mf], bh4[nf], acc[mf][nf]);
                    acc[mf][nf] = MF(af[mf], bl4[nf], acc[mf][nf]);
                }
        }
        __syncthreads();
    }
    #pragma unroll
    for (int mf = 0; mf < 4; mf++) {
        int fb = wave * 64 + mf * 16 + (lane >> 4) * 4;
        #pragma unroll
        for (int nf = 0; nf < 4; nf++) {
            int e = nf * 16 + fr;
            float vb = bF * vcs[e];
            #pragma unroll
            for (int r = 0; r < 4; r++)
                sbuf[(size_t)gc * 16384 + (size_t)(fb + r) * 64 + e] =
                    aF * acc[mf][nf][r] + vb;
        }
    }
}

// ---------- Pass B: exclusive prefix, 256 blocks (16 bh x 16 f-slabs) ----------
__global__ __launch_bounds__(256)
void prefix_scan(const float* __restrict__ sbuf, const float* __restrict__ zbuf,
                 u16* __restrict__ SpT, float* __restrict__ Zp,
                 float* __restrict__ outZ, float* __restrict__ outS)
{
    __shared__ float trans[64 * 17];
    const int bh = blockIdx.x >> 4, f0 = (blockIdx.x & 15) * 16;
    const int tid = threadIdx.x;
    const int e_ = tid >> 2, fl = (tid & 3) * 4;
    float run[4] = {0.f, 0.f, 0.f, 0.f};
    float zrun = 0.f;
    for (int c = 0; c < 32; c++) {
        const int gc = bh * 32 + c;
        const float* base = sbuf + (size_t)gc * 16384 + f0 * 64;
        float v[4];
        #pragma unroll
        for (int i = 0; i < 4; i++) v[i] = base[tid + i * 256];
        #pragma unroll
        for (int i = 0; i < 4; i++) {
            int idx = tid + i * 256;
            trans[(idx & 63) * 17 + (idx >> 6)] = run[i];
        }
        float zv = 0.f;
        if (tid < 16) zv = zbuf[(size_t)gc * 256 + f0 + tid];
        __syncthreads();
        {
            alignas(8) u16 hb[4], lb[4];
            #pragma unroll
            for (int q = 0; q < 4; q++) {
                float vv = trans[e_ * 17 + fl + q];
                u16 hh = f2bf(vv); hb[q] = hh; lb[q] = f2bf(vv - bf2f(hh));
            }
            u16* dh = SpT + (size_t)gc * 32768 + e_ * 256 + f0 + fl;
            *(uint2*)dh = *(uint2*)hb;
            *(uint2*)(dh + 16384) = *(uint2*)lb;
        }
        if (tid < 16) { Zp[(size_t)gc * 256 + f0 + tid] = zrun; zrun += zv; }
        #pragma unroll
        for (int i = 0; i < 4; i++) run[i] += v[i];
        __syncthreads();
    }
    #pragma unroll
    for (int i = 0; i < 4; i++)
        outS[(size_t)bh * 16384 + f0 * 64 + tid + i * 256] = run[i];
    if (tid < 16) outZ[bh * 256 + f0 + tid] = zrun;
}

// ---------- Pass C: aouts = Dinv*(Q@Sprev + tril(a*Q psi^T + b*rowQ)@V) ----------
__global__ __launch_bounds__(256)
void chunk_out_mfma(const u16* __restrict__ phiQ, const u16* __restrict__ psiK,
                    const u16* __restrict__ Vt, const u16* __restrict__ SpT,
                    const float* __restrict__ Zp, const u32* __restrict__ gmaxkey,
                    u16* __restrict__ aouts)
{
    extern __shared__ char sm[];
    char* bufQ = sm;             // [128][64] Q-slab
    char* bufK = sm + 16384;     // [128][64] psi-slab ; later V_hi [64][128] swz
    char* bufA = sm + 32768;     // f0 loop: Sp_hi @+0, Sp_lo @+8192 ; after: A [128][128] swz
    float* Dl = (float*)(sm + 65536);    // [128]
    float* Zl = (float*)(sm + 66048);    // [64]
    float* RowQ = (float*)(sm + 66304);  // [128]
    const float mg = gmax_decode(gmaxkey);
    const float aF = 0.0625f * expf(-mg);
    const float bF = 0.0625f * 1e-4f;
    const int gc = blockIdx.x, c = gc & 31, bh = gc >> 5, b = bh >> 3, h = bh & 7;
    const int row0 = b * 4096 + c * 128;
    const u16* Qg = phiQ + (size_t)row0 * 2048 + h * 256;
    const u16* Kg = psiK + (size_t)row0 * 2048 + h * 256;
    const u16* Vg = Vt + (size_t)gc * 16384;
    const u16* Sg = SpT + (size_t)gc * 32768;
    const float* Zg = Zp + (size_t)gc * 256;
    const int tid = threadIdx.x, lane = tid & 63, wave = tid >> 6;
    const int fr = lane & 15, fk = (lane >> 4) * 8;
    const int dr = tid >> 1, dc = (tid & 1) * 32;
    const int lr8 = lane >> 3;
    const int cE = ((lane & 7) ^ lr8) << 3;

    f32x4 acc2[2][8] = {};
    f32x4 acc1[2][4] = {};
    float dotZ = 0.f, sumQ = 0.f;

    for (int f0 = 0; f0 < 256; f0 += 64) {
        #pragma unroll
        for (int t = 0; t < 4; t++) {
            int i = wave * 4 + t;
            int r = (i << 3) + lr8;
            gload16(Qg + (size_t)r * 2048 + f0 + cE, bufQ + (i << 10));
            gload16(Kg + (size_t)r * 2048 + f0 + cE, bufK + (i << 10));
        }
        #pragma unroll
        for (int t = 0; t < 2; t++) {
            int i = wave * 2 + t;
            int e = (i << 3) + lr8;
            gload16(Sg + (size_t)e * 256 + f0 + cE, bufA + (i << 10));
            gload16(Sg + 16384 + (size_t)e * 256 + f0 + cE, bufA + 8192 + (i << 10));
        }
        if (tid < 64) Zl[tid] = Zg[f0 + tid];
        __syncthreads();
        #pragma unroll
        for (int ks = 0; ks < 2; ks++) {
            bf16x8 af[2];
            af[0] = *(bf16x8*)(bufQ + swz(wave * 32 + fr, ks * 32 + fk, 64));
            af[1] = *(bf16x8*)(bufQ + swz(wave * 32 + 16 + fr, ks * 32 + fk, 64));
            #pragma unroll
            for (int nf = 0; nf < 8; nf++) {
                bf16x8 bv = *(bf16x8*)(bufK + swz(nf * 16 + fr, ks * 32 + fk, 64));
                acc2[0][nf] = MF(af[0], bv, acc2[0][nf]);
                acc2[1][nf] = MF(af[1], bv, acc2[1][nf]);
            }
            #pragma unroll
            for (int nf = 0; nf < 4; nf++) {
                bf16x8 bvh = *(bf16x8*)(bufA + swz(nf * 16 + fr, ks * 32 + fk, 64));
                bf16x8 bvl = *(bf16x8*)(bufA + 8192 + swz(nf * 16 + fr, ks * 32 + fk, 64));
                acc1[0][nf] = MF(af[0], bvh, acc1[0][nf]);
                acc1[1][nf] = MF(af[1], bvh, acc1[1][nf]);
                acc1[0][nf] = MF(af[0], bvl, acc1[0][nf]);
                acc1[1][nf] = MF(af[1], bvl, acc1[1][nf]);
            }
        }
        #pragma unroll
        for (int jj = 0; jj < 4; jj++) {
            bf16x8 qv = *(bf16x8*)(bufQ + swz(dr, dc + jj * 8, 64));
            f32x4 z0 = *(f32x4*)(Zl + dc + jj * 8);
            f32x4 z1 = *(f32x4*)(Zl + dc + jj * 8 + 4);
            #pragma unroll
            for (int q = 0; q < 8; q++) {
                float qf = bf2f((u16)qv[q]);
                sumQ += qf;
                dotZ += qf * (q < 4 ? z0[q] : z1[q - 4]);
            }
        }
        __syncthreads();
    }
    // publish full row sums of phiQ (for A affine correction)
    {
        float rq = sumQ + __shfl_xor(sumQ, 1);
        if ((tid & 1) == 0) RowQ[dr] = rq;
    }
    __syncthreads();
    float4 vvh[4];
    #pragma unroll
    for (int j = 0; j < 4; j++) {
        int ci = tid + j * 256; int e = ci >> 4, cc = (ci & 15) * 8;
        vvh[j] = *(const float4*)(Vg + (size_t)e * 128 + cc);
    }
    #pragma unroll
    for (int mf = 0; mf < 2; mf++) {
        int rb = wave * 32 + mf * 16 + (lane >> 4) * 4;
        #pragma unroll
        for (int nf = 0; nf < 8; nf++) {
            int col = nf * 16 + fr;
            #pragma unroll
            for (int r = 0; r < 4; r++) {
                float v = (col <= rb + r) ? (aF * acc2[mf][nf][r] + bF * RowQ[rb + r]) : 0.f;
                *(u16*)(bufA + swz(rb + r, col, 128)) = f2bf(v);
            }
        }
    }
    #pragma unroll
    for (int j = 0; j < 4; j++) {
        int ci = tid + j * 256; int e = ci >> 4, cc = (ci & 15) * 8;
        *(float4*)(bufK + swz(e, cc, 128)) = vvh[j];
    }
    __syncthreads();
    {
        const int dcA = (tid & 1) * 64;
        float rs = 0.f;
        #pragma unroll
        for (int jj = 0; jj < 8; jj++) {
            bf16x8 av = *(bf16x8*)(bufA + swz(dr, dcA + jj * 8, 128));
            #pragma unroll
            for (int q = 0; q < 8; q++) rs += bf2f((u16)av[q]);
        }
        float tot = rs + dotZ + 1e-6f * sumQ;
        tot += __shfl_xor(tot, 1);
        if ((tid & 1) == 0) Dl[dr] = tot;
    }
    #pragma unroll
    for (int ks = 0; ks < 4; ks++) {
        bf16x8 af[2];
        af[0] = *(bf16x8*)(bufA + swz(wave * 32 + fr, ks * 32 + fk, 128));
        af[1] = *(bf16x8*)(bufA + swz(wave * 32 + 16 + fr, ks * 32 + fk, 128));
        #pragma unroll
        for (int nf = 0; nf < 4; nf++) {
            bf16x8 bvh = *(bf16x8*)(bufK + swz(nf * 16 + fr, ks * 32 + fk, 128));
            acc1[0][nf] = MF(af[0], bvh, acc1[0][nf]);
            acc1[1][nf] = MF(af[1], bvh, acc1[1][nf]);
        }
    }
    __syncthreads();
    float* st = (float*)sm;   // [128][65]
    #pragma unroll
    for (int mf = 0; mf < 2; mf++) {
        int rb = wave * 32 + mf * 16 + (lane >> 4) * 4;
        #pragma unroll
        for (int r = 0; r < 4; r++) {
            float dinv = 1.f / Dl[rb + r];
            #pragma unroll
            for (int nf = 0; nf < 4; nf++)
                st[(rb + r) * 65 + nf * 16 + fr] = acc1[mf][nf][r] * dinv;
        }
    }
    __syncthreads();
    {
        int lr = tid >> 1, e0 = (tid & 1) * 32;
        alignas(16) u16 hb[32];
        #pragma unroll
        for (int q = 0; q < 32; q++) hb[q] = f2bf(st[lr * 65 + e0 + q]);
        u16* d = aouts + (size_t)(row0 + lr) * 512 + h * 64 + e0;
        #pragma unroll
        for (int q = 0; q < 4; q++) *(uint4*)(d + q * 8) = *(uint4*)&hb[q * 8];
    }
}

extern "C" void kernel_launch(void* const* d_in, const int* in_sizes, int n_in,
                              void* d_out, int out_size, void* d_ws, size_t ws_size,
                              hipStream_t stream)
{
    const float* x    = (const float*)d_in[0];
    const float* Wq   = (const float*)d_in[1];
    const float* Wk   = (const float*)d_in[2];
    const float* Wv   = (const float*)d_in[3];
    const float* Wo   = (const float*)d_in[4];
    const float* bo   = (const float*)d_in[5];
    const float* proj = (const float*)d_in[6];
    float* out = (float*)d_out;
    float* ws = (float*)d_ws;

    // layout (float offsets)
    u16*   vpl   = (u16*)ws;                    // [2][8192][512] u16
    float* diagb = ws + 4194304;                // [2][8192][8] f32
    u16*   phi   = (u16*)(ws + 12582912);       // phiQ [8192][2048] | psiK [8192][2048]
    u16*   Vtb   = (u16*)(ws + 37748736);       // [512][2][64][128] u16
    float* sbuf  = ws + 41943040;               // 512*16384 f32
    u16*   qs    = (u16*)(ws + 41943040);       // q|k split u16 (dead after dd_gemm)
    u16*   phiKT = (u16*)(ws + 50331648);       // 512*32768 u16 (dead after chunk_sums)
    u16*   SpT   = (u16*)(ws + 50331648);       //   overlay: written by prefix_scan AFTER chunk_sums
    u16*   xs    = (u16*)(ws + 58720256);       // plain [8192][512] u16
    u16*   aouts = xs;                          //   overlay: plain [8192][512] u16
    u16*   Wqkvs = (u16*)(ws + 65011712);       // plain [1536][512] u16
    float* zbuf  = ws + 65142784;               //   overlay tail (dead after qkv_gemm)
    float* Zp    = ws + 65273856;
    u32*   gmax  = (u32*)(ws + 65404928);
    u16*   Wos   = (u16*)(ws + 66191360);       // plain [512][512] u16
    u16*   projs = (u16*)(ws + 66584576);       // [256][192] u16

    float* outO = out;                 // [2,4096,512]
    float* outZ = out + 4194304;       // [2,8,256]
    float* outS = out + 4198400;       // [2,8,256,64]

    dim3 blk(256);

    conv_plain<<<1024, blk, 0, stream>>>(x, xs, 1048576L);
    conv_plain<<<64, blk, 0, stream>>>(Wq, Wqkvs, 65536L);
    conv_plain<<<64, blk, 0, stream>>>(Wk, Wqkvs + 262144, 65536L);
    conv_plain<<<64, blk, 0, stream>>>(Wv, Wqkvs + 524288, 65536L);
    conv_plain<<<64, blk, 0, stream>>>(Wo, Wos, 65536L);
    conv_split<true ><<<16, blk, 0, stream>>>(proj, projs, 64, 4096L, 1.f);
    // fused QKV projection (plain bf16, K=512)
    qkv_gemm<<<dim3(64, 12), blk, 0, stream>>>(xs, Wqkvs, qs, diagb, vpl);
    hipMemsetAsync(gmax, 0, 4, stream);
    // merged dd GEMM: q -> phiQ (full feature map); k -> psi = exp(dd - diag) + blockmax
    const u16* ksplit = qs + 12582912;
    u16* psiK = phi + (size_t)8192 * 2048;
    dd_gemm<<<dim3(128, 1, 16), blk, 0, stream>>>(qs, ksplit, projs, diagb, gmax,
                                                  phi, psiK);
    // merged transpose (psi -> psiT ; vpl -> Vt)
    transpose_kv<<<1024, blk, 0, stream>>>(psiK, phiKT, vpl, Vtb);
    // chunked linear attention (affine-corrected with a = ratio*e^-m, b = ratio*1e-4)
    chunk_sums_mfma<<<512, blk, 0, stream>>>(phiKT, Vtb, gmax, sbuf, zbuf);
    prefix_scan<<<256, blk, 0, stream>>>(sbuf, zbuf, SpT, Zp, outZ, outS);
    hipFuncSetAttribute((const void*)chunk_out_mfma,
                        hipFuncAttributeMaxDynamicSharedMemorySize, 66816);
    chunk_out_mfma<<<512, blk, 66816, stream>>>(phi, psiK, Vtb, SpT, Zp, gmax, aouts);
    // final projection
    proj_gemm<<<dim3(64, 4), blk, 0, stream>>>(aouts, Wos, outO, bo);
}

// Round 20
// 215.386 us; speedup vs baseline: 1.5904x; 1.0744x over previous
//
#include <hip/hip_runtime.h>

typedef unsigned short u16;
typedef unsigned int u32;
typedef __attribute__((ext_vector_type(8))) short bf16x8;
typedef __attribute__((ext_vector_type(4))) float f32x4;

#define LOG2E 1.4426950408889634f

__device__ __forceinline__ u16 f2bf(float f) {
    u32 u = __float_as_uint(f);
    return (u16)((u + 0x7fffu + ((u >> 16) & 1u)) >> 16);
}
__device__ __forceinline__ float bf2f(u16 h) { return __uint_as_float(((u32)h) << 16); }
__device__ __forceinline__ u32 pk(u16 a, u16 b) { return (u32)a | ((u32)b << 16); }
__device__ __forceinline__ int swz(int row, int col, int ld) {
    return ((row * ld + col) * 2) ^ ((row & 7) << 4);
}
__device__ __forceinline__ f32x4 MF(bf16x8 a, bf16x8 b, f32x4 c) {
    return __builtin_amdgcn_mfma_f32_16x16x32_bf16(a, b, c, 0, 0, 0);
}
__device__ __forceinline__ float wave_max(float v) {
    #pragma unroll
    for (int o = 32; o; o >>= 1) v = fmaxf(v, __shfl_xor(v, o));
    return v;
}
__device__ __forceinline__ void gload16(const void* g, void* l) {
    __builtin_amdgcn_global_load_lds(
        (const __attribute__((address_space(1))) void*)g,
        (__attribute__((address_space(3))) void*)l, 16, 0, 0);
}
__device__ __forceinline__ float gmax_decode(const u32* gmaxkey) {
    u32 key = *gmaxkey;
    u32 ub = (key & 0x80000000u) ? (key & 0x7fffffffu) : ~key;
    return __uint_as_float(ub);
}

// ---------- split-bf16 convert: B:[hi|lo|hi] (proj, with scale) ----------
template<bool ISB>
__global__ __launch_bounds__(256)
void conv_split(const float* __restrict__ src, u16* __restrict__ dst,
                int K, long total4, float scale)
{
    const int K4 = K >> 2;
    for (long i = (long)blockIdx.x * 256 + threadIdx.x; i < total4;
         i += (long)gridDim.x * 256) {
        long row = i / K4;
        int c = (int)(i - row * K4) * 4;
        float4 v = ((const float4*)src)[i];
        float a0 = v.x * scale, a1 = v.y * scale, a2 = v.z * scale, a3 = v.w * scale;
        u16 h0 = f2bf(a0), h1 = f2bf(a1), h2 = f2bf(a2), h3 = f2bf(a3);
        u16 l0 = f2bf(a0 - bf2f(h0)), l1 = f2bf(a1 - bf2f(h1));
        u16 l2 = f2bf(a2 - bf2f(h2)), l3 = f2bf(a3 - bf2f(h3));
        uint2 hh; hh.x = pk(h0, h1); hh.y = pk(h2, h3);
        uint2 ll; ll.x = pk(l0, l1); ll.y = pk(l2, l3);
        u16* d = dst + row * (3L * K) + c;
        *(uint2*)d = hh;
        *(uint2*)(d + (ISB ? 2 * K : K)) = hh;
        *(uint2*)(d + (ISB ? K : 2 * K)) = ll;
    }
}

// ---------- plain bf16 convert ----------
__global__ __launch_bounds__(256)
void conv_plain(const float* __restrict__ src, u16* __restrict__ dst, long total4)
{
    for (long i = (long)blockIdx.x * 256 + threadIdx.x; i < total4;
         i += (long)gridDim.x * 256) {
        float4 v = ((const float4*)src)[i];
        ushort4 o;
        o.x = f2bf(v.x); o.y = f2bf(v.y); o.z = f2bf(v.z); o.w = f2bf(v.w);
        ((ushort4*)dst)[i] = o;
    }
}

// ---------- merged weight convert: Wq|Wk|Wv -> Wqkvs, Wo -> Wos (one launch) ----------
__global__ __launch_bounds__(256)
void conv_w4(const float* __restrict__ Wq, const float* __restrict__ Wk,
             const float* __restrict__ Wv, const float* __restrict__ Wo,
             u16* __restrict__ Wqkvs, u16* __restrict__ Wos)
{
    const int seg = blockIdx.x >> 6;              // 0..3, 64 blocks each
    const float* src = seg == 0 ? Wq : (seg == 1 ? Wk : (seg == 2 ? Wv : Wo));
    u16* dst = (seg == 3) ? Wos : (Wqkvs + (size_t)seg * 262144);
    long i = (long)(blockIdx.x & 63) * 256 + threadIdx.x;   // 16384 float4 per seg... (65536/4)
    for (; i < 65536L; i += 16384L) {
        float4 v = ((const float4*)src)[i];
        ushort4 o;
        o.x = f2bf(v.x); o.y = f2bf(v.y); o.z = f2bf(v.z); o.w = f2bf(v.w);
        ((ushort4*)dst)[i] = o;
    }
}

// ---------- fused QKV GEMM, plain bf16 K=512, 128x128 tile, gload staging ----------
// q/k epilogue: split [hi|hi|lo] per head + diag (log2-scaled); v -> vpl hi/lo planes
__global__ __launch_bounds__(256, 3)
void qkv_gemm(const u16* __restrict__ A, const u16* __restrict__ B,
              u16* __restrict__ qs, float* __restrict__ diagb,
              u16* __restrict__ vpl)
{
    __shared__ char smem[34816];
    char* As = smem; char* Bs = smem + 16384;
    const int m0 = blockIdx.x * 128, by = blockIdx.y, n0 = by * 128;
    const int tid = threadIdx.x, lane = tid & 63, wave = tid >> 6;
    const int wm = (wave >> 1) * 64, wn = (wave & 1) * 64;
    const int fr = lane & 15, fk = (lane >> 4) * 8;
    const int lr8 = lane >> 3;
    const int cE = ((lane & 7) ^ lr8) << 3;
    f32x4 acc[4][4] = {};
    for (int k0 = 0; k0 < 512; k0 += 64) {
        #pragma unroll
        for (int t = 0; t < 4; t++) {
            int i = wave * 4 + t;
            int r = (i << 3) + lr8;
            gload16(A + (size_t)(m0 + r) * 512 + k0 + cE, As + (i << 10));
            gload16(B + (size_t)(n0 + r) * 512 + k0 + cE, Bs + (i << 10));
        }
        __syncthreads();
        #pragma unroll
        for (int ks = 0; ks < 2; ks++) {
            bf16x8 af[4], bfv[4];
            #pragma unroll
            for (int mf = 0; mf < 4; mf++)
                af[mf] = *(bf16x8*)(As + swz(wm + mf * 16 + fr, ks * 32 + fk, 64));
            #pragma unroll
            for (int nf = 0; nf < 4; nf++)
                bfv[nf] = *(bf16x8*)(Bs + swz(wn + nf * 16 + fr, ks * 32 + fk, 64));
            #pragma unroll
            for (int mf = 0; mf < 4; mf++)
                #pragma unroll
                for (int nf = 0; nf < 4; nf++)
                    acc[mf][nf] = MF(af[mf], bfv[nf], acc[mf][nf]);
        }
        __syncthreads();
    }
    const float dn = 0.35355339059327373f;
    const int sel = by >> 2;        // 0=q,1=k,2=v
    float* st = (float*)smem;       // [64][130]
    for (int half = 0; half < 2; half++) {
        __syncthreads();
        if ((wave >> 1) == half) {
            #pragma unroll
            for (int mf = 0; mf < 4; mf++) {
                int lr = mf * 16 + (lane >> 4) * 4;
                #pragma unroll
                for (int nf = 0; nf < 4; nf++) {
                    int col = wn + nf * 16 + fr;
                    #pragma unroll
                    for (int r = 0; r < 4; r++)
                        st[(lr + r) * 130 + col] = acc[mf][nf][r];
                }
            }
        }
        __syncthreads();
        int grow = m0 + half * 64 + (tid >> 2);
        if (sel < 2) {
            int hl = (tid >> 1) & 1, e0 = (tid & 1) * 32;
            int h = (by & 3) * 2 + hl;
            alignas(16) u16 hbuf[32], lbuf[32];
            float ss = 0.f;
            #pragma unroll
            for (int q = 0; q < 32; q++) {
                float v = dn * st[(tid >> 2) * 130 + hl * 64 + e0 + q];
                ss += v * v;
                u16 hh = f2bf(v); hbuf[q] = hh; lbuf[q] = f2bf(v - bf2f(hh));
            }
            ss += __shfl_xor(ss, 1);
            if ((tid & 1) == 0)
                diagb[(size_t)sel * 65536 + grow * 8 + h] = 0.5f * LOG2E * ss;
            u16* d = qs + (size_t)sel * 12582912 + (size_t)grow * 1536 + h * 192 + e0;
            #pragma unroll
            for (int q = 0; q < 4; q++) *(uint4*)(d + q * 8) = *(uint4*)&hbuf[q * 8];
            #pragma unroll
            for (int q = 0; q < 4; q++) *(uint4*)(d + 64 + q * 8) = *(uint4*)&hbuf[q * 8];
            #pragma unroll
            for (int q = 0; q < 4; q++) *(uint4*)(d + 128 + q * 8) = *(uint4*)&lbuf[q * 8];
        } else {
            int e0 = (tid & 3) * 32;
            int colbase = (by & 3) * 128 + e0;
            alignas(16) u16 hbuf[32], lbuf[32];
            #pragma unroll
            for (int q = 0; q < 32; q++) {
                float v = st[(tid >> 2) * 130 + e0 + q];
                u16 hh = f2bf(v); hbuf[q] = hh; lbuf[q] = f2bf(v - bf2f(hh));
            }
            u16* dh = vpl + (size_t)grow * 512 + colbase;
            u16* dl = dh + 4194304;
            #pragma unroll
            for (int q = 0; q < 4; q++) *(uint4*)(dh + q * 8) = *(uint4*)&hbuf[q * 8];
            #pragma unroll
            for (int q = 0; q < 4; q++) *(uint4*)(dl + q * 8) = *(uint4*)&lbuf[q * 8];
        }
    }
}

// ---------- merged dd GEMM (log2-scaled proj), 64x256 per head, grid (128,1,16) ----------
// z<8: q path: phiQ = ratio*(exp2(v - diag^ - rowmax^) + 1e-4)
// z>=8: k path: psi = exp2(v - diag^); blockmax -> gmax (publishes m^ = log2e*m)
__global__ __launch_bounds__(256, 3)
void dd_gemm(const u16* __restrict__ Aq, const u16* __restrict__ Ak,
             const u16* __restrict__ Bp,
             const float* __restrict__ diagb, u32* __restrict__ gmax,
             u16* __restrict__ phiQ, u16* __restrict__ psiK)
{
    __shared__ char sm_[42240];
    char* As = sm_;                       // [64][64] u16 (8K, linear gload dest)
    char* Bs = sm_ + 8192;                // [256][64] u16 (32K)
    float* red  = (float*)(sm_ + 40960);  // [64][4]
    float* srow = (float*)(sm_ + 41984);  // [64]
    const int isq = (blockIdx.z < 8);
    const int h = isq ? blockIdx.z : (blockIdx.z - 8);
    const int m0 = blockIdx.x * 64;
    const u16* Ag = (isq ? Aq : Ak) + (size_t)m0 * 1536 + h * 192;
    const int tid = threadIdx.x, lane = tid & 63, wave = tid >> 6;
    const int wn = wave * 64;
    const int fr = lane & 15, fk = (lane >> 4) * 8;
    const int lr8 = lane >> 3;
    const int cE = ((lane & 7) ^ lr8) << 3;
    f32x4 acc[4][4] = {};
    for (int k0 = 0; k0 < 192; k0 += 64) {
        #pragma unroll
        for (int t = 0; t < 2; t++) {
            int i = wave * 2 + t;
            int r = (i << 3) + lr8;
            gload16(Ag + (size_t)r * 1536 + k0 + cE, As + (i << 10));
        }
        #pragma unroll
        for (int t = 0; t < 8; t++) {
            int i = wave * 8 + t;
            int r = (i << 3) + lr8;
            gload16(Bp + (size_t)r * 192 + k0 + cE, Bs + (i << 10));
        }
        __syncthreads();
        #pragma unroll
        for (int ks = 0; ks < 2; ks++) {
            bf16x8 af[4], bf4[4];
            #pragma unroll
            for (int mf = 0; mf < 4; mf++)
                af[mf] = *(bf16x8*)(As + swz(mf * 16 + fr, ks * 32 + fk, 64));
            #pragma unroll
            for (int nf = 0; nf < 4; nf++)
                bf4[nf] = *(bf16x8*)(Bs + swz(wn + nf * 16 + fr, ks * 32 + fk, 64));
            #pragma unroll
            for (int mf = 0; mf < 4; mf++)
                #pragma unroll
                for (int nf = 0; nf < 4; nf++)
                    acc[mf][nf] = MF(af[mf], bf4[nf], acc[mf][nf]);
        }
        __syncthreads();
    }

    if (!isq) {
        float mx = -1e30f;
        #pragma unroll
        for (int mf = 0; mf < 4; mf++)
            #pragma unroll
            for (int nf = 0; nf < 4; nf++)
                #pragma unroll
                for (int r = 0; r < 4; r++) mx = fmaxf(mx, acc[mf][nf][r]);
        mx = wave_max(mx);
        __syncthreads();
        if (lane == 0) red[wave] = mx;
        __syncthreads();
        if (tid == 0) {
            float m4 = fmaxf(fmaxf(red[0], red[1]), fmaxf(red[2], red[3]));
            u32 u = __float_as_uint(m4);
            u32 key = (u & 0x80000000u) ? ~u : (u | 0x80000000u);
            atomicMax(gmax, key);
        }
        if (tid < 64)
            srow[tid] = diagb[65536 + (size_t)(m0 + tid) * 8 + h];
    } else {
        float rm[4][4];
        #pragma unroll
        for (int mf = 0; mf < 4; mf++)
            #pragma unroll
            for (int r = 0; r < 4; r++) {
                float m = acc[mf][0][r];
                m = fmaxf(m, acc[mf][1][r]);
                m = fmaxf(m, acc[mf][2][r]);
                m = fmaxf(m, acc[mf][3][r]);
                #pragma unroll
                for (int o = 1; o < 16; o <<= 1) m = fmaxf(m, __shfl_xor(m, o));
                rm[mf][r] = m;
            }
        __syncthreads();
        if ((lane & 15) == 0) {
            #pragma unroll
            for (int mf = 0; mf < 4; mf++)
                #pragma unroll
                for (int r = 0; r < 4; r++)
                    red[(mf * 16 + (lane >> 4) * 4 + r) * 4 + wave] = rm[mf][r];
        }
        __syncthreads();
        if (tid < 64) {
            float m4 = fmaxf(fmaxf(red[tid * 4], red[tid * 4 + 1]),
                             fmaxf(red[tid * 4 + 2], red[tid * 4 + 3]));
            srow[tid] = m4 + diagb[(size_t)(m0 + tid) * 8 + h];
        }
    }
    // single-pass staging + dense writes (exp2 epilogue: one v_exp_f32 each)
    u16* stg = (u16*)sm_;    // [64][264]
    __syncthreads();
    #pragma unroll
    for (int mf = 0; mf < 4; mf++)
        #pragma unroll
        for (int r = 0; r < 4; r++) {
            int row = mf * 16 + (lane >> 4) * 4 + r;
            float s = srow[row];
            #pragma unroll
            for (int nf = 0; nf < 4; nf++) {
                float v = acc[mf][nf][r];
                u16 o = isq ? f2bf(0.0625f * (exp2f(v - s) + 1e-4f))
                            : f2bf(exp2f(v - s));
                stg[row * 264 + wn + nf * 16 + fr] = o;
            }
        }
    __syncthreads();
    {
        int lr = tid >> 2, c0 = (tid & 3) * 64;
        u16* base = isq ? phiQ : psiK;
        u16* dst = base + (size_t)(m0 + lr) * 2048 + h * 256 + c0;
        #pragma unroll
        for (int q = 0; q < 8; q++)
            *(uint4*)(dst + q * 8) = *(uint4*)(stg + lr * 264 + c0 + q * 8);
    }
}

// ---------- merged transpose: bid<512 psiK -> psiKT ; bid>=512 vpl -> Vt ----------
__global__ __launch_bounds__(256)
void transpose_kv(const u16* __restrict__ phiK, u16* __restrict__ phiKT,
                  const u16* __restrict__ vpl, u16* __restrict__ Vt)
{
    __shared__ u16 tr[64 * 136];
    const int isk = (blockIdx.x < 512);
    const int gc = isk ? blockIdx.x : (blockIdx.x - 512);
    const int c = gc & 31, bh = gc >> 5, b = bh >> 3, h = bh & 7;
    const int row0 = b * 4096 + c * 128;
    const int tid = threadIdx.x;
    if (isk) {
        const u16* src = phiK + (size_t)row0 * 2048 + h * 256;
        u16* dst = phiKT + (size_t)gc * 32768;
        for (int f0 = 0; f0 < 256; f0 += 64) {
            #pragma unroll
            for (int j = 0; j < 4; j++) {
                int ci = tid + j * 256; int r = ci >> 3, ff = (ci & 7) * 8;
                bf16x8 w = *(const bf16x8*)(src + (size_t)r * 2048 + f0 + ff);
                #pragma unroll
                for (int q = 0; q < 8; q++) tr[(ff + q) * 136 + r] = (u16)w[q];
            }
            __syncthreads();
            {
                int f = tid >> 2, r0 = (tid & 3) * 32;
                uint4 a0 = *(uint4*)&tr[f * 136 + r0];
                uint4 a1 = *(uint4*)&tr[f * 136 + r0 + 8];
                uint4 a2 = *(uint4*)&tr[f * 136 + r0 + 16];
                uint4 a3 = *(uint4*)&tr[f * 136 + r0 + 24];
                u16* dp = dst + (size_t)(f0 + f) * 128 + r0;
                *(uint4*)dp = a0; *(uint4*)(dp + 8) = a1;
                *(uint4*)(dp + 16) = a2; *(uint4*)(dp + 24) = a3;
            }
            __syncthreads();
        }
    } else {
        u16* dstb = Vt + (size_t)gc * 16384;
        for (int pl = 0; pl < 2; pl++) {
            if (pl) __syncthreads();
            const u16* src = vpl + (size_t)pl * 4194304 + (size_t)row0 * 512 + h * 64;
            #pragma unroll
            for (int j = 0; j < 8; j++) {
                int ci = tid + j * 256; int r = ci >> 4, e = (ci & 15) * 4;
                ushort4 v = *(const ushort4*)(src + (size_t)r * 512 + e);
                tr[(e + 0) * 136 + r] = v.x;
                tr[(e + 1) * 136 + r] = v.y;
                tr[(e + 2) * 136 + r] = v.z;
                tr[(e + 3) * 136 + r] = v.w;
            }
            __syncthreads();
            int e = tid >> 2, r0 = (tid & 3) * 32;
            u16* dst = dstb + pl * 8192;
            #pragma unroll
            for (int q = 0; q < 4; q++) {
                uint4 a = *(uint4*)&tr[e * 136 + r0 + q * 8];
                *(uint4*)(dst + (size_t)e * 128 + r0 + q * 8) = a;
            }
        }
    }
}

// ---------- final projection GEMM: plain bf16, K=512, gload staging ----------
__global__ __launch_bounds__(256, 3)
void proj_gemm(const u16* __restrict__ A, const u16* __restrict__ B,
               float* __restrict__ C, const float* __restrict__ bias)
{
    __shared__ char smem[34816];
    char* As = smem; char* Bs = smem + 16384;
    const int m0 = blockIdx.x * 128, n0 = blockIdx.y * 128;
    const int tid = threadIdx.x, lane = tid & 63, wave = tid >> 6;
    const int wm = (wave >> 1) * 64, wn = (wave & 1) * 64;
    const int fr = lane & 15, fk = (lane >> 4) * 8;
    const int lr8 = lane >> 3;
    const int cE = ((lane & 7) ^ lr8) << 3;
    f32x4 acc[4][4] = {};
    for (int k0 = 0; k0 < 512; k0 += 64) {
        #pragma unroll
        for (int t = 0; t < 4; t++) {
            int i = wave * 4 + t;
            int r = (i << 3) + lr8;
            gload16(A + (size_t)(m0 + r) * 512 + k0 + cE, As + (i << 10));
            gload16(B + (size_t)(n0 + r) * 512 + k0 + cE, Bs + (i << 10));
        }
        __syncthreads();
        #pragma unroll
        for (int ks = 0; ks < 2; ks++) {
            bf16x8 af[4], bfv[4];
            #pragma unroll
            for (int mf = 0; mf < 4; mf++)
                af[mf] = *(bf16x8*)(As + swz(wm + mf * 16 + fr, ks * 32 + fk, 64));
            #pragma unroll
            for (int nf = 0; nf < 4; nf++)
                bfv[nf] = *(bf16x8*)(Bs + swz(wn + nf * 16 + fr, ks * 32 + fk, 64));
            #pragma unroll
            for (int mf = 0; mf < 4; mf++)
                #pragma unroll
                for (int nf = 0; nf < 4; nf++)
                    acc[mf][nf] = MF(af[mf], bfv[nf], acc[mf][nf]);
        }
        __syncthreads();
    }
    float* st = (float*)smem;   // [64][130]
    for (int half = 0; half < 2; half++) {
        __syncthreads();
        if ((wave >> 1) == half) {
            #pragma unroll
            for (int mf = 0; mf < 4; mf++) {
                int lr = mf * 16 + (lane >> 4) * 4;
                #pragma unroll
                for (int nf = 0; nf < 4; nf++) {
                    int col = wn + nf * 16 + fr;
                    #pragma unroll
                    for (int r = 0; r < 4; r++)
                        st[(lr + r) * 130 + col] = acc[mf][nf][r];
                }
            }
        }
        __syncthreads();
        int lr = tid >> 2, c0 = (tid & 3) * 32;
        int grow = m0 + half * 64 + lr;
        float* dst = C + (size_t)grow * 512 + n0 + c0;
        #pragma unroll
        for (int q = 0; q < 8; q++) {
            float4 v;
            v.x = st[lr * 130 + c0 + q * 4 + 0] + bias[n0 + c0 + q * 4 + 0];
            v.y = st[lr * 130 + c0 + q * 4 + 1] + bias[n0 + c0 + q * 4 + 1];
            v.z = st[lr * 130 + c0 + q * 4 + 2] + bias[n0 + c0 + q * 4 + 2];
            v.w = st[lr * 130 + c0 + q * 4 + 3] + bias[n0 + c0 + q * 4 + 3];
            *(float4*)(dst + q * 4) = v;
        }
    }
}

// ---------- Pass A: S = a*(psi^T(Vhi+Vlo)) + b*Vcsum, Z = a*colsum(psi) + 128b ----------
__global__ __launch_bounds__(256)
void chunk_sums_mfma(const u16* __restrict__ phiKT, const u16* __restrict__ Vt,
                     const u32* __restrict__ gmaxkey,
                     float* __restrict__ sbuf, float* __restrict__ zbuf)
{
    __shared__ char smem[49152];
    __shared__ float vcs[64];
    char* bufA = smem;            // [256 f][64 r]
    char* bufBh = smem + 32768;   // [64 e][64 r]
    char* bufBl = smem + 40960;
    const float mg = gmax_decode(gmaxkey);
    const float aF = 0.0625f * exp2f(-mg);
    const float bF = 0.0625f * 1e-4f;
    const int gc = blockIdx.x;
    const u16* Ag = phiKT + (size_t)gc * 32768;
    const u16* Bg = Vt + (size_t)gc * 16384;
    const int tid = threadIdx.x, lane = tid & 63, wave = tid >> 6;
    const int fr = lane & 15, fk = (lane >> 4) * 8;
    const int lr8 = lane >> 3;
    const int cE = ((lane & 7) ^ lr8) << 3;
    {
        float z = 0.f;
        const u16* zp = Ag + (size_t)tid * 128;
        #pragma unroll
        for (int j = 0; j < 16; j++) {
            bf16x8 w = *(const bf16x8*)(zp + j * 8);
            #pragma unroll
            for (int q = 0; q < 8; q++) z += bf2f((u16)w[q]);
        }
        zbuf[(size_t)gc * 256 + tid] = aF * z + bF * 128.0f;
    }
    if (tid < 64) {
        const u16* vh = Bg + (size_t)tid * 128;
        const u16* vl = vh + 8192;
        float s = 0.f;
        #pragma unroll
        for (int j = 0; j < 16; j++) {
            bf16x8 wh = *(const bf16x8*)(vh + j * 8);
            bf16x8 wl = *(const bf16x8*)(vl + j * 8);
            #pragma unroll
            for (int q = 0; q < 8; q++)
                s += bf2f((u16)wh[q]) + bf2f((u16)wl[q]);
        }
        vcs[tid] = s;
    }
    f32x4 acc[4][4] = {};
    for (int kh = 0; kh < 2; kh++) {
        #pragma unroll
        for (int t = 0; t < 8; t++) {
            int i = wave * 8 + t;
            int f = (i << 3) + lr8;
            gload16(Ag + (size_t)f * 128 + kh * 64 + cE, bufA + (i << 10));
        }
        #pragma unroll
        for (int t = 0; t < 2; t++) {
            int i = wave * 2 + t;
            int e = (i << 3) + lr8;
            gload16(Bg + (size_t)e * 128 + kh * 64 + cE, bufBh + (i << 10));
            gload16(Bg + 8192 + (size_t)e * 128 + kh * 64 + cE, bufBl + (i << 10));
        }
        __syncthreads();
        #pragma unroll
        for (int ks = 0; ks < 2; ks++) {
            bf16x8 af[4], bh4[4], bl4[4];
            #pragma unroll
            for (int mf = 0; mf < 4; mf++)
                af[mf] = *(bf16x8*)(bufA + swz(wave * 64 + mf * 16 + fr, ks * 32 + fk, 64));
            #pragma unroll
            for (int nf = 0; nf < 4; nf++) {
                bh4[nf] = *(bf16x8*)(bufBh + swz(nf * 16 + fr, ks * 32 + fk, 64));
                bl4[nf] = *(bf16x8*)(bufBl + swz(nf * 16 + fr, ks * 32 + fk, 64));
            }
            #pragma unroll
            for (int mf = 0; mf < 4; mf++)
                #pragma unroll
                for (int nf = 0; nf < 4; nf++) {
                    acc[mf][nf] = MF(af[mf], bh4[nf], acc[mf][nf]);
                    acc[mf][nf] = MF(af[mf], bl4[nf], acc[mf][nf]);
                }
        }
        __syncthreads();
    }
    #pragma unroll
    for (int mf = 0; mf < 4; mf++) {
        int fb = wave * 64 + mf * 16 + (lane >> 4) * 4;
        #pragma unroll
        for (int nf = 0; nf < 4; nf++) {
            int e = nf * 16 + fr;
            float vb = bF * vcs[e];
            #pragma unroll
            for (int r = 0; r < 4; r++)
                sbuf[(size_t)gc * 16384 + (size_t)(fb + r) * 64 + e] =
                    aF * acc[mf][nf][r] + vb;
        }
    }
}

// ---------- Pass B: exclusive prefix, 256 blocks (16 bh x 16 f-slabs) ----------
__global__ __launch_bounds__(256)
void prefix_scan(const float* __restrict__ sbuf, const float* __restrict__ zbuf,
                 u16* __restrict__ SpT, float* __restrict__ Zp,
                 float* __restrict__ outZ, float* __restrict__ outS)
{
    __shared__ float trans[64 * 17];
    const int bh = blockIdx.x >> 4, f0 = (blockIdx.x & 15) * 16;
    const int tid = threadIdx.x;
    const int e_ = tid >> 2, fl = (tid & 3) * 4;
    float run[4] = {0.f, 0.f, 0.f, 0.f};
    float zrun = 0.f;
    for (int c = 0; c < 32; c++) {
        const int gc = bh * 32 + c;
        const float* base = sbuf + (size_t)gc * 16384 + f0 * 64;
        float v[4];
        #pragma unroll
        for (int i = 0; i < 4; i++) v[i] = base[tid + i * 256];
        #pragma unroll
        for (int i = 0; i < 4; i++) {
            int idx = tid + i * 256;
            trans[(idx & 63) * 17 + (idx >> 6)] = run[i];
        }
        float zv = 0.f;
        if (tid < 16) zv = zbuf[(size_t)gc * 256 + f0 + tid];
        __syncthreads();
        {
            alignas(8) u16 hb[4], lb[4];
            #pragma unroll
            for (int q = 0; q < 4; q++) {
                float vv = trans[e_ * 17 + fl + q];
                u16 hh = f2bf(vv); hb[q] = hh; lb[q] = f2bf(vv - bf2f(hh));
            }
            u16* dh = SpT + (size_t)gc * 32768 + e_ * 256 + f0 + fl;
            *(uint2*)dh = *(uint2*)hb;
            *(uint2*)(dh + 16384) = *(uint2*)lb;
        }
        if (tid < 16) { Zp[(size_t)gc * 256 + f0 + tid] = zrun; zrun += zv; }
        #pragma unroll
        for (int i = 0; i < 4; i++) run[i] += v[i];
        __syncthreads();
    }
    #pragma unroll
    for (int i = 0; i < 4; i++)
        outS[(size_t)bh * 16384 + f0 * 64 + tid + i * 256] = run[i];
    if (tid < 16) outZ[bh * 256 + f0 + tid] = zrun;
}

// ---------- Pass C: aouts = Dinv*(Q@Sprev + tril(a*Q psi^T + b*rowQ)@V) ----------
__global__ __launch_bounds__(256)
void chunk_out_mfma(const u16* __restrict__ phiQ, const u16* __restrict__ psiK,
                    const u16* __restrict__ Vt, const u16* __restrict__ SpT,
                    const float* __restrict__ Zp, const u32* __restrict__ gmaxkey,
                    u16* __restrict__ aouts)
{
    extern __shared__ char sm[];
    char* bufQ = sm;             // [128][64] Q-slab
    char* bufK = sm + 16384;     // [128][64] psi-slab ; later V_hi [64][128] swz
    char* bufA = sm + 32768;     // f0 loop: Sp_hi @+0, Sp_lo @+8192 ; after: A [128][128] swz
    float* Dl = (float*)(sm + 65536);    // [128]
    float* Zl = (float*)(sm + 66048);    // [64]
    float* RowQ = (float*)(sm + 66304);  // [128]
    const float mg = gmax_decode(gmaxkey);
    const float aF = 0.0625f * exp2f(-mg);
    const float bF = 0.0625f * 1e-4f;
    const int gc = blockIdx.x, c = gc & 31, bh = gc >> 5, b = bh >> 3, h = bh & 7;
    const int row0 = b * 4096 + c * 128;
    const u16* Qg = phiQ + (size_t)row0 * 2048 + h * 256;
    const u16* Kg = psiK + (size_t)row0 * 2048 + h * 256;
    const u16* Vg = Vt + (size_t)gc * 16384;
    const u16* Sg = SpT + (size_t)gc * 32768;
    const float* Zg = Zp + (size_t)gc * 256;
    const int tid = threadIdx.x, lane = tid & 63, wave = tid >> 6;
    const int fr = lane & 15, fk = (lane >> 4) * 8;
    const int dr = tid >> 1, dc = (tid & 1) * 32;
    const int lr8 = lane >> 3;
    const int cE = ((lane & 7) ^ lr8) << 3;

    f32x4 acc2[2][8] = {};
    f32x4 acc1[2][4] = {};
    float dotZ = 0.f, sumQ = 0.f;

    for (int f0 = 0; f0 < 256; f0 += 64) {
        #pragma unroll
        for (int t = 0; t < 4; t++) {
            int i = wave * 4 + t;
            int r = (i << 3) + lr8;
            gload16(Qg + (size_t)r * 2048 + f0 + cE, bufQ + (i << 10));
            gload16(Kg + (size_t)r * 2048 + f0 + cE, bufK + (i << 10));
        }
        #pragma unroll
        for (int t = 0; t < 2; t++) {
            int i = wave * 2 + t;
            int e = (i << 3) + lr8;
            gload16(Sg + (size_t)e * 256 + f0 + cE, bufA + (i << 10));
            gload16(Sg + 16384 + (size_t)e * 256 + f0 + cE, bufA + 8192 + (i << 10));
        }
        if (tid < 64) Zl[tid] = Zg[f0 + tid];
        __syncthreads();
        #pragma unroll
        for (int ks = 0; ks < 2; ks++) {
            bf16x8 af[2];
            af[0] = *(bf16x8*)(bufQ + swz(wave * 32 + fr, ks * 32 + fk, 64));
            af[1] = *(bf16x8*)(bufQ + swz(wave * 32 + 16 + fr, ks * 32 + fk, 64));
            #pragma unroll
            for (int nf = 0; nf < 8; nf++) {
                bf16x8 bv = *(bf16x8*)(bufK + swz(nf * 16 + fr, ks * 32 + fk, 64));
                acc2[0][nf] = MF(af[0], bv, acc2[0][nf]);
                acc2[1][nf] = MF(af[1], bv, acc2[1][nf]);
            }
            #pragma unroll
            for (int nf = 0; nf < 4; nf++) {
                bf16x8 bvh = *(bf16x8*)(bufA + swz(nf * 16 + fr, ks * 32 + fk, 64));
                bf16x8 bvl = *(bf16x8*)(bufA + 8192 + swz(nf * 16 + fr, ks * 32 + fk, 64));
                acc1[0][nf] = MF(af[0], bvh, acc1[0][nf]);
                acc1[1][nf] = MF(af[1], bvh, acc1[1][nf]);
                acc1[0][nf] = MF(af[0], bvl, acc1[0][nf]);
                acc1[1][nf] = MF(af[1], bvl, acc1[1][nf]);
            }
        }
        #pragma unroll
        for (int jj = 0; jj < 4; jj++) {
            bf16x8 qv = *(bf16x8*)(bufQ + swz(dr, dc + jj * 8, 64));
            f32x4 z0 = *(f32x4*)(Zl + dc + jj * 8);
            f32x4 z1 = *(f32x4*)(Zl + dc + jj * 8 + 4);
            #pragma unroll
            for (int q = 0; q < 8; q++) {
                float qf = bf2f((u16)qv[q]);
                sumQ += qf;
                dotZ += qf * (q < 4 ? z0[q] : z1[q - 4]);
            }
        }
        __syncthreads();
    }
    // publish full row sums of phiQ (for A affine correction)
    {
        float rq = sumQ + __shfl_xor(sumQ, 1);
        if ((tid & 1) == 0) RowQ[dr] = rq;
    }
    __syncthreads();
    float4 vvh[4];
    #pragma unroll
    for (int j = 0; j < 4; j++) {
        int ci = tid + j * 256; int e = ci >> 4, cc = (ci & 15) * 8;
        vvh[j] = *(const float4*)(Vg + (size_t)e * 128 + cc);
    }
    #pragma unroll
    for (int mf = 0; mf < 2; mf++) {
        int rb = wave * 32 + mf * 16 + (lane >> 4) * 4;
        #pragma unroll
        for (int nf = 0; nf < 8; nf++) {
            int col = nf * 16 + fr;
            #pragma unroll
            for (int r = 0; r < 4; r++) {
                float v = (col <= rb + r) ? (aF * acc2[mf][nf][r] + bF * RowQ[rb + r]) : 0.f;
                *(u16*)(bufA + swz(rb + r, col, 128)) = f2bf(v);
            }
        }
    }
    #pragma unroll
    for (int j = 0; j < 4; j++) {
        int ci = tid + j * 256; int e = ci >> 4, cc = (ci & 15) * 8;
        *(float4*)(bufK + swz(e, cc, 128)) = vvh[j];
    }
    __syncthreads();
    {
        const int dcA = (tid & 1) * 64;
        float rs = 0.f;
        #pragma unroll
        for (int jj = 0; jj < 8; jj++) {
            bf16x8 av = *(bf16x8*)(bufA + swz(dr, dcA + jj * 8, 128));
            #pragma unroll
            for (int q = 0; q < 8; q++) rs += bf2f((u16)av[q]);
        }
        float tot = rs + dotZ + 1e-6f * sumQ;
        tot += __shfl_xor(tot, 1);
        if ((tid & 1) == 0) Dl[dr] = tot;
    }
    #pragma unroll
    for (int ks = 0; ks < 4; ks++) {
        bf16x8 af[2];
        af[0] = *(bf16x8*)(bufA + swz(wave * 32 + fr, ks * 32 + fk, 128));
        af[1] = *(bf16x8*)(bufA + swz(wave * 32 + 16 + fr, ks * 32 + fk, 128));
        #pragma unroll
        for (int nf = 0; nf < 4; nf++) {
            bf16x8 bvh = *(bf16x8*)(bufK + swz(nf * 16 + fr, ks * 32 + fk, 128));
            acc1[0][nf] = MF(af[0], bvh, acc1[0][nf]);
            acc1[1][nf] = MF(af[1], bvh, acc1[1][nf]);
        }
    }
    __syncthreads();
    float* st = (float*)sm;   // [128][65]
    #pragma unroll
    for (int mf = 0; mf < 2; mf++) {
        int rb = wave * 32 + mf * 16 + (lane >> 4) * 4;
        #pragma unroll
        for (int r = 0; r < 4; r++) {
            float dinv = 1.f / Dl[rb + r];
            #pragma unroll
            for (int nf = 0; nf < 4; nf++)
                st[(rb + r) * 65 + nf * 16 + fr] = acc1[mf][nf][r] * dinv;
        }
    }
    __syncthreads();
    {
        int lr = tid >> 1, e0 = (tid & 1) * 32;
        alignas(16) u16 hb[32];
        #pragma unroll
        for (int q = 0; q < 32; q++) hb[q] = f2bf(st[lr * 65 + e0 + q]);
        u16* d = aouts + (size_t)(row0 + lr) * 512 + h * 64 + e0;
        #pragma unroll
        for (int q = 0; q < 4; q++) *(uint4*)(d + q * 8) = *(uint4*)&hb[q * 8];
    }
}

extern "C" void kernel_launch(void* const* d_in, const int* in_sizes, int n_in,
                              void* d_out, int out_size, void* d_ws, size_t ws_size,
                              hipStream_t stream)
{
    const float* x    = (const float*)d_in[0];
    const float* Wq   = (const float*)d_in[1];
    const float* Wk   = (const float*)d_in[2];
    const float* Wv   = (const float*)d_in[3];
    const float* Wo   = (const float*)d_in[4];
    const float* bo   = (const float*)d_in[5];
    const float* proj = (const float*)d_in[6];
    float* out = (float*)d_out;
    float* ws = (float*)d_ws;

    // layout (float offsets)
    u16*   vpl   = (u16*)ws;                    // [2][8192][512] u16
    float* diagb = ws + 4194304;                // [2][8192][8] f32 (log2-scaled)
    u16*   phi   = (u16*)(ws + 12582912);       // phiQ [8192][2048] | psiK [8192][2048]
    u16*   Vtb   = (u16*)(ws + 37748736);       // [512][2][64][128] u16
    float* sbuf  = ws + 41943040;               // 512*16384 f32
    u16*   qs    = (u16*)(ws + 41943040);       // q|k split u16 (dead after dd_gemm)
    u16*   phiKT = (u16*)(ws + 50331648);       // 512*32768 u16 (dead after chunk_sums)
    u16*   SpT   = (u16*)(ws + 50331648);       //   overlay: written by prefix_scan AFTER chunk_sums
    u16*   xs    = (u16*)(ws + 58720256);       // plain [8192][512] u16
    u16*   aouts = xs;                          //   overlay: plain [8192][512] u16
    u16*   Wqkvs = (u16*)(ws + 65011712);       // plain [1536][512] u16
    float* zbuf  = ws + 65142784;               //   overlay tail (dead after qkv_gemm)
    float* Zp    = ws + 65273856;
    u32*   gmax  = (u32*)(ws + 65404928);
    u16*   Wos   = (u16*)(ws + 66191360);       // plain [512][512] u16
    u16*   projs = (u16*)(ws + 66584576);       // [256][192] u16 (log2e-scaled)

    float* outO = out;                 // [2,4096,512]
    float* outZ = out + 4194304;       // [2,8,256]
    float* outS = out + 4198400;       // [2,8,256,64]

    dim3 blk(256);

    conv_plain<<<1024, blk, 0, stream>>>(x, xs, 1048576L);
    conv_w4<<<256, blk, 0, stream>>>(Wq, Wk, Wv, Wo, Wqkvs, Wos);
    conv_split<true ><<<16, blk, 0, stream>>>(proj, projs, 64, 4096L, LOG2E);
    // fused QKV projection (plain bf16, K=512; diag stored log2-scaled)
    qkv_gemm<<<dim3(64, 12), blk, 0, stream>>>(xs, Wqkvs, qs, diagb, vpl);
    hipMemsetAsync(gmax, 0, 4, stream);
    // merged dd GEMM (log2 domain): q -> phiQ; k -> psi = exp2(v - diag^) + blockmax
    const u16* ksplit = qs + 12582912;
    u16* psiK = phi + (size_t)8192 * 2048;
    dd_gemm<<<dim3(128, 1, 16), blk, 0, stream>>>(qs, ksplit, projs, diagb, gmax,
                                                  phi, psiK);
    // merged transpose (psi -> psiT ; vpl -> Vt)
    transpose_kv<<<1024, blk, 0, stream>>>(psiK, phiKT, vpl, Vtb);
    // chunked linear attention (affine: a = ratio*exp2(-m^), b = ratio*1e-4)
    chunk_sums_mfma<<<512, blk, 0, stream>>>(phiKT, Vtb, gmax, sbuf, zbuf);
    prefix_scan<<<256, blk, 0, stream>>>(sbuf, zbuf, SpT, Zp, outZ, outS);
    hipFuncSetAttribute((const void*)chunk_out_mfma,
                        hipFuncAttributeMaxDynamicSharedMemorySize, 66816);
    chunk_out_mfma<<<512, blk, 66816, stream>>>(phi, psiK, Vtb, SpT, Zp, gmax, aouts);
    // final projection
    proj_gemm<<<dim3(64, 4), blk, 0, stream>>>(aouts, Wos, outO, bo);
}

// Round 21
// 208.410 us; speedup vs baseline: 1.6436x; 1.0335x over previous
//
#include <hip/hip_runtime.h>
#include <hip/hip_bf16.h>

typedef unsigned short u16;
typedef unsigned int u32;
typedef __attribute__((ext_vector_type(8))) short bf16x8;
typedef __attribute__((ext_vector_type(4))) float f32x4;

#define LOG2E 1.4426950408889634f

__device__ __forceinline__ u16 f2bf(float f) {
    __hip_bfloat16 h = __float2bfloat16(f);
    u16 u; __builtin_memcpy(&u, &h, 2); return u;
}
__device__ __forceinline__ float bf2f(u16 h) { return __uint_as_float(((u32)h) << 16); }
__device__ __forceinline__ u32 pk(u16 a, u16 b) { return (u32)a | ((u32)b << 16); }
__device__ __forceinline__ int swz(int row, int col, int ld) {
    return ((row * ld + col) * 2) ^ ((row & 7) << 4);
}
__device__ __forceinline__ f32x4 MF(bf16x8 a, bf16x8 b, f32x4 c) {
    return __builtin_amdgcn_mfma_f32_16x16x32_bf16(a, b, c, 0, 0, 0);
}
__device__ __forceinline__ float wave_max(float v) {
    #pragma unroll
    for (int o = 32; o; o >>= 1) v = fmaxf(v, __shfl_xor(v, o));
    return v;
}
__device__ __forceinline__ void gload16(const void* g, void* l) {
    __builtin_amdgcn_global_load_lds(
        (const __attribute__((address_space(1))) void*)g,
        (__attribute__((address_space(3))) void*)l, 16, 0, 0);
}
__device__ __forceinline__ float gmax_decode(const u32* gmaxkey) {
    u32 key = *gmaxkey;
    u32 ub = (key & 0x80000000u) ? (key & 0x7fffffffu) : ~key;
    return __uint_as_float(ub);
}

// ---------- split-bf16 convert: B:[hi|lo|hi] (proj, with scale) ----------
template<bool ISB>
__global__ __launch_bounds__(256)
void conv_split(const float* __restrict__ src, u16* __restrict__ dst,
                int K, long total4, float scale)
{
    const int K4 = K >> 2;
    for (long i = (long)blockIdx.x * 256 + threadIdx.x; i < total4;
         i += (long)gridDim.x * 256) {
        long row = i / K4;
        int c = (int)(i - row * K4) * 4;
        float4 v = ((const float4*)src)[i];
        float a0 = v.x * scale, a1 = v.y * scale, a2 = v.z * scale, a3 = v.w * scale;
        u16 h0 = f2bf(a0), h1 = f2bf(a1), h2 = f2bf(a2), h3 = f2bf(a3);
        u16 l0 = f2bf(a0 - bf2f(h0)), l1 = f2bf(a1 - bf2f(h1));
        u16 l2 = f2bf(a2 - bf2f(h2)), l3 = f2bf(a3 - bf2f(h3));
        uint2 hh; hh.x = pk(h0, h1); hh.y = pk(h2, h3);
        uint2 ll; ll.x = pk(l0, l1); ll.y = pk(l2, l3);
        u16* d = dst + row * (3L * K) + c;
        *(uint2*)d = hh;
        *(uint2*)(d + (ISB ? 2 * K : K)) = hh;
        *(uint2*)(d + (ISB ? K : 2 * K)) = ll;
    }
}

// ---------- plain bf16 convert ----------
__global__ __launch_bounds__(256)
void conv_plain(const float* __restrict__ src, u16* __restrict__ dst, long total4)
{
    for (long i = (long)blockIdx.x * 256 + threadIdx.x; i < total4;
         i += (long)gridDim.x * 256) {
        float4 v = ((const float4*)src)[i];
        ushort4 o;
        o.x = f2bf(v.x); o.y = f2bf(v.y); o.z = f2bf(v.z); o.w = f2bf(v.w);
        ((ushort4*)dst)[i] = o;
    }
}

// ---------- merged weight convert ----------
__global__ __launch_bounds__(256)
void conv_w4(const float* __restrict__ Wq, const float* __restrict__ Wk,
             const float* __restrict__ Wv, const float* __restrict__ Wo,
             u16* __restrict__ Wqkvs, u16* __restrict__ Wos)
{
    const int seg = blockIdx.x >> 6;
    const float* src = seg == 0 ? Wq : (seg == 1 ? Wk : (seg == 2 ? Wv : Wo));
    u16* dst = (seg == 3) ? Wos : (Wqkvs + (size_t)seg * 262144);
    long i = (long)(blockIdx.x & 63) * 256 + threadIdx.x;
    for (; i < 65536L; i += 16384L) {
        float4 v = ((const float4*)src)[i];
        ushort4 o;
        o.x = f2bf(v.x); o.y = f2bf(v.y); o.z = f2bf(v.z); o.w = f2bf(v.w);
        ((ushort4*)dst)[i] = o;
    }
}

// ---------- fused QKV GEMM, plain bf16 K=512; v epilogue writes Vt transposed ----------
__global__ __launch_bounds__(256, 3)
void qkv_gemm(const u16* __restrict__ A, const u16* __restrict__ B,
              u16* __restrict__ qs, float* __restrict__ diagb,
              u16* __restrict__ Vtb)
{
    __shared__ char smem[34816];
    char* As = smem; char* Bs = smem + 16384;
    const int m0 = blockIdx.x * 128, by = blockIdx.y, n0 = by * 128;
    const int tid = threadIdx.x, lane = tid & 63, wave = tid >> 6;
    const int wm = (wave >> 1) * 64, wn = (wave & 1) * 64;
    const int fr = lane & 15, fk = (lane >> 4) * 8;
    const int lr8 = lane >> 3;
    const int cE = ((lane & 7) ^ lr8) << 3;
    f32x4 acc[4][4] = {};
    for (int k0 = 0; k0 < 512; k0 += 64) {
        #pragma unroll
        for (int t = 0; t < 4; t++) {
            int i = wave * 4 + t;
            int r = (i << 3) + lr8;
            gload16(A + (size_t)(m0 + r) * 512 + k0 + cE, As + (i << 10));
            gload16(B + (size_t)(n0 + r) * 512 + k0 + cE, Bs + (i << 10));
        }
        __syncthreads();
        #pragma unroll
        for (int ks = 0; ks < 2; ks++) {
            bf16x8 af[4], bfv[4];
            #pragma unroll
            for (int mf = 0; mf < 4; mf++)
                af[mf] = *(bf16x8*)(As + swz(wm + mf * 16 + fr, ks * 32 + fk, 64));
            #pragma unroll
            for (int nf = 0; nf < 4; nf++)
                bfv[nf] = *(bf16x8*)(Bs + swz(wn + nf * 16 + fr, ks * 32 + fk, 64));
            #pragma unroll
            for (int mf = 0; mf < 4; mf++)
                #pragma unroll
                for (int nf = 0; nf < 4; nf++)
                    acc[mf][nf] = MF(af[mf], bfv[nf], acc[mf][nf]);
        }
        __syncthreads();
    }
    const float dn = 0.35355339059327373f;
    const int sel = by >> 2;
    float* st = (float*)smem;       // [64][130]
    for (int half = 0; half < 2; half++) {
        __syncthreads();
        if ((wave >> 1) == half) {
            #pragma unroll
            for (int mf = 0; mf < 4; mf++) {
                int lr = mf * 16 + (lane >> 4) * 4;
                #pragma unroll
                for (int nf = 0; nf < 4; nf++) {
                    int col = wn + nf * 16 + fr;
                    #pragma unroll
                    for (int r = 0; r < 4; r++)
                        st[(lr + r) * 130 + col] = acc[mf][nf][r];
                }
            }
        }
        __syncthreads();
        if (sel < 2) {
            int grow = m0 + half * 64 + (tid >> 2);
            int hl = (tid >> 1) & 1, e0 = (tid & 1) * 32;
            int h = (by & 3) * 2 + hl;
            alignas(16) u16 hbuf[32], lbuf[32];
            float ss = 0.f;
            #pragma unroll
            for (int q = 0; q < 32; q++) {
                float v = dn * st[(tid >> 2) * 130 + hl * 64 + e0 + q];
                ss += v * v;
                u16 hh = f2bf(v); hbuf[q] = hh; lbuf[q] = f2bf(v - bf2f(hh));
            }
            ss += __shfl_xor(ss, 1);
            if ((tid & 1) == 0)
                diagb[(size_t)sel * 65536 + grow * 8 + h] = 0.5f * LOG2E * ss;
            u16* d = qs + (size_t)sel * 12582912 + (size_t)grow * 1536 + h * 192 + e0;
            #pragma unroll
            for (int q = 0; q < 4; q++) *(uint4*)(d + q * 8) = *(uint4*)&hbuf[q * 8];
            #pragma unroll
            for (int q = 0; q < 4; q++) *(uint4*)(d + 64 + q * 8) = *(uint4*)&hbuf[q * 8];
            #pragma unroll
            for (int q = 0; q < 4; q++) *(uint4*)(d + 128 + q * 8) = *(uint4*)&lbuf[q * 8];
        } else {
            const int bb = blockIdx.x >> 5, cc2 = blockIdx.x & 31;
            int e_full = tid >> 1;
            int h_local = e_full >> 6;
            int e = e_full & 63;
            int rhalf = (tid & 1) * 32;
            int gc = (bb * 8 + (by & 3) * 2 + h_local) * 32 + cc2;
            alignas(16) u16 hbuf[32], lbuf[32];
            #pragma unroll
            for (int q = 0; q < 32; q++) {
                float v = st[(rhalf + q) * 130 + h_local * 64 + e];
                u16 hh = f2bf(v); hbuf[q] = hh; lbuf[q] = f2bf(v - bf2f(hh));
            }
            u16* dh = Vtb + (size_t)gc * 16384 + (size_t)e * 128 + half * 64 + rhalf;
            u16* dl = dh + 8192;
            #pragma unroll
            for (int q = 0; q < 4; q++) *(uint4*)(dh + q * 8) = *(uint4*)&hbuf[q * 8];
            #pragma unroll
            for (int q = 0; q < 4; q++) *(uint4*)(dl + q * 8) = *(uint4*)&lbuf[q * 8];
        }
    }
}

// ---------- merged dd GEMM (log2-scaled proj), 64x256 per head, grid (128,1,16) ----------
__global__ __launch_bounds__(256, 3)
void dd_gemm(const u16* __restrict__ Aq, const u16* __restrict__ Ak,
             const u16* __restrict__ Bp,
             const float* __restrict__ diagb, u32* __restrict__ gmax,
             u16* __restrict__ phiQ, u16* __restrict__ psiK)
{
    __shared__ char sm_[42240];
    char* As = sm_;
    char* Bs = sm_ + 8192;
    float* red  = (float*)(sm_ + 40960);
    float* srow = (float*)(sm_ + 41984);
    const int isq = (blockIdx.z < 8);
    const int h = isq ? blockIdx.z : (blockIdx.z - 8);
    const int m0 = blockIdx.x * 64;
    const u16* Ag = (isq ? Aq : Ak) + (size_t)m0 * 1536 + h * 192;
    const int tid = threadIdx.x, lane = tid & 63, wave = tid >> 6;
    const int wn = wave * 64;
    const int fr = lane & 15, fk = (lane >> 4) * 8;
    const int lr8 = lane >> 3;
    const int cE = ((lane & 7) ^ lr8) << 3;
    f32x4 acc[4][4] = {};
    for (int k0 = 0; k0 < 192; k0 += 64) {
        #pragma unroll
        for (int t = 0; t < 2; t++) {
            int i = wave * 2 + t;
            int r = (i << 3) + lr8;
            gload16(Ag + (size_t)r * 1536 + k0 + cE, As + (i << 10));
        }
        #pragma unroll
        for (int t = 0; t < 8; t++) {
            int i = wave * 8 + t;
            int r = (i << 3) + lr8;
            gload16(Bp + (size_t)r * 192 + k0 + cE, Bs + (i << 10));
        }
        __syncthreads();
        #pragma unroll
        for (int ks = 0; ks < 2; ks++) {
            bf16x8 af[4], bf4[4];
            #pragma unroll
            for (int mf = 0; mf < 4; mf++)
                af[mf] = *(bf16x8*)(As + swz(mf * 16 + fr, ks * 32 + fk, 64));
            #pragma unroll
            for (int nf = 0; nf < 4; nf++)
                bf4[nf] = *(bf16x8*)(Bs + swz(wn + nf * 16 + fr, ks * 32 + fk, 64));
            #pragma unroll
            for (int mf = 0; mf < 4; mf++)
                #pragma unroll
                for (int nf = 0; nf < 4; nf++)
                    acc[mf][nf] = MF(af[mf], bf4[nf], acc[mf][nf]);
        }
        __syncthreads();
    }

    if (!isq) {
        float mx = -1e30f;
        #pragma unroll
        for (int mf = 0; mf < 4; mf++)
            #pragma unroll
            for (int nf = 0; nf < 4; nf++)
                #pragma unroll
                for (int r = 0; r < 4; r++) mx = fmaxf(mx, acc[mf][nf][r]);
        mx = wave_max(mx);
        __syncthreads();
        if (lane == 0) red[wave] = mx;
        __syncthreads();
        if (tid == 0) {
            float m4 = fmaxf(fmaxf(red[0], red[1]), fmaxf(red[2], red[3]));
            u32 u = __float_as_uint(m4);
            u32 key = (u & 0x80000000u) ? ~u : (u | 0x80000000u);
            atomicMax(gmax, key);
        }
        if (tid < 64)
            srow[tid] = diagb[65536 + (size_t)(m0 + tid) * 8 + h];
    } else {
        float rm[4][4];
        #pragma unroll
        for (int mf = 0; mf < 4; mf++)
            #pragma unroll
            for (int r = 0; r < 4; r++) {
                float m = acc[mf][0][r];
                m = fmaxf(m, acc[mf][1][r]);
                m = fmaxf(m, acc[mf][2][r]);
                m = fmaxf(m, acc[mf][3][r]);
                #pragma unroll
                for (int o = 1; o < 16; o <<= 1) m = fmaxf(m, __shfl_xor(m, o));
                rm[mf][r] = m;
            }
        __syncthreads();
        if ((lane & 15) == 0) {
            #pragma unroll
            for (int mf = 0; mf < 4; mf++)
                #pragma unroll
                for (int r = 0; r < 4; r++)
                    red[(mf * 16 + (lane >> 4) * 4 + r) * 4 + wave] = rm[mf][r];
        }
        __syncthreads();
        if (tid < 64) {
            float m4 = fmaxf(fmaxf(red[tid * 4], red[tid * 4 + 1]),
                             fmaxf(red[tid * 4 + 2], red[tid * 4 + 3]));
            srow[tid] = m4 + diagb[(size_t)(m0 + tid) * 8 + h];
        }
    }
    u16* stg = (u16*)sm_;
    __syncthreads();
    #pragma unroll
    for (int mf = 0; mf < 4; mf++)
        #pragma unroll
        for (int r = 0; r < 4; r++) {
            int row = mf * 16 + (lane >> 4) * 4 + r;
            float s = srow[row];
            #pragma unroll
            for (int nf = 0; nf < 4; nf++) {
                float v = acc[mf][nf][r];
                u16 o = isq ? f2bf(0.0625f * (exp2f(v - s) + 1e-4f))
                            : f2bf(exp2f(v - s));
                stg[row * 264 + wn + nf * 16 + fr] = o;
            }
        }
    __syncthreads();
    {
        int lr = tid >> 2, c0 = (tid & 3) * 64;
        u16* base = isq ? phiQ : psiK;
        u16* dst = base + (size_t)(m0 + lr) * 2048 + h * 256 + c0;
        #pragma unroll
        for (int q = 0; q < 8; q++)
            *(uint4*)(dst + q * 8) = *(uint4*)(stg + lr * 264 + c0 + q * 8);
    }
}

// ---------- plain transpose psiK per chunk -> psiKT[gc][f=256][r=128] ----------
__global__ __launch_bounds__(256)
void transpose_k(const u16* __restrict__ phiK, u16* __restrict__ phiKT)
{
    __shared__ u16 tr[64 * 136];
    const int gc = blockIdx.x, c = gc & 31, bh = gc >> 5, b = bh >> 3, h = bh & 7;
    const int row0 = b * 4096 + c * 128;
    const u16* src = phiK + (size_t)row0 * 2048 + h * 256;
    u16* dst = phiKT + (size_t)gc * 32768;
    const int tid = threadIdx.x;
    for (int f0 = 0; f0 < 256; f0 += 64) {
        #pragma unroll
        for (int j = 0; j < 4; j++) {
            int ci = tid + j * 256; int r = ci >> 3, ff = (ci & 7) * 8;
            bf16x8 w = *(const bf16x8*)(src + (size_t)r * 2048 + f0 + ff);
            #pragma unroll
            for (int q = 0; q < 8; q++) tr[(ff + q) * 136 + r] = (u16)w[q];
        }
        __syncthreads();
        {
            int f = tid >> 2, r0 = (tid & 3) * 32;
            uint4 a0 = *(uint4*)&tr[f * 136 + r0];
            uint4 a1 = *(uint4*)&tr[f * 136 + r0 + 8];
            uint4 a2 = *(uint4*)&tr[f * 136 + r0 + 16];
            uint4 a3 = *(uint4*)&tr[f * 136 + r0 + 24];
            u16* dp = dst + (size_t)(f0 + f) * 128 + r0;
            *(uint4*)dp = a0; *(uint4*)(dp + 8) = a1;
            *(uint4*)(dp + 16) = a2; *(uint4*)(dp + 24) = a3;
        }
        __syncthreads();
    }
}

// ---------- final projection GEMM ----------
__global__ __launch_bounds__(256, 3)
void proj_gemm(const u16* __restrict__ A, const u16* __restrict__ B,
               float* __restrict__ C, const float* __restrict__ bias)
{
    __shared__ char smem[34816];
    char* As = smem; char* Bs = smem + 16384;
    const int m0 = blockIdx.x * 128, n0 = blockIdx.y * 128;
    const int tid = threadIdx.x, lane = tid & 63, wave = tid >> 6;
    const int wm = (wave >> 1) * 64, wn = (wave & 1) * 64;
    const int fr = lane & 15, fk = (lane >> 4) * 8;
    const int lr8 = lane >> 3;
    const int cE = ((lane & 7) ^ lr8) << 3;
    f32x4 acc[4][4] = {};
    for (int k0 = 0; k0 < 512; k0 += 64) {
        #pragma unroll
        for (int t = 0; t < 4; t++) {
            int i = wave * 4 + t;
            int r = (i << 3) + lr8;
            gload16(A + (size_t)(m0 + r) * 512 + k0 + cE, As + (i << 10));
            gload16(B + (size_t)(n0 + r) * 512 + k0 + cE, Bs + (i << 10));
        }
        __syncthreads();
        #pragma unroll
        for (int ks = 0; ks < 2; ks++) {
            bf16x8 af[4], bfv[4];
            #pragma unroll
            for (int mf = 0; mf < 4; mf++)
                af[mf] = *(bf16x8*)(As + swz(wm + mf * 16 + fr, ks * 32 + fk, 64));
            #pragma unroll
            for (int nf = 0; nf < 4; nf++)
                bfv[nf] = *(bf16x8*)(Bs + swz(wn + nf * 16 + fr, ks * 32 + fk, 64));
            #pragma unroll
            for (int mf = 0; mf < 4; mf++)
                #pragma unroll
                for (int nf = 0; nf < 4; nf++)
                    acc[mf][nf] = MF(af[mf], bfv[nf], acc[mf][nf]);
        }
        __syncthreads();
    }
    float* st = (float*)smem;
    for (int half = 0; half < 2; half++) {
        __syncthreads();
        if ((wave >> 1) == half) {
            #pragma unroll
            for (int mf = 0; mf < 4; mf++) {
                int lr = mf * 16 + (lane >> 4) * 4;
                #pragma unroll
                for (int nf = 0; nf < 4; nf++) {
                    int col = wn + nf * 16 + fr;
                    #pragma unroll
                    for (int r = 0; r < 4; r++)
                        st[(lr + r) * 130 + col] = acc[mf][nf][r];
                }
            }
        }
        __syncthreads();
        int lr = tid >> 2, c0 = (tid & 3) * 32;
        int grow = m0 + half * 64 + lr;
        float* dst = C + (size_t)grow * 512 + n0 + c0;
        #pragma unroll
        for (int q = 0; q < 8; q++) {
            float4 v;
            v.x = st[lr * 130 + c0 + q * 4 + 0] + bias[n0 + c0 + q * 4 + 0];
            v.y = st[lr * 130 + c0 + q * 4 + 1] + bias[n0 + c0 + q * 4 + 1];
            v.z = st[lr * 130 + c0 + q * 4 + 2] + bias[n0 + c0 + q * 4 + 2];
            v.w = st[lr * 130 + c0 + q * 4 + 3] + bias[n0 + c0 + q * 4 + 3];
            *(float4*)(dst + q * 4) = v;
        }
    }
}

// ---------- Pass A ----------
__global__ __launch_bounds__(256)
void chunk_sums_mfma(const u16* __restrict__ phiKT, const u16* __restrict__ Vt,
                     const u32* __restrict__ gmaxkey,
                     float* __restrict__ sbuf, float* __restrict__ zbuf)
{
    __shared__ char smem[49152];
    __shared__ float vcs[64];
    char* bufA = smem;
    char* bufBh = smem + 32768;
    char* bufBl = smem + 40960;
    const float mg = gmax_decode(gmaxkey);
    const float aF = 0.0625f * exp2f(-mg);
    const float bF = 0.0625f * 1e-4f;
    const int gc = blockIdx.x;
    const u16* Ag = phiKT + (size_t)gc * 32768;
    const u16* Bg = Vt + (size_t)gc * 16384;
    const int tid = threadIdx.x, lane = tid & 63, wave = tid >> 6;
    const int fr = lane & 15, fk = (lane >> 4) * 8;
    const int lr8 = lane >> 3;
    const int cE = ((lane & 7) ^ lr8) << 3;
    {
        float z = 0.f;
        const u16* zp = Ag + (size_t)tid * 128;
        #pragma unroll
        for (int j = 0; j < 16; j++) {
            bf16x8 w = *(const bf16x8*)(zp + j * 8);
            #pragma unroll
            for (int q = 0; q < 8; q++) z += bf2f((u16)w[q]);
        }
        zbuf[(size_t)gc * 256 + tid] = aF * z + bF * 128.0f;
    }
    if (tid < 64) {
        const u16* vh = Bg + (size_t)tid * 128;
        const u16* vl = vh + 8192;
        float s = 0.f;
        #pragma unroll
        for (int j = 0; j < 16; j++) {
            bf16x8 wh = *(const bf16x8*)(vh + j * 8);
            bf16x8 wl = *(const bf16x8*)(vl + j * 8);
            #pragma unroll
            for (int q = 0; q < 8; q++)
                s += bf2f((u16)wh[q]) + bf2f((u16)wl[q]);
        }
        vcs[tid] = s;
    }
    f32x4 acc[4][4] = {};
    for (int kh = 0; kh < 2; kh++) {
        #pragma unroll
        for (int t = 0; t < 8; t++) {
            int i = wave * 8 + t;
            int f = (i << 3) + lr8;
            gload16(Ag + (size_t)f * 128 + kh * 64 + cE, bufA + (i << 10));
        }
        #pragma unroll
        for (int t = 0; t < 2; t++) {
            int i = wave * 2 + t;
            int e = (i << 3) + lr8;
            gload16(Bg + (size_t)e * 128 + kh * 64 + cE, bufBh + (i << 10));
            gload16(Bg + 8192 + (size_t)e * 128 + kh * 64 + cE, bufBl + (i << 10));
        }
        __syncthreads();
        #pragma unroll
        for (int ks = 0; ks < 2; ks++) {
            bf16x8 af[4], bh4[4], bl4[4];
            #pragma unroll
            for (int mf = 0; mf < 4; mf++)
                af[mf] = *(bf16x8*)(bufA + swz(wave * 64 + mf * 16 + fr, ks * 32 + fk, 64));
            #pragma unroll
            for (int nf = 0; nf < 4; nf++) {
                bh4[nf] = *(bf16x8*)(bufBh + swz(nf * 16 + fr, ks * 32 + fk, 64));
                bl4[nf] = *(bf16x8*)(bufBl + swz(nf * 16 + fr, ks * 32 + fk, 64));
            }
            #pragma unroll
            for (int mf = 0; mf < 4; mf++)
                #pragma unroll
                for (int nf = 0; nf < 4; nf++) {
                    acc[mf][nf] = MF(af[mf], bh4[nf], acc[mf][nf]);
                    acc[mf][nf] = MF(af[mf], bl4[nf], acc[mf][nf]);
                }
        }
        __syncthreads();
    }
    #pragma unroll
    for (int mf = 0; mf < 4; mf++) {
        int fb = wave * 64 + mf * 16 + (lane >> 4) * 4;
        #pragma unroll
        for (int nf = 0; nf < 4; nf++) {
            int e = nf * 16 + fr;
            float vb = bF * vcs[e];
            #pragma unroll
            for (int r = 0; r < 4; r++)
                sbuf[(size_t)gc * 16384 + (size_t)(fb + r) * 64 + e] =
                    aF * acc[mf][nf][r] + vb;
        }
    }
}

// ---------- Pass B ----------
__global__ __launch_bounds__(256)
void prefix_scan(const float* __restrict__ sbuf, const float* __restrict__ zbuf,
                 u16* __restrict__ SpT, float* __restrict__ Zp,
                 float* __restrict__ outZ, float* __restrict__ outS)
{
    __shared__ float trans[64 * 17];
    const int bh = blockIdx.x >> 4, f0 = (blockIdx.x & 15) * 16;
    const int tid = threadIdx.x;
    const int e_ = tid >> 2, fl = (tid & 3) * 4;
    float run[4] = {0.f, 0.f, 0.f, 0.f};
    float zrun = 0.f;
    for (int c = 0; c < 32; c++) {
        const int gc = bh * 32 + c;
        const float* base = sbuf + (size_t)gc * 16384 + f0 * 64;
        float v[4];
        #pragma unroll
        for (int i = 0; i < 4; i++) v[i] = base[tid + i * 256];
        #pragma unroll
        for (int i = 0; i < 4; i++) {
            int idx = tid + i * 256;
            trans[(idx & 63) * 17 + (idx >> 6)] = run[i];
        }
        float zv = 0.f;
        if (tid < 16) zv = zbuf[(size_t)gc * 256 + f0 + tid];
        __syncthreads();
        {
            alignas(8) u16 hb[4], lb[4];
            #pragma unroll
            for (int q = 0; q < 4; q++) {
                float vv = trans[e_ * 17 + fl + q];
                u16 hh = f2bf(vv); hb[q] = hh; lb[q] = f2bf(vv - bf2f(hh));
            }
            u16* dh = SpT + (size_t)gc * 32768 + e_ * 256 + f0 + fl;
            *(uint2*)dh = *(uint2*)hb;
            *(uint2*)(dh + 16384) = *(uint2*)lb;
        }
        if (tid < 16) { Zp[(size_t)gc * 256 + f0 + tid] = zrun; zrun += zv; }
        #pragma unroll
        for (int i = 0; i < 4; i++) run[i] += v[i];
        __syncthreads();
    }
    #pragma unroll
    for (int i = 0; i < 4; i++)
        outS[(size_t)bh * 16384 + f0 * 64 + tid + i * 256] = run[i];
    if (tid < 16) outZ[bh * 256 + f0 + tid] = zrun;
}

// ---------- Pass C ----------
__global__ __launch_bounds__(256)
void chunk_out_mfma(const u16* __restrict__ phiQ, const u16* __restrict__ psiK,
                    const u16* __restrict__ Vt, const u16* __restrict__ SpT,
                    const float* __restrict__ Zp, const u32* __restrict__ gmaxkey,
                    u16* __restrict__ aouts)
{
    extern __shared__ char sm[];
    char* bufQ = sm;
    char* bufK = sm + 16384;
    char* bufA = sm + 32768;
    float* Dl = (float*)(sm + 65536);
    float* Zl = (float*)(sm + 66048);
    float* RowQ = (float*)(sm + 66304);
    const float mg = gmax_decode(gmaxkey);
    const float aF = 0.0625f * exp2f(-mg);
    const float bF = 0.0625f * 1e-4f;
    const int gc = blockIdx.x, c = gc & 31, bh = gc >> 5, b = bh >> 3, h = bh & 7;
    const int row0 = b * 4096 + c * 128;
    const u16* Qg = phiQ + (size_t)row0 * 2048 + h * 256;
    const u16* Kg = psiK + (size_t)row0 * 2048 + h * 256;
    const u16* Vg = Vt + (size_t)gc * 16384;
    const u16* Sg = SpT + (size_t)gc * 32768;
    const float* Zg = Zp + (size_t)gc * 256;
    const int tid = threadIdx.x, lane = tid & 63, wave = tid >> 6;
    const int fr = lane & 15, fk = (lane >> 4) * 8;
    const int dr = tid >> 1, dc = (tid & 1) * 32;
    const int lr8 = lane >> 3;
    const int cE = ((lane & 7) ^ lr8) << 3;

    f32x4 acc2[2][8] = {};
    f32x4 acc1[2][4] = {};
    float dotZ = 0.f, sumQ = 0.f;

    for (int f0 = 0; f0 < 256; f0 += 64) {
        #pragma unroll
        for (int t = 0; t < 4; t++) {
            int i = wave * 4 + t;
            int r = (i << 3) + lr8;
            gload16(Qg + (size_t)r * 2048 + f0 + cE, bufQ + (i << 10));
            gload16(Kg + (size_t)r * 2048 + f0 + cE, bufK + (i << 10));
        }
        #pragma unroll
        for (int t = 0; t < 2; t++) {
            int i = wave * 2 + t;
            int e = (i << 3) + lr8;
            gload16(Sg + (size_t)e * 256 + f0 + cE, bufA + (i << 10));
            gload16(Sg + 16384 + (size_t)e * 256 + f0 + cE, bufA + 8192 + (i << 10));
        }
        if (tid < 64) Zl[tid] = Zg[f0 + tid];
        __syncthreads();
        #pragma unroll
        for (int ks = 0; ks < 2; ks++) {
            bf16x8 af[2];
            af[0] = *(bf16x8*)(bufQ + swz(wave * 32 + fr, ks * 32 + fk, 64));
            af[1] = *(bf16x8*)(bufQ + swz(wave * 32 + 16 + fr, ks * 32 + fk, 64));
            #pragma unroll
            for (int nf = 0; nf < 8; nf++) {
                bf16x8 bv = *(bf16x8*)(bufK + swz(nf * 16 + fr, ks * 32 + fk, 64));
                acc2[0][nf] = MF(af[0], bv, acc2[0][nf]);
                acc2[1][nf] = MF(af[1], bv, acc2[1][nf]);
            }
            #pragma unroll
            for (int nf = 0; nf < 4; nf++) {
                bf16x8 bvh = *(bf16x8*)(bufA + swz(nf * 16 + fr, ks * 32 + fk, 64));
                bf16x8 bvl = *(bf16x8*)(bufA + 8192 + swz(nf * 16 + fr, ks * 32 + fk, 64));
                acc1[0][nf] = MF(af[0], bvh, acc1[0][nf]);
                acc1[1][nf] = MF(af[1], bvh, acc1[1][nf]);
                acc1[0][nf] = MF(af[0], bvl, acc1[0][nf]);
                acc1[1][nf] = MF(af[1], bvl, acc1[1][nf]);
            }
        }
        #pragma unroll
        for (int jj = 0; jj < 4; jj++) {
            bf16x8 qv = *(bf16x8*)(bufQ + swz(dr, dc + jj * 8, 64));
            f32x4 z0 = *(f32x4*)(Zl + dc + jj * 8);
            f32x4 z1 = *(f32x4*)(Zl + dc + jj * 8 + 4);
            #pragma unroll
            for (int q = 0; q < 8; q++) {
                float qf = bf2f((u16)qv[q]);
                sumQ += qf;
                dotZ += qf * (q < 4 ? z0[q] : z1[q - 4]);
            }
        }
        __syncthreads();
    }
    {
        float rq = sumQ + __shfl_xor(sumQ, 1);
        if ((tid & 1) == 0) RowQ[dr] = rq;
    }
    __syncthreads();
    float4 vvh[4];
    #pragma unroll
    for (int j = 0; j < 4; j++) {
        int ci = tid + j * 256; int e = ci >> 4, cc = (ci & 15) * 8;
        vvh[j] = *(const float4*)(Vg + (size_t)e * 128 + cc);
    }
    #pragma unroll
    for (int mf = 0; mf < 2; mf++) {
        int rb = wave * 32 + mf * 16 + (lane >> 4) * 4;
        #pragma unroll
        for (int nf = 0; nf < 8; nf++) {
            int col = nf * 16 + fr;
            #pragma unroll
            for (int r = 0; r < 4; r++) {
                float v = (col <= rb + r) ? (aF * acc2[mf][nf][r] + bF * RowQ[rb + r]) : 0.f;
                *(u16*)(bufA + swz(rb + r, col, 128)) = f2bf(v);
            }
        }
    }
    #pragma unroll
    for (int j = 0; j < 4; j++) {
        int ci = tid + j * 256; int e = ci >> 4, cc = (ci & 15) * 8;
        *(float4*)(bufK + swz(e, cc, 128)) = vvh[j];
    }
    __syncthreads();
    {
        const int dcA = (tid & 1) * 64;
        float rs = 0.f;
        #pragma unroll
        for (int jj = 0; jj < 8; jj++) {
            bf16x8 av = *(bf16x8*)(bufA + swz(dr, dcA + jj * 8, 128));
            #pragma unroll
            for (int q = 0; q < 8; q++) rs += bf2f((u16)av[q]);
        }
        float tot = rs + dotZ + 1e-6f * sumQ;
        tot += __shfl_xor(tot, 1);
        if ((tid & 1) == 0) Dl[dr] = tot;
    }
    #pragma unroll
    for (int ks = 0; ks < 4; ks++) {
        bf16x8 af[2];
        af[0] = *(bf16x8*)(bufA + swz(wave * 32 + fr, ks * 32 + fk, 128));
        af[1] = *(bf16x8*)(bufA + swz(wave * 32 + 16 + fr, ks * 32 + fk, 128));
        #pragma unroll
        for (int nf = 0; nf < 4; nf++) {
            bf16x8 bvh = *(bf16x8*)(bufK + swz(nf * 16 + fr, ks * 32 + fk, 128));
            acc1[0][nf] = MF(af[0], bvh, acc1[0][nf]);
            acc1[1][nf] = MF(af[1], bvh, acc1[1][nf]);
        }
    }
    __syncthreads();
    float* st = (float*)sm;
    #pragma unroll
    for (int mf = 0; mf < 2; mf++) {
        int rb = wave * 32 + mf * 16 + (lane >> 4) * 4;
        #pragma unroll
        for (int r = 0; r < 4; r++) {
            float dinv = 1.f / Dl[rb + r];
            #pragma unroll
            for (int nf = 0; nf < 4; nf++)
                st[(rb + r) * 65 + nf * 16 + fr] = acc1[mf][nf][r] * dinv;
        }
    }
    __syncthreads();
    {
        int lr = tid >> 1, e0 = (tid & 1) * 32;
        alignas(16) u16 hb[32];
        #pragma unroll
        for (int q = 0; q < 32; q++) hb[q] = f2bf(st[lr * 65 + e0 + q]);
        u16* d = aouts + (size_t)(row0 + lr) * 512 + h * 64 + e0;
        #pragma unroll
        for (int q = 0; q < 4; q++) *(uint4*)(d + q * 8) = *(uint4*)&hb[q * 8];
    }
}

extern "C" void kernel_launch(void* const* d_in, const int* in_sizes, int n_in,
                              void* d_out, int out_size, void* d_ws, size_t ws_size,
                              hipStream_t stream)
{
    const float* x    = (const float*)d_in[0];
    const float* Wq   = (const float*)d_in[1];
    const float* Wk   = (const float*)d_in[2];
    const float* Wv   = (const float*)d_in[3];
    const float* Wo   = (const float*)d_in[4];
    const float* bo   = (const float*)d_in[5];
    const float* proj = (const float*)d_in[6];
    float* out = (float*)d_out;
    float* ws = (float*)d_ws;

    float* diagb = ws + 4194304;                // [2][8192][8] f32 (log2-scaled)
    u16*   phi   = (u16*)(ws + 12582912);       // phiQ | psiK
    u16*   Vtb   = (u16*)(ws + 37748736);       // [512][2][64][128] u16
    float* sbuf  = ws + 41943040;               // 512*16384 f32
    u16*   qs    = (u16*)(ws + 41943040);       // q|k split (dead after dd_gemm)
    u16*   phiKT = (u16*)(ws + 50331648);       // dead after chunk_sums
    u16*   SpT   = (u16*)(ws + 50331648);       // overlay
    u16*   xs    = (u16*)(ws + 58720256);       // plain [8192][512] u16
    u16*   aouts = xs;
    u16*   Wqkvs = (u16*)(ws + 65011712);       // plain [1536][512] u16
    float* zbuf  = ws + 65142784;
    float* Zp    = ws + 65273856;
    u32*   gmax  = (u32*)(ws + 65404928);
    u16*   Wos   = (u16*)(ws + 66191360);       // plain [512][512] u16
    u16*   projs = (u16*)(ws + 66584576);       // [256][192] u16 (log2e-scaled)

    float* outO = out;
    float* outZ = out + 4194304;
    float* outS = out + 4198400;

    dim3 blk(256);

    conv_plain<<<1024, blk, 0, stream>>>(x, xs, 1048576L);
    conv_w4<<<256, blk, 0, stream>>>(Wq, Wk, Wv, Wo, Wqkvs, Wos);
    conv_split<true ><<<16, blk, 0, stream>>>(proj, projs, 64, 4096L, LOG2E);
    qkv_gemm<<<dim3(64, 12), blk, 0, stream>>>(xs, Wqkvs, qs, diagb, Vtb);
    hipMemsetAsync(gmax, 0, 4, stream);
    const u16* ksplit = qs + 12582912;
    u16* psiK = phi + (size_t)8192 * 2048;
    dd_gemm<<<dim3(128, 1, 16), blk, 0, stream>>>(qs, ksplit, projs, diagb, gmax,
                                                  phi, psiK);
    transpose_k<<<512, blk, 0, stream>>>(psiK, phiKT);
    chunk_sums_mfma<<<512, blk, 0, stream>>>(phiKT, Vtb, gmax, sbuf, zbuf);
    prefix_scan<<<256, blk, 0, stream>>>(sbuf, zbuf, SpT, Zp, outZ, outS);
    hipFuncSetAttribute((const void*)chunk_out_mfma,
                        hipFuncAttributeMaxDynamicSharedMemorySize, 66816);
    chunk_out_mfma<<<512, blk, 66816, stream>>>(phi, psiK, Vtb, SpT, Zp, gmax, aouts);
    proj_gemm<<<dim3(64, 4), blk, 0, stream>>>(aouts, Wos, outO, bo);
}

// Round 22
// 198.365 us; speedup vs baseline: 1.7268x; 1.0506x over previous
//
#include <hip/hip_runtime.h>
#include <hip/hip_bf16.h>

typedef unsigned short u16;
typedef unsigned int u32;
typedef __attribute__((ext_vector_type(8))) short bf16x8;
typedef __attribute__((ext_vector_type(4))) float f32x4;

#define LOG2E 1.4426950408889634f

__device__ __forceinline__ u16 f2bf(float f) {
    __hip_bfloat16 h = __float2bfloat16(f);
    u16 u; __builtin_memcpy(&u, &h, 2); return u;
}
__device__ __forceinline__ float bf2f(u16 h) { return __uint_as_float(((u32)h) << 16); }
__device__ __forceinline__ u32 pk(u16 a, u16 b) { return (u32)a | ((u32)b << 16); }
__device__ __forceinline__ int swz(int row, int col, int ld) {
    return ((row * ld + col) * 2) ^ ((row & 7) << 4);
}
__device__ __forceinline__ f32x4 MF(bf16x8 a, bf16x8 b, f32x4 c) {
    return __builtin_amdgcn_mfma_f32_16x16x32_bf16(a, b, c, 0, 0, 0);
}
__device__ __forceinline__ float wave_max(float v) {
    #pragma unroll
    for (int o = 32; o; o >>= 1) v = fmaxf(v, __shfl_xor(v, o));
    return v;
}
__device__ __forceinline__ void gload16(const void* g, void* l) {
    __builtin_amdgcn_global_load_lds(
        (const __attribute__((address_space(1))) void*)g,
        (__attribute__((address_space(3))) void*)l, 16, 0, 0);
}
__device__ __forceinline__ float gmax_decode(const u32* gmaxkey) {
    u32 key = *gmaxkey;
    u32 ub = (key & 0x80000000u) ? (key & 0x7fffffffu) : ~key;
    return __uint_as_float(ub);
}

// ---------- split-bf16 convert: B:[hi|lo|hi] (proj, with scale) ----------
template<bool ISB>
__global__ __launch_bounds__(256)
void conv_split(const float* __restrict__ src, u16* __restrict__ dst,
                int K, long total4, float scale)
{
    const int K4 = K >> 2;
    for (long i = (long)blockIdx.x * 256 + threadIdx.x; i < total4;
         i += (long)gridDim.x * 256) {
        long row = i / K4;
        int c = (int)(i - row * K4) * 4;
        float4 v = ((const float4*)src)[i];
        float a0 = v.x * scale, a1 = v.y * scale, a2 = v.z * scale, a3 = v.w * scale;
        u16 h0 = f2bf(a0), h1 = f2bf(a1), h2 = f2bf(a2), h3 = f2bf(a3);
        u16 l0 = f2bf(a0 - bf2f(h0)), l1 = f2bf(a1 - bf2f(h1));
        u16 l2 = f2bf(a2 - bf2f(h2)), l3 = f2bf(a3 - bf2f(h3));
        uint2 hh; hh.x = pk(h0, h1); hh.y = pk(h2, h3);
        uint2 ll; ll.x = pk(l0, l1); ll.y = pk(l2, l3);
        u16* d = dst + row * (3L * K) + c;
        *(uint2*)d = hh;
        *(uint2*)(d + (ISB ? 2 * K : K)) = hh;
        *(uint2*)(d + (ISB ? K : 2 * K)) = ll;
    }
}

// ---------- plain bf16 convert ----------
__global__ __launch_bounds__(256)
void conv_plain(const float* __restrict__ src, u16* __restrict__ dst, long total4)
{
    for (long i = (long)blockIdx.x * 256 + threadIdx.x; i < total4;
         i += (long)gridDim.x * 256) {
        float4 v = ((const float4*)src)[i];
        ushort4 o;
        o.x = f2bf(v.x); o.y = f2bf(v.y); o.z = f2bf(v.z); o.w = f2bf(v.w);
        ((ushort4*)dst)[i] = o;
    }
}

// ---------- merged weight convert ----------
__global__ __launch_bounds__(256)
void conv_w4(const float* __restrict__ Wq, const float* __restrict__ Wk,
             const float* __restrict__ Wv, const float* __restrict__ Wo,
             u16* __restrict__ Wqkvs, u16* __restrict__ Wos)
{
    const int seg = blockIdx.x >> 6;
    const float* src = seg == 0 ? Wq : (seg == 1 ? Wk : (seg == 2 ? Wv : Wo));
    u16* dst = (seg == 3) ? Wos : (Wqkvs + (size_t)seg * 262144);
    long i = (long)(blockIdx.x & 63) * 256 + threadIdx.x;
    for (; i < 65536L; i += 16384L) {
        float4 v = ((const float4*)src)[i];
        ushort4 o;
        o.x = f2bf(v.x); o.y = f2bf(v.y); o.z = f2bf(v.z); o.w = f2bf(v.w);
        ((ushort4*)dst)[i] = o;
    }
}

// ---------- fused QKV GEMM, plain bf16 K=512; v epilogue writes Vt transposed ----------
// q/k epilogue: split [hi|lo] per head (row stride 1024) + diag (log2-scaled)
__global__ __launch_bounds__(256, 3)
void qkv_gemm(const u16* __restrict__ A, const u16* __restrict__ B,
              u16* __restrict__ qs, float* __restrict__ diagb,
              u16* __restrict__ Vtb)
{
    __shared__ char smem[34816];
    char* As = smem; char* Bs = smem + 16384;
    const int m0 = blockIdx.x * 128, by = blockIdx.y, n0 = by * 128;
    const int tid = threadIdx.x, lane = tid & 63, wave = tid >> 6;
    const int wm = (wave >> 1) * 64, wn = (wave & 1) * 64;
    const int fr = lane & 15, fk = (lane >> 4) * 8;
    const int lr8 = lane >> 3;
    const int cE = ((lane & 7) ^ lr8) << 3;
    f32x4 acc[4][4] = {};
    for (int k0 = 0; k0 < 512; k0 += 64) {
        #pragma unroll
        for (int t = 0; t < 4; t++) {
            int i = wave * 4 + t;
            int r = (i << 3) + lr8;
            gload16(A + (size_t)(m0 + r) * 512 + k0 + cE, As + (i << 10));
            gload16(B + (size_t)(n0 + r) * 512 + k0 + cE, Bs + (i << 10));
        }
        __syncthreads();
        #pragma unroll
        for (int ks = 0; ks < 2; ks++) {
            bf16x8 af[4], bfv[4];
            #pragma unroll
            for (int mf = 0; mf < 4; mf++)
                af[mf] = *(bf16x8*)(As + swz(wm + mf * 16 + fr, ks * 32 + fk, 64));
            #pragma unroll
            for (int nf = 0; nf < 4; nf++)
                bfv[nf] = *(bf16x8*)(Bs + swz(wn + nf * 16 + fr, ks * 32 + fk, 64));
            #pragma unroll
            for (int mf = 0; mf < 4; mf++)
                #pragma unroll
                for (int nf = 0; nf < 4; nf++)
                    acc[mf][nf] = MF(af[mf], bfv[nf], acc[mf][nf]);
        }
        __syncthreads();
    }
    const float dn = 0.35355339059327373f;
    const int sel = by >> 2;
    float* st = (float*)smem;       // [64][130]
    for (int half = 0; half < 2; half++) {
        __syncthreads();
        if ((wave >> 1) == half) {
            #pragma unroll
            for (int mf = 0; mf < 4; mf++) {
                int lr = mf * 16 + (lane >> 4) * 4;
                #pragma unroll
                for (int nf = 0; nf < 4; nf++) {
                    int col = wn + nf * 16 + fr;
                    #pragma unroll
                    for (int r = 0; r < 4; r++)
                        st[(lr + r) * 130 + col] = acc[mf][nf][r];
                }
            }
        }
        __syncthreads();
        if (sel < 2) {
            int grow = m0 + half * 64 + (tid >> 2);
            int hl = (tid >> 1) & 1, e0 = (tid & 1) * 32;
            int h = (by & 3) * 2 + hl;
            alignas(16) u16 hbuf[32], lbuf[32];
            float ss = 0.f;
            #pragma unroll
            for (int q = 0; q < 32; q++) {
                float v = dn * st[(tid >> 2) * 130 + hl * 64 + e0 + q];
                ss += v * v;
                u16 hh = f2bf(v); hbuf[q] = hh; lbuf[q] = f2bf(v - bf2f(hh));
            }
            ss += __shfl_xor(ss, 1);
            if ((tid & 1) == 0)
                diagb[(size_t)sel * 65536 + grow * 8 + h] = 0.5f * LOG2E * ss;
            u16* d = qs + (size_t)sel * 8388608 + (size_t)grow * 1024 + h * 128 + e0;
            #pragma unroll
            for (int q = 0; q < 4; q++) *(uint4*)(d + q * 8) = *(uint4*)&hbuf[q * 8];
            #pragma unroll
            for (int q = 0; q < 4; q++) *(uint4*)(d + 64 + q * 8) = *(uint4*)&lbuf[q * 8];
        } else {
            const int bb = blockIdx.x >> 5, cc2 = blockIdx.x & 31;
            int e_full = tid >> 1;
            int h_local = e_full >> 6;
            int e = e_full & 63;
            int rhalf = (tid & 1) * 32;
            int gc = (bb * 8 + (by & 3) * 2 + h_local) * 32 + cc2;
            alignas(16) u16 hbuf[32], lbuf[32];
            #pragma unroll
            for (int q = 0; q < 32; q++) {
                float v = st[(rhalf + q) * 130 + h_local * 64 + e];
                u16 hh = f2bf(v); hbuf[q] = hh; lbuf[q] = f2bf(v - bf2f(hh));
            }
            u16* dh = Vtb + (size_t)gc * 16384 + (size_t)e * 128 + half * 64 + rhalf;
            u16* dl = dh + 8192;
            #pragma unroll
            for (int q = 0; q < 4; q++) *(uint4*)(dh + q * 8) = *(uint4*)&hbuf[q * 8];
            #pragma unroll
            for (int q = 0; q < 4; q++) *(uint4*)(dl + q * 8) = *(uint4*)&lbuf[q * 8];
        }
    }
}

// ---------- merged dd GEMM (log2-scaled proj), 64x256 per head, grid (128,1,16) ----------
// A layout [hi|lo] per head (stride 1024); A-slabs {hi,hi,lo} vs proj slabs {hi,lo,hi}.
// z<8: q path -> phiQ (full feature map). z>=8: k path -> psiK row-major AND
// psiKT[gc][f][r] directly from LDS (transpose fused; transpose_k deleted).
__global__ __launch_bounds__(256, 3)
void dd_gemm(const u16* __restrict__ Aq, const u16* __restrict__ Ak,
             const u16* __restrict__ Bp,
             const float* __restrict__ diagb, u32* __restrict__ gmax,
             u16* __restrict__ phiQ, u16* __restrict__ psiK,
             u16* __restrict__ psiKT)
{
    __shared__ char sm_[42240];
    char* As = sm_;                       // [64][64] u16 (8K, linear gload dest)
    char* Bs = sm_ + 8192;                // [256][64] u16 (32K)
    float* red  = (float*)(sm_ + 40960);  // [64][4]
    float* srow = (float*)(sm_ + 41984);  // [64]
    const int isq = (blockIdx.z < 8);
    const int h = isq ? blockIdx.z : (blockIdx.z - 8);
    const int m0 = blockIdx.x * 64;
    const u16* Ag = (isq ? Aq : Ak) + (size_t)m0 * 1024 + h * 128;
    const int tid = threadIdx.x, lane = tid & 63, wave = tid >> 6;
    const int wn = wave * 64;
    const int fr = lane & 15, fk = (lane >> 4) * 8;
    const int lr8 = lane >> 3;
    const int cE = ((lane & 7) ^ lr8) << 3;
    f32x4 acc[4][4] = {};
    for (int kk = 0; kk < 3; kk++) {
        if (kk != 1) {                    // kk=1 reuses the hi slab already in As
            int aoff = kk ? 64 : 0;
            #pragma unroll
            for (int t = 0; t < 2; t++) {
                int i = wave * 2 + t;
                int r = (i << 3) + lr8;
                gload16(Ag + (size_t)r * 1024 + aoff + cE, As + (i << 10));
            }
        }
        #pragma unroll
        for (int t = 0; t < 8; t++) {
            int i = wave * 8 + t;
            int r = (i << 3) + lr8;
            gload16(Bp + (size_t)r * 192 + kk * 64 + cE, Bs + (i << 10));
        }
        __syncthreads();
        #pragma unroll
        for (int ks = 0; ks < 2; ks++) {
            bf16x8 af[4], bf4[4];
            #pragma unroll
            for (int mf = 0; mf < 4; mf++)
                af[mf] = *(bf16x8*)(As + swz(mf * 16 + fr, ks * 32 + fk, 64));
            #pragma unroll
            for (int nf = 0; nf < 4; nf++)
                bf4[nf] = *(bf16x8*)(Bs + swz(wn + nf * 16 + fr, ks * 32 + fk, 64));
            #pragma unroll
            for (int mf = 0; mf < 4; mf++)
                #pragma unroll
                for (int nf = 0; nf < 4; nf++)
                    acc[mf][nf] = MF(af[mf], bf4[nf], acc[mf][nf]);
        }
        __syncthreads();
    }

    if (!isq) {
        float mx = -1e30f;
        #pragma unroll
        for (int mf = 0; mf < 4; mf++)
            #pragma unroll
            for (int nf = 0; nf < 4; nf++)
                #pragma unroll
                for (int r = 0; r < 4; r++) mx = fmaxf(mx, acc[mf][nf][r]);
        mx = wave_max(mx);
        __syncthreads();
        if (lane == 0) red[wave] = mx;
        __syncthreads();
        if (tid == 0) {
            float m4 = fmaxf(fmaxf(red[0], red[1]), fmaxf(red[2], red[3]));
            u32 u = __float_as_uint(m4);
            u32 key = (u & 0x80000000u) ? ~u : (u | 0x80000000u);
            atomicMax(gmax, key);
        }
        if (tid < 64)
            srow[tid] = diagb[65536 + (size_t)(m0 + tid) * 8 + h];
    } else {
        float rm[4][4];
        #pragma unroll
        for (int mf = 0; mf < 4; mf++)
            #pragma unroll
            for (int r = 0; r < 4; r++) {
                float m = acc[mf][0][r];
                m = fmaxf(m, acc[mf][1][r]);
                m = fmaxf(m, acc[mf][2][r]);
                m = fmaxf(m, acc[mf][3][r]);
                #pragma unroll
                for (int o = 1; o < 16; o <<= 1) m = fmaxf(m, __shfl_xor(m, o));
                rm[mf][r] = m;
            }
        __syncthreads();
        if ((lane & 15) == 0) {
            #pragma unroll
            for (int mf = 0; mf < 4; mf++)
                #pragma unroll
                for (int r = 0; r < 4; r++)
                    red[(mf * 16 + (lane >> 4) * 4 + r) * 4 + wave] = rm[mf][r];
        }
        __syncthreads();
        if (tid < 64) {
            float m4 = fmaxf(fmaxf(red[tid * 4], red[tid * 4 + 1]),
                             fmaxf(red[tid * 4 + 2], red[tid * 4 + 3]));
            srow[tid] = m4 + diagb[(size_t)(m0 + tid) * 8 + h];
        }
    }
    u16* stg = (u16*)sm_;   // [64][264]
    __syncthreads();
    #pragma unroll
    for (int mf = 0; mf < 4; mf++)
        #pragma unroll
        for (int r = 0; r < 4; r++) {
            int row = mf * 16 + (lane >> 4) * 4 + r;
            float s = srow[row];
            #pragma unroll
            for (int nf = 0; nf < 4; nf++) {
                float v = acc[mf][nf][r];
                u16 o = isq ? f2bf(0.0625f * (exp2f(v - s) + 1e-4f))
                            : f2bf(exp2f(v - s));
                stg[row * 264 + wn + nf * 16 + fr] = o;
            }
        }
    __syncthreads();
    {
        int lr = tid >> 2, c0 = (tid & 3) * 64;
        u16* base = isq ? phiQ : psiK;
        u16* dst = base + (size_t)(m0 + lr) * 2048 + h * 256 + c0;
        #pragma unroll
        for (int q = 0; q < 8; q++)
            *(uint4*)(dst + q * 8) = *(uint4*)(stg + lr * 264 + c0 + q * 8);
    }
    if (!isq) {
        // fused transpose: this block = rows [m0, m0+64) = half-chunk (rc0)
        const int bb = m0 >> 12, cch = (m0 >> 7) & 31, rc0 = m0 & 64;
        const int gc = ((bb * 8 + h) << 5) + cch;
        u16* dT = psiKT + (size_t)gc * 32768 + (size_t)tid * 128 + rc0;
        #pragma unroll
        for (int jj = 0; jj < 4; jj++) {
            u32 w[8];
            #pragma unroll
            for (int p = 0; p < 8; p++) {
                int r = jj * 16 + p * 2;
                w[p] = pk(stg[r * 264 + tid], stg[(r + 1) * 264 + tid]);
            }
            *(uint4*)(dT + jj * 16) = *(uint4*)&w[0];
            *(uint4*)(dT + jj * 16 + 8) = *(uint4*)&w[4];
        }
    }
}

// ---------- final projection GEMM ----------
__global__ __launch_bounds__(256, 3)
void proj_gemm(const u16* __restrict__ A, const u16* __restrict__ B,
               float* __restrict__ C, const float* __restrict__ bias)
{
    __shared__ char smem[34816];
    char* As = smem; char* Bs = smem + 16384;
    const int m0 = blockIdx.x * 128, n0 = blockIdx.y * 128;
    const int tid = threadIdx.x, lane = tid & 63, wave = tid >> 6;
    const int wm = (wave >> 1) * 64, wn = (wave & 1) * 64;
    const int fr = lane & 15, fk = (lane >> 4) * 8;
    const int lr8 = lane >> 3;
    const int cE = ((lane & 7) ^ lr8) << 3;
    f32x4 acc[4][4] = {};
    for (int k0 = 0; k0 < 512; k0 += 64) {
        #pragma unroll
        for (int t = 0; t < 4; t++) {
            int i = wave * 4 + t;
            int r = (i << 3) + lr8;
            gload16(A + (size_t)(m0 + r) * 512 + k0 + cE, As + (i << 10));
            gload16(B + (size_t)(n0 + r) * 512 + k0 + cE, Bs + (i << 10));
        }
        __syncthreads();
        #pragma unroll
        for (int ks = 0; ks < 2; ks++) {
            bf16x8 af[4], bfv[4];
            #pragma unroll
            for (int mf = 0; mf < 4; mf++)
                af[mf] = *(bf16x8*)(As + swz(wm + mf * 16 + fr, ks * 32 + fk, 64));
            #pragma unroll
            for (int nf = 0; nf < 4; nf++)
                bfv[nf] = *(bf16x8*)(Bs + swz(wn + nf * 16 + fr, ks * 32 + fk, 64));
            #pragma unroll
            for (int mf = 0; mf < 4; mf++)
                #pragma unroll
                for (int nf = 0; nf < 4; nf++)
                    acc[mf][nf] = MF(af[mf], bfv[nf], acc[mf][nf]);
        }
        __syncthreads();
    }
    float* st = (float*)smem;
    for (int half = 0; half < 2; half++) {
        __syncthreads();
        if ((wave >> 1) == half) {
            #pragma unroll
            for (int mf = 0; mf < 4; mf++) {
                int lr = mf * 16 + (lane >> 4) * 4;
                #pragma unroll
                for (int nf = 0; nf < 4; nf++) {
                    int col = wn + nf * 16 + fr;
                    #pragma unroll
                    for (int r = 0; r < 4; r++)
                        st[(lr + r) * 130 + col] = acc[mf][nf][r];
                }
            }
        }
        __syncthreads();
        int lr = tid >> 2, c0 = (tid & 3) * 32;
        int grow = m0 + half * 64 + lr;
        float* dst = C + (size_t)grow * 512 + n0 + c0;
        #pragma unroll
        for (int q = 0; q < 8; q++) {
            float4 v;
            v.x = st[lr * 130 + c0 + q * 4 + 0] + bias[n0 + c0 + q * 4 + 0];
            v.y = st[lr * 130 + c0 + q * 4 + 1] + bias[n0 + c0 + q * 4 + 1];
            v.z = st[lr * 130 + c0 + q * 4 + 2] + bias[n0 + c0 + q * 4 + 2];
            v.w = st[lr * 130 + c0 + q * 4 + 3] + bias[n0 + c0 + q * 4 + 3];
            *(float4*)(dst + q * 4) = v;
        }
    }
}

// ---------- Pass A ----------
__global__ __launch_bounds__(256)
void chunk_sums_mfma(const u16* __restrict__ phiKT, const u16* __restrict__ Vt,
                     const u32* __restrict__ gmaxkey,
                     float* __restrict__ sbuf, float* __restrict__ zbuf)
{
    __shared__ char smem[49152];
    __shared__ float vcs[64];
    char* bufA = smem;
    char* bufBh = smem + 32768;
    char* bufBl = smem + 40960;
    const float mg = gmax_decode(gmaxkey);
    const float aF = 0.0625f * exp2f(-mg);
    const float bF = 0.0625f * 1e-4f;
    const int gc = blockIdx.x;
    const u16* Ag = phiKT + (size_t)gc * 32768;
    const u16* Bg = Vt + (size_t)gc * 16384;
    const int tid = threadIdx.x, lane = tid & 63, wave = tid >> 6;
    const int fr = lane & 15, fk = (lane >> 4) * 8;
    const int lr8 = lane >> 3;
    const int cE = ((lane & 7) ^ lr8) << 3;
    {
        float z = 0.f;
        const u16* zp = Ag + (size_t)tid * 128;
        #pragma unroll
        for (int j = 0; j < 16; j++) {
            bf16x8 w = *(const bf16x8*)(zp + j * 8);
            #pragma unroll
            for (int q = 0; q < 8; q++) z += bf2f((u16)w[q]);
        }
        zbuf[(size_t)gc * 256 + tid] = aF * z + bF * 128.0f;
    }
    if (tid < 64) {
        const u16* vh = Bg + (size_t)tid * 128;
        const u16* vl = vh + 8192;
        float s = 0.f;
        #pragma unroll
        for (int j = 0; j < 16; j++) {
            bf16x8 wh = *(const bf16x8*)(vh + j * 8);
            bf16x8 wl = *(const bf16x8*)(vl + j * 8);
            #pragma unroll
            for (int q = 0; q < 8; q++)
                s += bf2f((u16)wh[q]) + bf2f((u16)wl[q]);
        }
        vcs[tid] = s;
    }
    f32x4 acc[4][4] = {};
    for (int kh = 0; kh < 2; kh++) {
        #pragma unroll
        for (int t = 0; t < 8; t++) {
            int i = wave * 8 + t;
            int f = (i << 3) + lr8;
            gload16(Ag + (size_t)f * 128 + kh * 64 + cE, bufA + (i << 10));
        }
        #pragma unroll
        for (int t = 0; t < 2; t++) {
            int i = wave * 2 + t;
            int e = (i << 3) + lr8;
            gload16(Bg + (size_t)e * 128 + kh * 64 + cE, bufBh + (i << 10));
            gload16(Bg + 8192 + (size_t)e * 128 + kh * 64 + cE, bufBl + (i << 10));
        }
        __syncthreads();
        #pragma unroll
        for (int ks = 0; ks < 2; ks++) {
            bf16x8 af[4], bh4[4], bl4[4];
            #pragma unroll
            for (int mf = 0; mf < 4; mf++)
                af[mf] = *(bf16x8*)(bufA + swz(wave * 64 + mf * 16 + fr, ks * 32 + fk, 64));
            #pragma unroll
            for (int nf = 0; nf < 4; nf++) {
                bh4[nf] = *(bf16x8*)(bufBh + swz(nf * 16 + fr, ks * 32 + fk, 64));
                bl4[nf] = *(bf16x8*)(bufBl + swz(nf * 16 + fr, ks * 32 + fk, 64));
            }
            #pragma unroll
            for (int mf = 0; mf < 4; mf++)
                #pragma unroll
                for (int nf = 0; nf < 4; nf++) {
                    acc[mf][nf] = MF(af[mf], bh4[nf], acc[mf][nf]);
                    acc[mf][nf] = MF(af[mf], bl4[nf], acc[mf][nf]);
                }
        }
        __syncthreads();
    }
    #pragma unroll
    for (int mf = 0; mf < 4; mf++) {
        int fb = wave * 64 + mf * 16 + (lane >> 4) * 4;
        #pragma unroll
        for (int nf = 0; nf < 4; nf++) {
            int e = nf * 16 + fr;
            float vb = bF * vcs[e];
            #pragma unroll
            for (int r = 0; r < 4; r++)
                sbuf[(size_t)gc * 16384 + (size_t)(fb + r) * 64 + e] =
                    aF * acc[mf][nf][r] + vb;
        }
    }
}

// ---------- Pass B ----------
__global__ __launch_bounds__(256)
void prefix_scan(const float* __restrict__ sbuf, const float* __restrict__ zbuf,
                 u16* __restrict__ SpT, float* __restrict__ Zp,
                 float* __restrict__ outZ, float* __restrict__ outS)
{
    __shared__ float trans[64 * 17];
    const int bh = blockIdx.x >> 4, f0 = (blockIdx.x & 15) * 16;
    const int tid = threadIdx.x;
    const int e_ = tid >> 2, fl = (tid & 3) * 4;
    float run[4] = {0.f, 0.f, 0.f, 0.f};
    float zrun = 0.f;
    for (int c = 0; c < 32; c++) {
        const int gc = bh * 32 + c;
        const float* base = sbuf + (size_t)gc * 16384 + f0 * 64;
        float v[4];
        #pragma unroll
        for (int i = 0; i < 4; i++) v[i] = base[tid + i * 256];
        #pragma unroll
        for (int i = 0; i < 4; i++) {
            int idx = tid + i * 256;
            trans[(idx & 63) * 17 + (idx >> 6)] = run[i];
        }
        float zv = 0.f;
        if (tid < 16) zv = zbuf[(size_t)gc * 256 + f0 + tid];
        __syncthreads();
        {
            alignas(8) u16 hb[4], lb[4];
            #pragma unroll
            for (int q = 0; q < 4; q++) {
                float vv = trans[e_ * 17 + fl + q];
                u16 hh = f2bf(vv); hb[q] = hh; lb[q] = f2bf(vv - bf2f(hh));
            }
            u16* dh = SpT + (size_t)gc * 32768 + e_ * 256 + f0 + fl;
            *(uint2*)dh = *(uint2*)hb;
            *(uint2*)(dh + 16384) = *(uint2*)lb;
        }
        if (tid < 16) { Zp[(size_t)gc * 256 + f0 + tid] = zrun; zrun += zv; }
        #pragma unroll
        for (int i = 0; i < 4; i++) run[i] += v[i];
        __syncthreads();
    }
    #pragma unroll
    for (int i = 0; i < 4; i++)
        outS[(size_t)bh * 16384 + f0 * 64 + tid + i * 256] = run[i];
    if (tid < 16) outZ[bh * 256 + f0 + tid] = zrun;
}

// ---------- Pass C ----------
__global__ __launch_bounds__(256)
void chunk_out_mfma(const u16* __restrict__ phiQ, const u16* __restrict__ psiK,
                    const u16* __restrict__ Vt, const u16* __restrict__ SpT,
                    const float* __restrict__ Zp, const u32* __restrict__ gmaxkey,
                    u16* __restrict__ aouts)
{
    extern __shared__ char sm[];
    char* bufQ = sm;
    char* bufK = sm + 16384;
    char* bufA = sm + 32768;
    float* Dl = (float*)(sm + 65536);
    float* Zl = (float*)(sm + 66048);
    float* RowQ = (float*)(sm + 66304);
    const float mg = gmax_decode(gmaxkey);
    const float aF = 0.0625f * exp2f(-mg);
    const float bF = 0.0625f * 1e-4f;
    const int gc = blockIdx.x, c = gc & 31, bh = gc >> 5, b = bh >> 3, h = bh & 7;
    const int row0 = b * 4096 + c * 128;
    const u16* Qg = phiQ + (size_t)row0 * 2048 + h * 256;
    const u16* Kg = psiK + (size_t)row0 * 2048 + h * 256;
    const u16* Vg = Vt + (size_t)gc * 16384;
    const u16* Sg = SpT + (size_t)gc * 32768;
    const float* Zg = Zp + (size_t)gc * 256;
    const int tid = threadIdx.x, lane = tid & 63, wave = tid >> 6;
    const int fr = lane & 15, fk = (lane >> 4) * 8;
    const int dr = tid >> 1, dc = (tid & 1) * 32;
    const int lr8 = lane >> 3;
    const int cE = ((lane & 7) ^ lr8) << 3;

    f32x4 acc2[2][8] = {};
    f32x4 acc1[2][4] = {};
    float dotZ = 0.f, sumQ = 0.f;

    for (int f0 = 0; f0 < 256; f0 += 64) {
        #pragma unroll
        for (int t = 0; t < 4; t++) {
            int i = wave * 4 + t;
            int r = (i << 3) + lr8;
            gload16(Qg + (size_t)r * 2048 + f0 + cE, bufQ + (i << 10));
            gload16(Kg + (size_t)r * 2048 + f0 + cE, bufK + (i << 10));
        }
        #pragma unroll
        for (int t = 0; t < 2; t++) {
            int i = wave * 2 + t;
            int e = (i << 3) + lr8;
            gload16(Sg + (size_t)e * 256 + f0 + cE, bufA + (i << 10));
            gload16(Sg + 16384 + (size_t)e * 256 + f0 + cE, bufA + 8192 + (i << 10));
        }
        if (tid < 64) Zl[tid] = Zg[f0 + tid];
        __syncthreads();
        #pragma unroll
        for (int ks = 0; ks < 2; ks++) {
            bf16x8 af[2];
            af[0] = *(bf16x8*)(bufQ + swz(wave * 32 + fr, ks * 32 + fk, 64));
            af[1] = *(bf16x8*)(bufQ + swz(wave * 32 + 16 + fr, ks * 32 + fk, 64));
            #pragma unroll
            for (int nf = 0; nf < 8; nf++) {
                bf16x8 bv = *(bf16x8*)(bufK + swz(nf * 16 + fr, ks * 32 + fk, 64));
                acc2[0][nf] = MF(af[0], bv, acc2[0][nf]);
                acc2[1][nf] = MF(af[1], bv, acc2[1][nf]);
            }
            #pragma unroll
            for (int nf = 0; nf < 4; nf++) {
                bf16x8 bvh = *(bf16x8*)(bufA + swz(nf * 16 + fr, ks * 32 + fk, 64));
                bf16x8 bvl = *(bf16x8*)(bufA + 8192 + swz(nf * 16 + fr, ks * 32 + fk, 64));
                acc1[0][nf] = MF(af[0], bvh, acc1[0][nf]);
                acc1[1][nf] = MF(af[1], bvh, acc1[1][nf]);
                acc1[0][nf] = MF(af[0], bvl, acc1[0][nf]);
                acc1[1][nf] = MF(af[1], bvl, acc1[1][nf]);
            }
        }
        #pragma unroll
        for (int jj = 0; jj < 4; jj++) {
            bf16x8 qv = *(bf16x8*)(bufQ + swz(dr, dc + jj * 8, 64));
            f32x4 z0 = *(f32x4*)(Zl + dc + jj * 8);
            f32x4 z1 = *(f32x4*)(Zl + dc + jj * 8 + 4);
            #pragma unroll
            for (int q = 0; q < 8; q++) {
                float qf = bf2f((u16)qv[q]);
                sumQ += qf;
                dotZ += qf * (q < 4 ? z0[q] : z1[q - 4]);
            }
        }
        __syncthreads();
    }
    {
        float rq = sumQ + __shfl_xor(sumQ, 1);
        if ((tid & 1) == 0) RowQ[dr] = rq;
    }
    __syncthreads();
    float4 vvh[4];
    #pragma unroll
    for (int j = 0; j < 4; j++) {
        int ci = tid + j * 256; int e = ci >> 4, cc = (ci & 15) * 8;
        vvh[j] = *(const float4*)(Vg + (size_t)e * 128 + cc);
    }
    #pragma unroll
    for (int mf = 0; mf < 2; mf++) {
        int rb = wave * 32 + mf * 16 + (lane >> 4) * 4;
        #pragma unroll
        for (int nf = 0; nf < 8; nf++) {
            int col = nf * 16 + fr;
            #pragma unroll
            for (int r = 0; r < 4; r++) {
                float v = (col <= rb + r) ? (aF * acc2[mf][nf][r] + bF * RowQ[rb + r]) : 0.f;
                *(u16*)(bufA + swz(rb + r, col, 128)) = f2bf(v);
            }
        }
    }
    #pragma unroll
    for (int j = 0; j < 4; j++) {
        int ci = tid + j * 256; int e = ci >> 4, cc = (ci & 15) * 8;
        *(float4*)(bufK + swz(e, cc, 128)) = vvh[j];
    }
    __syncthreads();
    {
        const int dcA = (tid & 1) * 64;
        float rs = 0.f;
        #pragma unroll
        for (int jj = 0; jj < 8; jj++) {
            bf16x8 av = *(bf16x8*)(bufA + swz(dr, dcA + jj * 8, 128));
            #pragma unroll
            for (int q = 0; q < 8; q++) rs += bf2f((u16)av[q]);
        }
        float tot = rs + dotZ + 1e-6f * sumQ;
        tot += __shfl_xor(tot, 1);
        if ((tid & 1) == 0) Dl[dr] = tot;
    }
    #pragma unroll
    for (int ks = 0; ks < 4; ks++) {
        bf16x8 af[2];
        af[0] = *(bf16x8*)(bufA + swz(wave * 32 + fr, ks * 32 + fk, 128));
        af[1] = *(bf16x8*)(bufA + swz(wave * 32 + 16 + fr, ks * 32 + fk, 128));
        #pragma unroll
        for (int nf = 0; nf < 4; nf++) {
            bf16x8 bvh = *(bf16x8*)(bufK + swz(nf * 16 + fr, ks * 32 + fk, 128));
            acc1[0][nf] = MF(af[0], bvh, acc1[0][nf]);
            acc1[1][nf] = MF(af[1], bvh, acc1[1][nf]);
        }
    }
    __syncthreads();
    float* st = (float*)sm;
    #pragma unroll
    for (int mf = 0; mf < 2; mf++) {
        int rb = wave * 32 + mf * 16 + (lane >> 4) * 4;
        #pragma unroll
        for (int r = 0; r < 4; r++) {
            float dinv = 1.f / Dl[rb + r];
            #pragma unroll
            for (int nf = 0; nf < 4; nf++)
                st[(rb + r) * 65 + nf * 16 + fr] = acc1[mf][nf][r] * dinv;
        }
    }
    __syncthreads();
    {
        int lr = tid >> 1, e0 = (tid & 1) * 32;
        alignas(16) u16 hb[32];
        #pragma unroll
        for (int q = 0; q < 32; q++) hb[q] = f2bf(st[lr * 65 + e0 + q]);
        u16* d = aouts + (size_t)(row0 + lr) * 512 + h * 64 + e0;
        #pragma unroll
        for (int q = 0; q < 4; q++) *(uint4*)(d + q * 8) = *(uint4*)&hb[q * 8];
    }
}

extern "C" void kernel_launch(void* const* d_in, const int* in_sizes, int n_in,
                              void* d_out, int out_size, void* d_ws, size_t ws_size,
                              hipStream_t stream)
{
    const float* x    = (const float*)d_in[0];
    const float* Wq   = (const float*)d_in[1];
    const float* Wk   = (const float*)d_in[2];
    const float* Wv   = (const float*)d_in[3];
    const float* Wo   = (const float*)d_in[4];
    const float* bo   = (const float*)d_in[5];
    const float* proj = (const float*)d_in[6];
    float* out = (float*)d_out;
    float* ws = (float*)d_ws;

    float* diagb = ws + 4194304;                // [2][8192][8] f32 (log2-scaled)
    u16*   phi   = (u16*)(ws + 12582912);       // phiQ | psiK
    u16*   Vtb   = (u16*)(ws + 37748736);       // [512][2][64][128] u16
    float* sbuf  = ws + 41943040;               // 512*16384 f32
    u16*   qs    = (u16*)(ws + 41943040);       // q|k split [hi|lo] (dead after dd_gemm)
    u16*   phiKT = (u16*)(ws + 50331648);       // written by dd, dead after chunk_sums
    u16*   SpT   = (u16*)(ws + 50331648);       // overlay
    u16*   xs    = (u16*)(ws + 58720256);       // plain [8192][512] u16
    u16*   aouts = xs;
    u16*   Wqkvs = (u16*)(ws + 65011712);       // plain [1536][512] u16
    float* zbuf  = ws + 65142784;
    float* Zp    = ws + 65273856;
    u32*   gmax  = (u32*)(ws + 65404928);
    u16*   Wos   = (u16*)(ws + 66191360);       // plain [512][512] u16
    u16*   projs = (u16*)(ws + 66584576);       // [256][192] u16 (log2e-scaled)

    float* outO = out;
    float* outZ = out + 4194304;
    float* outS = out + 4198400;

    dim3 blk(256);

    hipMemsetAsync(gmax, 0, 4, stream);
    conv_plain<<<1024, blk, 0, stream>>>(x, xs, 1048576L);
    conv_w4<<<256, blk, 0, stream>>>(Wq, Wk, Wv, Wo, Wqkvs, Wos);
    conv_split<true ><<<16, blk, 0, stream>>>(proj, projs, 64, 4096L, LOG2E);
    qkv_gemm<<<dim3(64, 12), blk, 0, stream>>>(xs, Wqkvs, qs, diagb, Vtb);
    const u16* ksplit = qs + 8388608;
    u16* psiK = phi + (size_t)8192 * 2048;
    dd_gemm<<<dim3(128, 1, 16), blk, 0, stream>>>(qs, ksplit, projs, diagb, gmax,
                                                  phi, psiK, phiKT);
    chunk_sums_mfma<<<512, blk, 0, stream>>>(phiKT, Vtb, gmax, sbuf, zbuf);
    prefix_scan<<<256, blk, 0, stream>>>(sbuf, zbuf, SpT, Zp, outZ, outS);
    hipFuncSetAttribute((const void*)chunk_out_mfma,
                        hipFuncAttributeMaxDynamicSharedMemorySize, 66816);
    chunk_out_mfma<<<512, blk, 66816, stream>>>(phi, psiK, Vtb, SpT, Zp, gmax, aouts);
    proj_gemm<<<dim3(64, 4), blk, 0, stream>>>(aouts, Wos, outO, bo);
}